// Round 1
// 1012.469 us; speedup vs baseline: 1.9006x; 1.9006x over previous
//
#include <hip/hip_runtime.h>
#include <math.h>

#define BB 2
#define SS 4096
#define HIDK 512
#define HH 8
#define DD 64
#define NHH 4
#define NCC 256      // chunks per (b,h) = NH*S/CHUNK
#define RANKS 16384  // NH*S

typedef unsigned int u32;
typedef unsigned char u8;

__device__ __forceinline__ float bflo(u32 u){ return __uint_as_float(u << 16); }
__device__ __forceinline__ float bfhi(u32 u){ return __uint_as_float(u & 0xffff0000u); }

// ---------------------------------------------------------------------------
// Kernel 0: input dtype detection (bf16 vs fp32 bit patterns in w_qk).
// ---------------------------------------------------------------------------
__global__ __launch_bounds__(256) void k_detect(const u32* __restrict__ w, int* __restrict__ flag)
{
  int i = blockIdx.x * 256 + threadIdx.x;   // grid 512 -> 131072 u32
  float lo = bflo(w[i]);
  bool bad = !(fabsf(lo) <= 1024.0f);       // true also for NaN
  if (__any(bad)) {
    if ((threadIdx.x & 63) == 0) atomicOr(flag, 1);
  }
}

// ---------------------------------------------------------------------------
// Kernel 1: projections, fp32 accumulation.
// which=0: q=dec@wqk -> qb   (raw; hash + attention)
// which=1: k=hid@wqk -> kraw (raw; hash + attention, normalized in-LDS later)
// which=2: v=hid@wv  -> vb   (fp32)
// All outputs [B,H,S,D] fp32.
// ---------------------------------------------------------------------------
__global__ __launch_bounds__(256) void k_proj(
    const u32* __restrict__ dec, const u32* __restrict__ hid,
    const u32* __restrict__ wqk, const u32* __restrict__ wv,
    const int* __restrict__ flag,
    float* __restrict__ qb, float* __restrict__ kraw, float* __restrict__ vb)
{
  const int which = blockIdx.z;
  const u32* A = (which == 0) ? dec : hid;
  const u32* W = (which == 2) ? wv : wqk;
  const int m0 = blockIdx.x * 64;
  const int h  = blockIdx.y;
  const int t  = threadIdx.x;
  const int ty = t >> 4, tx = t & 15;
  const int is32 = flag[0];

  __shared__ float AsT[32][65];     // [kk][row i]
  __shared__ float Wst[32][4][16];  // [kk][c&3][c>>2] = W[kk][col c]

  float acc[4][4];
  #pragma unroll
  for (int r = 0; r < 4; ++r)
    #pragma unroll
    for (int c = 0; c < 4; ++c) acc[r][c] = 0.0f;

  for (int k0 = 0; k0 < HIDK; k0 += 32) {
    if (is32) {
      const float* Af = (const float*)A;
      const float* Wf = (const float*)W;
      #pragma unroll
      for (int it = 0; it < 8; ++it) {
        int idx = t + it * 256;          // 2048: 64 rows x 32 k
        int i = idx >> 5, kk = idx & 31;
        AsT[kk][i] = Af[(size_t)(m0 + i) * HIDK + k0 + kk];
      }
      #pragma unroll
      for (int it = 0; it < 8; ++it) {
        int idx = t + it * 256;          // 2048: 32 rows x 64 cols
        int kk = idx >> 6, c = idx & 63;
        Wst[kk][c & 3][c >> 2] = Wf[(size_t)(k0 + kk) * HIDK + h * 64 + c];
      }
    } else {
      #pragma unroll
      for (int it = 0; it < 4; ++it) {
        int idx = t + it * 256;          // 1024: A tile 64 rows x 16 u32
        int i = idx >> 4, kp = idx & 15;
        u32 uv = A[(size_t)(m0 + i) * (HIDK / 2) + (k0 >> 1) + kp];
        AsT[2 * kp][i]     = bflo(uv);
        AsT[2 * kp + 1][i] = bfhi(uv);
      }
      #pragma unroll
      for (int it = 0; it < 4; ++it) {
        int idx = t + it * 256;          // 1024: W tile 32 rows x 32 u32
        int kk = idx >> 5, cp = idx & 31;
        u32 uv = W[(size_t)(k0 + kk) * (HIDK / 2) + h * 32 + cp];
        int c0 = 2 * cp, c1 = 2 * cp + 1;
        Wst[kk][c0 & 3][c0 >> 2] = bflo(uv);
        Wst[kk][c1 & 3][c1 >> 2] = bfhi(uv);
      }
    }
    __syncthreads();
    for (int kk = 0; kk < 32; ++kk) {
      float a0 = AsT[kk][ty * 4 + 0];
      float a1 = AsT[kk][ty * 4 + 1];
      float a2 = AsT[kk][ty * 4 + 2];
      float a3 = AsT[kk][ty * 4 + 3];
      float w0 = Wst[kk][0][tx];
      float w1 = Wst[kk][1][tx];
      float w2 = Wst[kk][2][tx];
      float w3 = Wst[kk][3][tx];
      acc[0][0] += a0 * w0; acc[0][1] += a0 * w1; acc[0][2] += a0 * w2; acc[0][3] += a0 * w3;
      acc[1][0] += a1 * w0; acc[1][1] += a1 * w1; acc[1][2] += a1 * w2; acc[1][3] += a1 * w3;
      acc[2][0] += a2 * w0; acc[2][1] += a2 * w1; acc[2][2] += a2 * w2; acc[2][3] += a2 * w3;
      acc[3][0] += a3 * w0; acc[3][1] += a3 * w1; acc[3][2] += a3 * w2; acc[3][3] += a3 * w3;
    }
    __syncthreads();
  }

  float* outp = (which == 0) ? qb : ((which == 1) ? kraw : vb);
  #pragma unroll
  for (int r = 0; r < 4; ++r) {
    int m = m0 + ty * 4 + r;
    int b = m >> 12, s = m & 4095;
    float4 o;
    o.x = acc[r][0]; o.y = acc[r][1]; o.z = acc[r][2]; o.w = acc[r][3];
    *reinterpret_cast<float4*>(outp + ((size_t)((b * HH + h) * SS + s)) * DD + tx * 4) = o;
  }
}

// ---------------------------------------------------------------------------
// Kernel 2: LSH hash, fp32; raw q / raw k. First-index argmax over [rv,-rv]
// (np.argmax tie-break; positive half wins ties).
// ---------------------------------------------------------------------------
__global__ __launch_bounds__(256) void k_hash(
    const float* __restrict__ qb, const float* __restrict__ kraw,
    const u32* __restrict__ rots, const int* __restrict__ flag,
    u8* __restrict__ bucketOut)
{
  const int bhn = blockIdx.x;       // 0..63 : (b*8+h)*4+n
  const int which = blockIdx.y;     // 0=q 1=k
  const int squarter = blockIdx.z;  // 0..3
  const int t = threadIdx.x;
  const int bh = bhn >> 2;
  const int h  = bh & 7;
  const int n  = bhn & 3;
  const int is32 = flag[0];

  __shared__ float rotS[64][65];    // [d][r]
  if (is32) {
    const float* rf = (const float*)rots;
    #pragma unroll
    for (int it = 0; it < 16; ++it) {
      int idx = t + it * 256;       // 4096 floats
      int d = idx >> 6, r = idx & 63;
      rotS[d][r] = rf[((size_t)((h * 64 + d) * 4 + n)) * 64 + r];
    }
  } else {
    #pragma unroll
    for (int it = 0; it < 8; ++it) {
      int idx = t + it * 256;       // 2048 u32 (4096 bf16)
      int d = idx >> 5, rp = idx & 31;
      u32 uv = rots[((size_t)((h * 64 + d) * 4 + n)) * 32 + rp];
      rotS[d][2 * rp]     = bflo(uv);
      rotS[d][2 * rp + 1] = bfhi(uv);
    }
  }
  __syncthreads();

  const float* src = ((which == 0) ? qb : kraw) + (size_t)bh * SS * DD;
  u8* bout = bucketOut + ((size_t)(which * 64 + bhn)) * SS;

  for (int ii = 0; ii < 4; ++ii) {
    int s = squarter * 1024 + ii * 256 + t;
    const float* row = src + (size_t)s * DD;
    float vec[64];
    #pragma unroll
    for (int d4 = 0; d4 < 16; ++d4) {
      float4 v4 = *reinterpret_cast<const float4*>(row + d4 * 4);
      vec[d4 * 4 + 0] = v4.x; vec[d4 * 4 + 1] = v4.y;
      vec[d4 * 4 + 2] = v4.z; vec[d4 * 4 + 3] = v4.w;
    }
    float bestP = -1e30f, bestN = -1e30f;
    int idxP = 0, idxN = 0;
    #pragma unroll 1
    for (int r0 = 0; r0 < 64; r0 += 16) {
      float acc[16];
      #pragma unroll
      for (int rr = 0; rr < 16; ++rr) acc[rr] = 0.0f;
      #pragma unroll
      for (int d = 0; d < 64; ++d) {
        float vd = vec[d];
        #pragma unroll
        for (int rr = 0; rr < 16; ++rr) acc[rr] += vd * rotS[d][r0 + rr];
      }
      #pragma unroll
      for (int rr = 0; rr < 16; ++rr) {
        float a = acc[rr];
        int r = r0 + rr;
        if (a > bestP) { bestP = a; idxP = r; }
        if (-a > bestN) { bestN = -a; idxN = r; }
      }
    }
    int bucket = (bestP >= bestN) ? idxP : (64 + idxN);
    bout[s] = (u8)bucket;
  }
}

// ---------------------------------------------------------------------------
// Kernel 3: stable counting sort per (b,h,round,which): 4096 items, 128 bins.
// For which==1 also emits the rank (inverse permutation) used by k_combine.
// ---------------------------------------------------------------------------
__global__ __launch_bounds__(256) void k_sort(
    const u8* __restrict__ bucketIn, int* __restrict__ sq_pos,
    int* __restrict__ sk_pos, int* __restrict__ sk_rank)
{
  const int bhn = blockIdx.x, which = blockIdx.y;
  const int t = threadIdx.x;
  const int bh = bhn >> 2, n = bhn & 3;
  __shared__ u8 bk[4096];
  __shared__ int cntS[128];
  __shared__ int startS[128];
  const u8* bin = bucketIn + ((size_t)(which * 64 + bhn)) * SS;
  #pragma unroll
  for (int it = 0; it < 4; ++it)
    ((u32*)bk)[t + it * 256] = ((const u32*)bin)[t + it * 256];
  __syncthreads();
  if (t < 128) {
    int c = 0;
    for (int s = 0; s < 4096; ++s) c += (bk[s] == (u8)t) ? 1 : 0;
    cntS[t] = c;
  }
  __syncthreads();
  if (t == 0) {
    int run = 0;
    for (int b2 = 0; b2 < 128; ++b2) { startS[b2] = run; run += cntS[b2]; }
  }
  __syncthreads();
  int* outp = ((which == 0) ? sq_pos : sk_pos) + (size_t)bh * RANKS + n * SS;
  int* rnkp = sk_rank + (size_t)bh * RANKS + n * SS;
  if (t < 128) {
    int off = startS[t];
    for (int s = 0; s < 4096; ++s) {
      if (bk[s] == (u8)t) {
        outp[off] = s;
        if (which == 1) rnkp[s] = off;
        off++;
      }
    }
  }
}

// ---------------------------------------------------------------------------
// Kernel 4: single attention pass (replaces logits + weights + pv).
// Denominator trick: per-round softmax normalization and the cross-round
// logsumexp weighting cancel:
//   out[s] = (sum_n sum_j exp(dot) v_j) / (sum_n sum_j exp(dot))
// dots bounded (|q|<~5, |k_norm|=1) so no max-subtraction needed in fp32.
// mode==1 (big ws): write unnormalized num rows CONTIGUOUSLY in sorted order
//                   (coalesced, no atomics) + per-slot den; k_combine gathers.
// mode==0 (fallback): atomicAdd num into d_out and den into denA; k_div last.
// ---------------------------------------------------------------------------
__global__ __launch_bounds__(256) void k_attn(
    const float* __restrict__ qb, const float* __restrict__ kraw,
    const float* __restrict__ vb,
    const int* __restrict__ sq_pos, const int* __restrict__ sk_pos,
    const int mode,
    float* __restrict__ outA, float* __restrict__ denA,
    float* __restrict__ numB, float* __restrict__ denB)
{
  const int c = blockIdx.x;
  const int h = blockIdx.y, b = blockIdx.z;
  const int bh = b * HH + h;
  const int t = threadIdx.x;
  const int cprev = (c + NCC - 1) & (NCC - 1);

  __shared__ float Qs[64][68];
  __shared__ float KVs[128][68];
  __shared__ float sc[128];
  __shared__ int kposS[128], mposS[128];

  if (t < 128) {
    int slot = (t < 64) ? (cprev * 64 + t) : (c * 64 + (t - 64));
    kposS[t] = sk_pos[(size_t)bh * RANKS + slot];
    mposS[t] = sq_pos[(size_t)bh * RANKS + slot];
  }
  __syncthreads();

  const float* qbase = qb + (size_t)bh * SS * DD;
  const float* kbase = kraw + (size_t)bh * SS * DD;
  const float* vbase = vb + (size_t)bh * SS * DD;

  #pragma unroll
  for (int it = 0; it < 4; ++it) {
    int idx = t + it * 256;
    int i = idx >> 4, d4 = idx & 15;
    *reinterpret_cast<float4*>(&Qs[i][d4 * 4]) =
        *reinterpret_cast<const float4*>(qbase + (size_t)mposS[64 + i] * DD + d4 * 4);
  }
  #pragma unroll
  for (int it = 0; it < 8; ++it) {
    int idx = t + it * 256;
    int j = idx >> 4, d4 = idx & 15;
    *reinterpret_cast<float4*>(&KVs[j][d4 * 4]) =
        *reinterpret_cast<const float4*>(kbase + (size_t)kposS[j] * DD + d4 * 4);
  }
  __syncthreads();
  if (t < 128) {
    float ms = 0.f;
    #pragma unroll 8
    for (int d = 0; d < 64; ++d) { float x = KVs[t][d]; ms += x * x; }
    sc[t] = 0.125f / sqrtf(ms * (1.0f / 64.0f) + 1e-6f);
  }
  __syncthreads();
  #pragma unroll
  for (int it = 0; it < 8; ++it) {
    int idx = t + it * 256;
    int j = idx >> 4, d4 = idx & 15;
    float s_ = sc[j];
    float4 v4 = *reinterpret_cast<float4*>(&KVs[j][d4 * 4]);
    v4.x *= s_; v4.y *= s_; v4.z *= s_; v4.w *= s_;
    *reinterpret_cast<float4*>(&KVs[j][d4 * 4]) = v4;
  }
  __syncthreads();

  const int i = t >> 2, j0 = t & 3;
  const int myqpos = mposS[64 + i];

  float accD[32];
  #pragma unroll
  for (int jj = 0; jj < 32; ++jj) accD[jj] = 0.f;
  #pragma unroll 4
  for (int d0 = 0; d0 < 16; ++d0) {
    float4 q4 = *reinterpret_cast<const float4*>(&Qs[i][d0 * 4]);
    #pragma unroll
    for (int jj = 0; jj < 32; ++jj) {
      float4 k4 = *reinterpret_cast<const float4*>(&KVs[j0 + 4 * jj][d0 * 4]);
      accD[jj] += q4.x * k4.x + q4.y * k4.y + q4.z * k4.z + q4.w * k4.w;
    }
  }
  #pragma unroll
  for (int jj = 0; jj < 32; ++jj) {
    if (mposS[j0 + 4 * jj] == myqpos) accD[jj] = -100000.0f;
  }
  // un-normalized exp(dot); masked -> expf(-1e5) == 0
  float ssum = 0.f;
  #pragma unroll
  for (int jj = 0; jj < 32; ++jj) { float e = expf(accD[jj]); accD[jj] = e; ssum += e; }
  ssum += __shfl_xor(ssum, 1);
  ssum += __shfl_xor(ssum, 2);

  __syncthreads();  // done with K in LDS; reload V
  #pragma unroll
  for (int it = 0; it < 8; ++it) {
    int idx = t + it * 256;
    int j = idx >> 4, d4 = idx & 15;
    *reinterpret_cast<float4*>(&KVs[j][d4 * 4]) =
        *reinterpret_cast<const float4*>(vbase + (size_t)kposS[j] * DD + d4 * 4);
  }
  __syncthreads();

  float4 acc4[16];
  #pragma unroll
  for (int d4 = 0; d4 < 16; ++d4) acc4[d4] = make_float4(0.f, 0.f, 0.f, 0.f);
  #pragma unroll 4
  for (int jj = 0; jj < 32; ++jj) {
    float p = accD[jj];
    const int j = j0 + 4 * jj;
    #pragma unroll
    for (int d4 = 0; d4 < 16; ++d4) {
      float4 v4 = *reinterpret_cast<const float4*>(&KVs[j][d4 * 4]);
      acc4[d4].x += p * v4.x; acc4[d4].y += p * v4.y;
      acc4[d4].z += p * v4.z; acc4[d4].w += p * v4.w;
    }
  }
  #pragma unroll
  for (int d4 = 0; d4 < 16; ++d4) {
    acc4[d4].x += __shfl_xor(acc4[d4].x, 1); acc4[d4].x += __shfl_xor(acc4[d4].x, 2);
    acc4[d4].y += __shfl_xor(acc4[d4].y, 1); acc4[d4].y += __shfl_xor(acc4[d4].y, 2);
    acc4[d4].z += __shfl_xor(acc4[d4].z, 1); acc4[d4].z += __shfl_xor(acc4[d4].z, 2);
    acc4[d4].w += __shfl_xor(acc4[d4].w, 1); acc4[d4].w += __shfl_xor(acc4[d4].w, 2);
  }
  const int n = c >> 6;
  if (mode) {
    // contiguous per-round sorted layout; each row written exactly once
    const int sr = (c & 63) * 64 + i;
    float* nrow = numB + ((size_t)(bh * NHH + n) * SS + sr) * DD;
    #pragma unroll
    for (int dd = 0; dd < 4; ++dd)
      *reinterpret_cast<float4*>(nrow + j0 * 16 + dd * 4) = acc4[j0 * 4 + dd];
    if (j0 == 0) denB[(size_t)(bh * NHH + n) * SS + sr] = ssum;
  } else {
    const int sdst = kposS[64 + i];
    float* orow = outA + ((size_t)(b * SS + sdst)) * (HH * DD) + h * DD;
    #pragma unroll
    for (int dd = 0; dd < 4; ++dd) {
      float4 a = acc4[j0 * 4 + dd];
      int d = j0 * 16 + dd * 4;
      atomicAdd(&orow[d + 0], a.x);
      atomicAdd(&orow[d + 1], a.y);
      atomicAdd(&orow[d + 2], a.z);
      atomicAdd(&orow[d + 3], a.w);
    }
    if (j0 == 0) atomicAdd(&denA[(size_t)bh * SS + sdst], ssum);
  }
}

// ---------------------------------------------------------------------------
// Kernel 5 (big-ws path): gather-combine. For each (b,h,s) pull the 4 round
// rows via the K-sort rank array, sum num and den, divide, write coalesced.
// ---------------------------------------------------------------------------
__global__ __launch_bounds__(256) void k_combine(
    const float* __restrict__ numB, const float* __restrict__ denB,
    const int* __restrict__ sk_rank, float* __restrict__ outp)
{
  const int bh = blockIdx.y;
  const int s = blockIdx.x * 16 + (threadIdx.x >> 4);
  const int lane = threadIdx.x & 15;
  const int b = bh >> 3, h = bh & 7;
  float4 acc = make_float4(0.f, 0.f, 0.f, 0.f);
  float den = 0.f;
  #pragma unroll
  for (int n = 0; n < NHH; ++n) {
    int r = sk_rank[(size_t)bh * RANKS + n * SS + s];
    size_t rowi = (size_t)(bh * NHH + n) * SS + r;
    float4 v = *reinterpret_cast<const float4*>(numB + rowi * DD + lane * 4);
    acc.x += v.x; acc.y += v.y; acc.z += v.z; acc.w += v.w;
    den += denB[rowi];
  }
  float inv = 1.0f / den;
  acc.x *= inv; acc.y *= inv; acc.z *= inv; acc.w *= inv;
  *reinterpret_cast<float4*>(outp + ((size_t)(b * SS + s)) * (HH * DD) + h * DD + lane * 4) = acc;
}

// ---------------------------------------------------------------------------
// Kernel 5' (fallback path): divide accumulated numerator by denominator.
// ---------------------------------------------------------------------------
__global__ __launch_bounds__(256) void k_div(
    const float* __restrict__ den, float* __restrict__ outp)
{
  int idx = blockIdx.x * 256 + threadIdx.x;  // grid 4096 -> 1,048,576 float4
  int f = idx * 4;
  int col = f & 511;
  int h = col >> 6;
  int srow = f >> 9;                          // b*4096+s
  int b = srow >> 12, s = srow & 4095;
  float inv = 1.0f / den[(size_t)(b * HH + h) * SS + s];
  float4 v = *reinterpret_cast<float4*>(outp + (size_t)f);
  v.x *= inv; v.y *= inv; v.z *= inv; v.w *= inv;
  *reinterpret_cast<float4*>(outp + (size_t)f) = v;
}

// ---------------------------------------------------------------------------
// Kernel Z: zero the fp32 output (fallback path; harness poisons d_out).
// ---------------------------------------------------------------------------
__global__ __launch_bounds__(256) void k_zero_out(float* __restrict__ outp)
{
  int flat = blockIdx.x * 256 + threadIdx.x;  // grid 4096 -> 1,048,576 float4
  float4 z = make_float4(0.f, 0.f, 0.f, 0.f);
  *reinterpret_cast<float4*>(outp + (size_t)flat * 4) = z;
}

// ---------------------------------------------------------------------------
extern "C" void kernel_launch(void* const* d_in, const int* in_sizes, int n_in,
                              void* d_out, int out_size, void* d_ws, size_t ws_size,
                              hipStream_t stream)
{
  (void)in_sizes; (void)n_in; (void)out_size;
  const u32* dec = (const u32*)d_in[0];
  const u32* hid = (const u32*)d_in[1];
  const u32* wqk = (const u32*)d_in[2];
  const u32* wv  = (const u32*)d_in[3];
  const u32* rot = (const u32*)d_in[4];

  const size_t QKV  = (size_t)BB * HH * SS * DD;   // 4,194,304 elems
  const size_t LOGU = (size_t)BB * HH * NHH * SS;  // 262,144

  // Workspace layout:
  //   qb, kraw, vb        : 3 x 16.78 MB
  //   den                 : 1.05 MB  (A: [bh][s] prefix; B: [bh][n][slot])
  //   sq_pos, sk_pos      : 1.05 MB each
  //   sk_rank             : 1.05 MB
  //   buckets             : 0.52 MB
  //   flag                : 4 B
  //   numB (big ws only)  : 67.11 MB @ offset 55,050,496 (256B aligned)
  float* qb      = (float*)d_ws;
  float* kraw    = qb + QKV;
  float* vb      = kraw + QKV;
  float* den     = vb + QKV;                  // LOGU floats
  int*   sq_pos  = (int*)(den + LOGU);
  int*   sk_pos  = sq_pos + LOGU;
  int*   sk_rank = sk_pos + LOGU;
  u8*    buckets = (u8*)(sk_rank + LOGU);
  int*   flag    = (int*)(buckets + (size_t)2 * 64 * SS);
  const size_t numb_off = 55050496;           // align_up(55,050,244, 256)
  float* numb    = (float*)((char*)d_ws + numb_off);
  const size_t need_big = numb_off + (size_t)NHH * QKV * sizeof(float);  // 122,159,360
  const int big = (ws_size >= need_big) ? 1 : 0;

  hipMemsetAsync(flag, 0, sizeof(int), stream);
  k_detect<<<dim3(512), 256, 0, stream>>>(wqk, flag);
  k_proj<<<dim3(128, 8, 3), 256, 0, stream>>>(dec, hid, wqk, wv, flag, qb, kraw, vb);
  k_hash<<<dim3(64, 2, 4), 256, 0, stream>>>(qb, kraw, rot, flag, buckets);
  k_sort<<<dim3(64, 2), 256, 0, stream>>>(buckets, sq_pos, sk_pos, sk_rank);

  if (big) {
    k_attn<<<dim3(NCC, HH, BB), 256, 0, stream>>>(
        qb, kraw, vb, sq_pos, sk_pos, 1, nullptr, nullptr, numb, den);
    k_combine<<<dim3(SS / 16, BB * HH), 256, 0, stream>>>(
        numb, den, sk_rank, (float*)d_out);
  } else {
    hipMemsetAsync(den, 0, (size_t)BB * HH * SS * sizeof(float), stream);
    k_zero_out<<<dim3(4096), 256, 0, stream>>>((float*)d_out);
    k_attn<<<dim3(NCC, HH, BB), 256, 0, stream>>>(
        qb, kraw, vb, sq_pos, sk_pos, 0, (float*)d_out, den, nullptr, nullptr);
    k_div<<<dim3(4096), 256, 0, stream>>>(den, (float*)d_out);
  }
}

// Round 2
// 689.094 us; speedup vs baseline: 2.7924x; 1.4693x over previous
//
#include <hip/hip_runtime.h>
#include <math.h>

#define BB 2
#define SS 4096
#define HIDK 512
#define HH 8
#define DD 64
#define NHH 4
#define NCC 256      // chunks per (b,h) = NH*S/CHUNK
#define RANKS 16384  // NH*S

typedef unsigned int u32;
typedef unsigned char u8;

__device__ __forceinline__ float bflo(u32 u){ return __uint_as_float(u << 16); }
__device__ __forceinline__ float bfhi(u32 u){ return __uint_as_float(u & 0xffff0000u); }

// ---------------------------------------------------------------------------
// Kernel 0: input dtype detection (bf16 vs fp32 bit patterns in w_qk).
// ---------------------------------------------------------------------------
__global__ __launch_bounds__(256) void k_detect(const u32* __restrict__ w, int* __restrict__ flag)
{
  int i = blockIdx.x * 256 + threadIdx.x;   // grid 512 -> 131072 u32
  float lo = bflo(w[i]);
  bool bad = !(fabsf(lo) <= 1024.0f);       // true also for NaN
  if (__any(bad)) {
    if ((threadIdx.x & 63) == 0) atomicOr(flag, 1);
  }
}

// ---------------------------------------------------------------------------
// Kernel 1: projections, fp32 accumulation.
// which=0: q=dec@wqk -> qb   (raw; hash + attention)
// which=1: k=hid@wqk -> kraw (raw; hash + attention, normalized in-LDS later)
// which=2: v=hid@wv  -> vb   (fp32)
// All outputs [B,H,S,D] fp32.
// ---------------------------------------------------------------------------
__global__ __launch_bounds__(256) void k_proj(
    const u32* __restrict__ dec, const u32* __restrict__ hid,
    const u32* __restrict__ wqk, const u32* __restrict__ wv,
    const int* __restrict__ flag,
    float* __restrict__ qb, float* __restrict__ kraw, float* __restrict__ vb)
{
  const int which = blockIdx.z;
  const u32* A = (which == 0) ? dec : hid;
  const u32* W = (which == 2) ? wv : wqk;
  const int m0 = blockIdx.x * 64;
  const int h  = blockIdx.y;
  const int t  = threadIdx.x;
  const int ty = t >> 4, tx = t & 15;
  const int is32 = flag[0];

  __shared__ float AsT[32][65];     // [kk][row i]
  __shared__ float Wst[32][4][16];  // [kk][c&3][c>>2] = W[kk][col c]

  float acc[4][4];
  #pragma unroll
  for (int r = 0; r < 4; ++r)
    #pragma unroll
    for (int c = 0; c < 4; ++c) acc[r][c] = 0.0f;

  for (int k0 = 0; k0 < HIDK; k0 += 32) {
    if (is32) {
      const float* Af = (const float*)A;
      const float* Wf = (const float*)W;
      #pragma unroll
      for (int it = 0; it < 8; ++it) {
        int idx = t + it * 256;          // 2048: 64 rows x 32 k
        int i = idx >> 5, kk = idx & 31;
        AsT[kk][i] = Af[(size_t)(m0 + i) * HIDK + k0 + kk];
      }
      #pragma unroll
      for (int it = 0; it < 8; ++it) {
        int idx = t + it * 256;          // 2048: 32 rows x 64 cols
        int kk = idx >> 6, c = idx & 63;
        Wst[kk][c & 3][c >> 2] = Wf[(size_t)(k0 + kk) * HIDK + h * 64 + c];
      }
    } else {
      #pragma unroll
      for (int it = 0; it < 4; ++it) {
        int idx = t + it * 256;          // 1024: A tile 64 rows x 16 u32
        int i = idx >> 4, kp = idx & 15;
        u32 uv = A[(size_t)(m0 + i) * (HIDK / 2) + (k0 >> 1) + kp];
        AsT[2 * kp][i]     = bflo(uv);
        AsT[2 * kp + 1][i] = bfhi(uv);
      }
      #pragma unroll
      for (int it = 0; it < 4; ++it) {
        int idx = t + it * 256;          // 1024: W tile 32 rows x 32 u32
        int kk = idx >> 5, cp = idx & 31;
        u32 uv = W[(size_t)(k0 + kk) * (HIDK / 2) + h * 32 + cp];
        int c0 = 2 * cp, c1 = 2 * cp + 1;
        Wst[kk][c0 & 3][c0 >> 2] = bflo(uv);
        Wst[kk][c1 & 3][c1 >> 2] = bfhi(uv);
      }
    }
    __syncthreads();
    for (int kk = 0; kk < 32; ++kk) {
      float a0 = AsT[kk][ty * 4 + 0];
      float a1 = AsT[kk][ty * 4 + 1];
      float a2 = AsT[kk][ty * 4 + 2];
      float a3 = AsT[kk][ty * 4 + 3];
      float w0 = Wst[kk][0][tx];
      float w1 = Wst[kk][1][tx];
      float w2 = Wst[kk][2][tx];
      float w3 = Wst[kk][3][tx];
      acc[0][0] += a0 * w0; acc[0][1] += a0 * w1; acc[0][2] += a0 * w2; acc[0][3] += a0 * w3;
      acc[1][0] += a1 * w0; acc[1][1] += a1 * w1; acc[1][2] += a1 * w2; acc[1][3] += a1 * w3;
      acc[2][0] += a2 * w0; acc[2][1] += a2 * w1; acc[2][2] += a2 * w2; acc[2][3] += a2 * w3;
      acc[3][0] += a3 * w0; acc[3][1] += a3 * w1; acc[3][2] += a3 * w2; acc[3][3] += a3 * w3;
    }
    __syncthreads();
  }

  float* outp = (which == 0) ? qb : ((which == 1) ? kraw : vb);
  #pragma unroll
  for (int r = 0; r < 4; ++r) {
    int m = m0 + ty * 4 + r;
    int b = m >> 12, s = m & 4095;
    float4 o;
    o.x = acc[r][0]; o.y = acc[r][1]; o.z = acc[r][2]; o.w = acc[r][3];
    *reinterpret_cast<float4*>(outp + ((size_t)((b * HH + h) * SS + s)) * DD + tx * 4) = o;
  }
}

// ---------------------------------------------------------------------------
// Kernel 2: LSH hash, fp32; raw q / raw k. First-index argmax over [rv,-rv]
// (np.argmax tie-break; positive half wins ties).
// ---------------------------------------------------------------------------
__global__ __launch_bounds__(256) void k_hash(
    const float* __restrict__ qb, const float* __restrict__ kraw,
    const u32* __restrict__ rots, const int* __restrict__ flag,
    u8* __restrict__ bucketOut)
{
  const int bhn = blockIdx.x;       // 0..63 : (b*8+h)*4+n
  const int which = blockIdx.y;     // 0=q 1=k
  const int squarter = blockIdx.z;  // 0..3
  const int t = threadIdx.x;
  const int bh = bhn >> 2;
  const int h  = bh & 7;
  const int n  = bhn & 3;
  const int is32 = flag[0];

  __shared__ float rotS[64][65];    // [d][r]
  if (is32) {
    const float* rf = (const float*)rots;
    #pragma unroll
    for (int it = 0; it < 16; ++it) {
      int idx = t + it * 256;       // 4096 floats
      int d = idx >> 6, r = idx & 63;
      rotS[d][r] = rf[((size_t)((h * 64 + d) * 4 + n)) * 64 + r];
    }
  } else {
    #pragma unroll
    for (int it = 0; it < 8; ++it) {
      int idx = t + it * 256;       // 2048 u32 (4096 bf16)
      int d = idx >> 5, rp = idx & 31;
      u32 uv = rots[((size_t)((h * 64 + d) * 4 + n)) * 32 + rp];
      rotS[d][2 * rp]     = bflo(uv);
      rotS[d][2 * rp + 1] = bfhi(uv);
    }
  }
  __syncthreads();

  const float* src = ((which == 0) ? qb : kraw) + (size_t)bh * SS * DD;
  u8* bout = bucketOut + ((size_t)(which * 64 + bhn)) * SS;

  for (int ii = 0; ii < 4; ++ii) {
    int s = squarter * 1024 + ii * 256 + t;
    const float* row = src + (size_t)s * DD;
    float vec[64];
    #pragma unroll
    for (int d4 = 0; d4 < 16; ++d4) {
      float4 v4 = *reinterpret_cast<const float4*>(row + d4 * 4);
      vec[d4 * 4 + 0] = v4.x; vec[d4 * 4 + 1] = v4.y;
      vec[d4 * 4 + 2] = v4.z; vec[d4 * 4 + 3] = v4.w;
    }
    float bestP = -1e30f, bestN = -1e30f;
    int idxP = 0, idxN = 0;
    #pragma unroll 1
    for (int r0 = 0; r0 < 64; r0 += 16) {
      float acc[16];
      #pragma unroll
      for (int rr = 0; rr < 16; ++rr) acc[rr] = 0.0f;
      #pragma unroll
      for (int d = 0; d < 64; ++d) {
        float vd = vec[d];
        #pragma unroll
        for (int rr = 0; rr < 16; ++rr) acc[rr] += vd * rotS[d][r0 + rr];
      }
      #pragma unroll
      for (int rr = 0; rr < 16; ++rr) {
        float a = acc[rr];
        int r = r0 + rr;
        if (a > bestP) { bestP = a; idxP = r; }
        if (-a > bestN) { bestN = -a; idxN = r; }
      }
    }
    int bucket = (bestP >= bestN) ? idxP : (64 + idxN);
    bout[s] = (u8)bucket;
  }
}

// ---------------------------------------------------------------------------
// Kernel 3: PARALLEL stable counting sort per (b,h,round,which).
// 4096 items, 128 bins. Wave-ballot bucket matching gives per-64-chunk stable
// ranks; chunk histograms + bin prefix + per-bin chunk prefix give globally
// stable positions. Serial depth ~100 vs old ~8192.
// ---------------------------------------------------------------------------
__global__ __launch_bounds__(256) void k_sort(
    const u8* __restrict__ bucketIn, int* __restrict__ sq_pos,
    int* __restrict__ sk_pos, int* __restrict__ sk_rank)
{
  const int bhn = blockIdx.x, which = blockIdx.y;
  const int t = threadIdx.x;
  const int bh = bhn >> 2, n = bhn & 3;
  const int lane = t & 63, w = t >> 6;

  __shared__ u8 bk[4096];
  __shared__ u8 rk[4096];
  __shared__ int chunkh[64 * 128];   // [chunk][bin], 32 KB
  __shared__ int hist[128];
  __shared__ int scanS[128];

  const u8* bin = bucketIn + ((size_t)(which * 64 + bhn)) * SS;
  #pragma unroll
  for (int it = 0; it < 4; ++it)
    ((u32*)bk)[t + it * 256] = ((const u32*)bin)[t + it * 256];
  #pragma unroll
  for (int it = 0; it < 32; ++it) chunkh[t + it * 256] = 0;
  if (t < 128) hist[t] = 0;
  __syncthreads();

  const unsigned long long below = (lane == 0) ? 0ull : (~0ull >> (64 - lane));
  #pragma unroll 1
  for (int k = 0; k < 16; ++k) {
    const int c = w * 16 + k;
    const int s = c * 64 + lane;
    const int b = bk[s];
    unsigned long long m = ~0ull;
    #pragma unroll
    for (int bit = 0; bit < 7; ++bit) {
      unsigned long long vote = __ballot((b >> bit) & 1);
      m &= ((b >> bit) & 1) ? vote : ~vote;
    }
    const int r = (int)__popcll(m & below);
    rk[s] = (u8)r;
    if (r == 0) {
      const int cnt = (int)__popcll(m);
      chunkh[c * 128 + b] = cnt;
      atomicAdd(&hist[b], cnt);
    }
  }
  __syncthreads();

  // inclusive Hillis-Steele scan over 128 bins (barriers wave-uniform)
  if (t < 128) scanS[t] = hist[t];
  __syncthreads();
  for (int off = 1; off < 128; off <<= 1) {
    int add = 0;
    if (t < 128 && t >= off) add = scanS[t - off];
    __syncthreads();
    if (t < 128) scanS[t] += add;
    __syncthreads();
  }
  // per-bin exclusive prefix over 64 chunks; thread t = bin t
  if (t < 128) {
    int run = scanS[t] - hist[t];    // global bin start
    #pragma unroll 1
    for (int c = 0; c < 64; ++c) {
      int v = chunkh[c * 128 + t];
      chunkh[c * 128 + t] = run;
      run += v;
    }
  }
  __syncthreads();

  int* outp = ((which == 0) ? sq_pos : sk_pos) + (size_t)bh * RANKS + n * SS;
  int* rnkp = sk_rank + (size_t)bh * RANKS + n * SS;
  #pragma unroll 1
  for (int k = 0; k < 16; ++k) {
    const int c = w * 16 + k;
    const int s = c * 64 + lane;
    const int b = bk[s];
    const int pos = chunkh[c * 128 + b] + (int)rk[s];
    outp[pos] = s;
    if (which) rnkp[s] = pos;
  }
}

// ---------------------------------------------------------------------------
// Kernel 4: single attention pass.
//   out[s] = (sum_n sum_j exp(dot) v_j) / (sum_n sum_j exp(dot))
// PV epilogue is split into 4 passes over 16-d blocks so only 16 accumulator
// floats are live at once (was 96 -> scratch spill -> 420 MB HBM writeback).
// ---------------------------------------------------------------------------
__global__ __launch_bounds__(256) void k_attn(
    const float* __restrict__ qb, const float* __restrict__ kraw,
    const float* __restrict__ vb,
    const int* __restrict__ sq_pos, const int* __restrict__ sk_pos,
    const int mode,
    float* __restrict__ outA, float* __restrict__ denA,
    float* __restrict__ numB, float* __restrict__ denB)
{
  const int c = blockIdx.x;
  const int h = blockIdx.y, b = blockIdx.z;
  const int bh = b * HH + h;
  const int t = threadIdx.x;
  const int cprev = (c + NCC - 1) & (NCC - 1);

  __shared__ float Qs[64][68];
  __shared__ float KVs[128][68];
  __shared__ float sc[128];
  __shared__ int kposS[128], mposS[128];

  if (t < 128) {
    int slot = (t < 64) ? (cprev * 64 + t) : (c * 64 + (t - 64));
    kposS[t] = sk_pos[(size_t)bh * RANKS + slot];
    mposS[t] = sq_pos[(size_t)bh * RANKS + slot];
  }
  __syncthreads();

  const float* qbase = qb + (size_t)bh * SS * DD;
  const float* kbase = kraw + (size_t)bh * SS * DD;
  const float* vbase = vb + (size_t)bh * SS * DD;

  #pragma unroll
  for (int it = 0; it < 4; ++it) {
    int idx = t + it * 256;
    int i = idx >> 4, d4 = idx & 15;
    *reinterpret_cast<float4*>(&Qs[i][d4 * 4]) =
        *reinterpret_cast<const float4*>(qbase + (size_t)mposS[64 + i] * DD + d4 * 4);
  }
  #pragma unroll
  for (int it = 0; it < 8; ++it) {
    int idx = t + it * 256;
    int j = idx >> 4, d4 = idx & 15;
    *reinterpret_cast<float4*>(&KVs[j][d4 * 4]) =
        *reinterpret_cast<const float4*>(kbase + (size_t)kposS[j] * DD + d4 * 4);
  }
  __syncthreads();
  if (t < 128) {
    float ms = 0.f;
    #pragma unroll
    for (int d4 = 0; d4 < 16; ++d4) {
      float4 x4 = *reinterpret_cast<float4*>(&KVs[t][d4 * 4]);
      ms += x4.x * x4.x + x4.y * x4.y + x4.z * x4.z + x4.w * x4.w;
    }
    sc[t] = 0.125f / sqrtf(ms * (1.0f / 64.0f) + 1e-6f);
  }
  __syncthreads();
  #pragma unroll
  for (int it = 0; it < 8; ++it) {
    int idx = t + it * 256;
    int j = idx >> 4, d4 = idx & 15;
    float s_ = sc[j];
    float4 v4 = *reinterpret_cast<float4*>(&KVs[j][d4 * 4]);
    v4.x *= s_; v4.y *= s_; v4.z *= s_; v4.w *= s_;
    *reinterpret_cast<float4*>(&KVs[j][d4 * 4]) = v4;
  }
  __syncthreads();

  const int i = t >> 2, j0 = t & 3;
  const int myqpos = mposS[64 + i];

  float accD[32];
  #pragma unroll
  for (int jj = 0; jj < 32; ++jj) accD[jj] = 0.f;
  #pragma unroll 4
  for (int d0 = 0; d0 < 16; ++d0) {
    float4 q4 = *reinterpret_cast<const float4*>(&Qs[i][d0 * 4]);
    #pragma unroll
    for (int jj = 0; jj < 32; ++jj) {
      float4 k4 = *reinterpret_cast<const float4*>(&KVs[j0 + 4 * jj][d0 * 4]);
      accD[jj] += q4.x * k4.x + q4.y * k4.y + q4.z * k4.z + q4.w * k4.w;
    }
  }
  #pragma unroll
  for (int jj = 0; jj < 32; ++jj) {
    if (mposS[j0 + 4 * jj] == myqpos) accD[jj] = -100000.0f;
  }
  // un-normalized exp(dot); masked -> expf(-1e5) == 0
  float ssum = 0.f;
  #pragma unroll
  for (int jj = 0; jj < 32; ++jj) { float e = expf(accD[jj]); accD[jj] = e; ssum += e; }
  ssum += __shfl_xor(ssum, 1);
  ssum += __shfl_xor(ssum, 2);

  __syncthreads();  // done with K in LDS; reload V
  #pragma unroll
  for (int it = 0; it < 8; ++it) {
    int idx = t + it * 256;
    int j = idx >> 4, d4 = idx & 15;
    *reinterpret_cast<float4*>(&KVs[j][d4 * 4]) =
        *reinterpret_cast<const float4*>(vbase + (size_t)kposS[j] * DD + d4 * 4);
  }
  __syncthreads();

  const int n = c >> 6;
  const int sr = (c & 63) * 64 + i;
  const int sdst = kposS[64 + i];
  float* nrow = mode ? (numB + ((size_t)(bh * NHH + n) * SS + sr) * DD)
                     : (outA + ((size_t)(b * SS + sdst)) * (HH * DD) + h * DD);
  if (j0 == 0) {
    if (mode) denB[(size_t)(bh * NHH + n) * SS + sr] = ssum;
    else      atomicAdd(&denA[(size_t)bh * SS + sdst], ssum);
  }

  // PV: 4 passes over 16-d blocks; only 4 float4 accumulators live at a time
  #pragma unroll 1
  for (int db = 0; db < 4; ++db) {
    float4 a0 = make_float4(0.f, 0.f, 0.f, 0.f);
    float4 a1 = a0, a2 = a0, a3 = a0;
    #pragma unroll 4
    for (int jj = 0; jj < 32; ++jj) {
      const float p = accD[jj];
      const float* vr = &KVs[j0 + 4 * jj][db * 16];
      float4 v0 = *reinterpret_cast<const float4*>(vr + 0);
      float4 v1 = *reinterpret_cast<const float4*>(vr + 4);
      float4 v2 = *reinterpret_cast<const float4*>(vr + 8);
      float4 v3 = *reinterpret_cast<const float4*>(vr + 12);
      a0.x += p * v0.x; a0.y += p * v0.y; a0.z += p * v0.z; a0.w += p * v0.w;
      a1.x += p * v1.x; a1.y += p * v1.y; a1.z += p * v1.z; a1.w += p * v1.w;
      a2.x += p * v2.x; a2.y += p * v2.y; a2.z += p * v2.z; a2.w += p * v2.w;
      a3.x += p * v3.x; a3.y += p * v3.y; a3.z += p * v3.z; a3.w += p * v3.w;
    }
    // reduce across the 4 lanes sharing q-row i
    a0.x += __shfl_xor(a0.x, 1); a0.x += __shfl_xor(a0.x, 2);
    a0.y += __shfl_xor(a0.y, 1); a0.y += __shfl_xor(a0.y, 2);
    a0.z += __shfl_xor(a0.z, 1); a0.z += __shfl_xor(a0.z, 2);
    a0.w += __shfl_xor(a0.w, 1); a0.w += __shfl_xor(a0.w, 2);
    a1.x += __shfl_xor(a1.x, 1); a1.x += __shfl_xor(a1.x, 2);
    a1.y += __shfl_xor(a1.y, 1); a1.y += __shfl_xor(a1.y, 2);
    a1.z += __shfl_xor(a1.z, 1); a1.z += __shfl_xor(a1.z, 2);
    a1.w += __shfl_xor(a1.w, 1); a1.w += __shfl_xor(a1.w, 2);
    a2.x += __shfl_xor(a2.x, 1); a2.x += __shfl_xor(a2.x, 2);
    a2.y += __shfl_xor(a2.y, 1); a2.y += __shfl_xor(a2.y, 2);
    a2.z += __shfl_xor(a2.z, 1); a2.z += __shfl_xor(a2.z, 2);
    a2.w += __shfl_xor(a2.w, 1); a2.w += __shfl_xor(a2.w, 2);
    a3.x += __shfl_xor(a3.x, 1); a3.x += __shfl_xor(a3.x, 2);
    a3.y += __shfl_xor(a3.y, 1); a3.y += __shfl_xor(a3.y, 2);
    a3.z += __shfl_xor(a3.z, 1); a3.z += __shfl_xor(a3.z, 2);
    a3.w += __shfl_xor(a3.w, 1); a3.w += __shfl_xor(a3.w, 2);
    // lane j0 writes float4 at db*16 + j0*4 (64B line fully covered per i)
    float4 mine = (j0 == 0) ? a0 : (j0 == 1) ? a1 : (j0 == 2) ? a2 : a3;
    if (mode) {
      *reinterpret_cast<float4*>(nrow + db * 16 + j0 * 4) = mine;
    } else {
      float* p = nrow + db * 16 + j0 * 4;
      atomicAdd(&p[0], mine.x);
      atomicAdd(&p[1], mine.y);
      atomicAdd(&p[2], mine.z);
      atomicAdd(&p[3], mine.w);
    }
  }
}

// ---------------------------------------------------------------------------
// Kernel 5 (big-ws path): gather-combine. For each (b,h,s) pull the 4 round
// rows via the K-sort rank array, sum num and den, divide, write coalesced.
// ---------------------------------------------------------------------------
__global__ __launch_bounds__(256) void k_combine(
    const float* __restrict__ numB, const float* __restrict__ denB,
    const int* __restrict__ sk_rank, float* __restrict__ outp)
{
  const int bh = blockIdx.y;
  const int s = blockIdx.x * 16 + (threadIdx.x >> 4);
  const int lane = threadIdx.x & 15;
  const int b = bh >> 3, h = bh & 7;
  float4 acc = make_float4(0.f, 0.f, 0.f, 0.f);
  float den = 0.f;
  #pragma unroll
  for (int n = 0; n < NHH; ++n) {
    int r = sk_rank[(size_t)bh * RANKS + n * SS + s];
    size_t rowi = (size_t)(bh * NHH + n) * SS + r;
    float4 v = *reinterpret_cast<const float4*>(numB + rowi * DD + lane * 4);
    acc.x += v.x; acc.y += v.y; acc.z += v.z; acc.w += v.w;
    den += denB[rowi];
  }
  float inv = 1.0f / den;
  acc.x *= inv; acc.y *= inv; acc.z *= inv; acc.w *= inv;
  *reinterpret_cast<float4*>(outp + ((size_t)(b * SS + s)) * (HH * DD) + h * DD + lane * 4) = acc;
}

// ---------------------------------------------------------------------------
// Kernel 5' (fallback path): divide accumulated numerator by denominator.
// ---------------------------------------------------------------------------
__global__ __launch_bounds__(256) void k_div(
    const float* __restrict__ den, float* __restrict__ outp)
{
  int idx = blockIdx.x * 256 + threadIdx.x;  // grid 4096 -> 1,048,576 float4
  int f = idx * 4;
  int col = f & 511;
  int h = col >> 6;
  int srow = f >> 9;                          // b*4096+s
  int b = srow >> 12, s = srow & 4095;
  float inv = 1.0f / den[(size_t)(b * HH + h) * SS + s];
  float4 v = *reinterpret_cast<float4*>(outp + (size_t)f);
  v.x *= inv; v.y *= inv; v.z *= inv; v.w *= inv;
  *reinterpret_cast<float4*>(outp + (size_t)f) = v;
}

// ---------------------------------------------------------------------------
// Kernel Z: zero the fp32 output (fallback path; harness poisons d_out).
// ---------------------------------------------------------------------------
__global__ __launch_bounds__(256) void k_zero_out(float* __restrict__ outp)
{
  int flat = blockIdx.x * 256 + threadIdx.x;  // grid 4096 -> 1,048,576 float4
  float4 z = make_float4(0.f, 0.f, 0.f, 0.f);
  *reinterpret_cast<float4*>(outp + (size_t)flat * 4) = z;
}

// ---------------------------------------------------------------------------
extern "C" void kernel_launch(void* const* d_in, const int* in_sizes, int n_in,
                              void* d_out, int out_size, void* d_ws, size_t ws_size,
                              hipStream_t stream)
{
  (void)in_sizes; (void)n_in; (void)out_size;
  const u32* dec = (const u32*)d_in[0];
  const u32* hid = (const u32*)d_in[1];
  const u32* wqk = (const u32*)d_in[2];
  const u32* wv  = (const u32*)d_in[3];
  const u32* rot = (const u32*)d_in[4];

  const size_t QKV  = (size_t)BB * HH * SS * DD;   // 4,194,304 elems
  const size_t LOGU = (size_t)BB * HH * NHH * SS;  // 262,144

  // Workspace layout:
  //   qb, kraw, vb        : 3 x 16.78 MB
  //   den                 : 1.05 MB  (A: [bh][s] prefix; B: [bh][n][slot])
  //   sq_pos, sk_pos      : 1.05 MB each
  //   sk_rank             : 1.05 MB
  //   buckets             : 0.52 MB
  //   flag                : 4 B
  //   numB (big ws only)  : 67.11 MB @ offset 55,050,496 (256B aligned)
  float* qb      = (float*)d_ws;
  float* kraw    = qb + QKV;
  float* vb      = kraw + QKV;
  float* den     = vb + QKV;                  // LOGU floats
  int*   sq_pos  = (int*)(den + LOGU);
  int*   sk_pos  = sq_pos + LOGU;
  int*   sk_rank = sk_pos + LOGU;
  u8*    buckets = (u8*)(sk_rank + LOGU);
  int*   flag    = (int*)(buckets + (size_t)2 * 64 * SS);
  const size_t numb_off = 55050496;           // align_up(55,050,244, 256)
  float* numb    = (float*)((char*)d_ws + numb_off);
  const size_t need_big = numb_off + (size_t)NHH * QKV * sizeof(float);  // 122,159,360
  const int big = (ws_size >= need_big) ? 1 : 0;

  hipMemsetAsync(flag, 0, sizeof(int), stream);
  k_detect<<<dim3(512), 256, 0, stream>>>(wqk, flag);
  k_proj<<<dim3(128, 8, 3), 256, 0, stream>>>(dec, hid, wqk, wv, flag, qb, kraw, vb);
  k_hash<<<dim3(64, 2, 4), 256, 0, stream>>>(qb, kraw, rot, flag, buckets);
  k_sort<<<dim3(64, 2), 256, 0, stream>>>(buckets, sq_pos, sk_pos, sk_rank);

  if (big) {
    k_attn<<<dim3(NCC, HH, BB), 256, 0, stream>>>(
        qb, kraw, vb, sq_pos, sk_pos, 1, nullptr, nullptr, numb, den);
    k_combine<<<dim3(SS / 16, BB * HH), 256, 0, stream>>>(
        numb, den, sk_rank, (float*)d_out);
  } else {
    hipMemsetAsync(den, 0, (size_t)BB * HH * SS * sizeof(float), stream);
    k_zero_out<<<dim3(4096), 256, 0, stream>>>((float*)d_out);
    k_attn<<<dim3(NCC, HH, BB), 256, 0, stream>>>(
        qb, kraw, vb, sq_pos, sk_pos, 0, (float*)d_out, den, nullptr, nullptr);
    k_div<<<dim3(4096), 256, 0, stream>>>(den, (float*)d_out);
  }
}

// Round 7
// 669.006 us; speedup vs baseline: 2.8763x; 1.0300x over previous
//
#include <hip/hip_runtime.h>
#include <math.h>

#define BB 2
#define SS 4096
#define HIDK 512
#define HH 8
#define DD 64
#define NHH 4
#define NCC 256      // chunks per (b,h) = NH*S/CHUNK
#define RANKS 16384  // NH*S

typedef unsigned int u32;
typedef unsigned char u8;
typedef __attribute__((ext_vector_type(8))) short bf16x8;
typedef __attribute__((ext_vector_type(4))) float f32x4;

__device__ __forceinline__ float bflo(u32 u){ return __uint_as_float(u << 16); }
__device__ __forceinline__ float bfhi(u32 u){ return __uint_as_float(u & 0xffff0000u); }

// RN fp32 -> bf16 (top of x)
__device__ __forceinline__ unsigned short brn(float x)
{
  u32 u = __float_as_uint(x);
  u32 r = u + 0x7FFFu + ((u >> 16) & 1u);
  return (unsigned short)(r >> 16);
}

// 3-term bf16 split: x ~= b0 + b1 + b2 (Sterbenz-exact residuals).
__device__ __forceinline__ void bsplit3(float x, unsigned short& b0, unsigned short& b1, unsigned short& b2)
{
  b0 = brn(x);
  float x1 = x - __uint_as_float((u32)b0 << 16);
  b1 = brn(x1);
  float x2 = x1 - __uint_as_float((u32)b1 << 16);
  b2 = brn(x2);
}

// ---------------------------------------------------------------------------
// Kernel 0: input dtype detection (bf16 vs fp32 bit patterns in w_qk).
// ---------------------------------------------------------------------------
__global__ __launch_bounds__(256) void k_detect(const u32* __restrict__ w, int* __restrict__ flag)
{
  int i = blockIdx.x * 256 + threadIdx.x;   // grid 512 -> 131072 u32
  float lo = bflo(w[i]);
  bool bad = !(fabsf(lo) <= 1024.0f);       // true also for NaN
  if (__any(bad)) {
    if ((threadIdx.x & 63) == 0) atomicOr(flag, 1);
  }
}

// ---------------------------------------------------------------------------
// Kernel P: prep weights. Transpose W[k][n] -> Wt[n][k], 3-term bf16 split
// for fp32 inputs. wt*: [2][512][512] u16 (plane 0 = wqk, 1 = wv).
// ---------------------------------------------------------------------------
__global__ __launch_bounds__(256) void k_prep(
    const u32* __restrict__ wqk, const u32* __restrict__ wv,
    const int* __restrict__ flag,
    unsigned short* __restrict__ wt0, unsigned short* __restrict__ wt1,
    unsigned short* __restrict__ wt2)
{
  const int which = blockIdx.y;
  const u32* W = which ? wv : wqk;
  const int tk = blockIdx.x >> 4, tn = blockIdx.x & 15;
  const int t = threadIdx.x;
  const int is32 = flag[0];
  __shared__ unsigned short h0s[32][36];
  __shared__ unsigned short h1s[32][36];
  __shared__ unsigned short h2s[32][36];
  if (is32) {
    const float* Wf = (const float*)W;
    #pragma unroll
    for (int it = 0; it < 4; ++it) {
      int idx = t + it * 256;           // 1024 = 32 k x 32 n
      int kk = idx >> 5, nn = idx & 31;
      float x = Wf[(size_t)(tk * 32 + kk) * 512 + tn * 32 + nn];
      bsplit3(x, h0s[kk][nn], h1s[kk][nn], h2s[kk][nn]);
    }
  } else {
    #pragma unroll
    for (int it = 0; it < 2; ++it) {
      int idx = t + it * 256;           // 512 u32 = 32 k x 16 pairs
      int kk = idx >> 4, np = idx & 15;
      u32 uv = W[(size_t)(tk * 32 + kk) * 256 + tn * 16 + np];
      h0s[kk][2 * np]     = (unsigned short)(uv & 0xffffu);
      h0s[kk][2 * np + 1] = (unsigned short)(uv >> 16);
      h1s[kk][2 * np] = 0; h1s[kk][2 * np + 1] = 0;
      h2s[kk][2 * np] = 0; h2s[kk][2 * np + 1] = 0;
    }
  }
  __syncthreads();
  size_t obase = ((size_t)which * 512 + tn * 32) * 512 + tk * 32;
  #pragma unroll
  for (int it = 0; it < 4; ++it) {
    int idx = t + it * 256;
    int nn = idx >> 5, kk = idx & 31;
    wt0[obase + (size_t)nn * 512 + kk] = h0s[kk][nn];
    wt1[obase + (size_t)nn * 512 + kk] = h1s[kk][nn];
    wt2[obase + (size_t)nn * 512 + kk] = h2s[kk][nn];
  }
}

// ---------------------------------------------------------------------------
// Kernel 1a: SCALAR projections for q and k (hash-feeding; R0-R2-proven).
// which=0: q=dec@wqk -> qb ; which=1: k=hid@wqk -> kraw.
// ---------------------------------------------------------------------------
__global__ __launch_bounds__(256) void k_proj_s(
    const u32* __restrict__ dec, const u32* __restrict__ hid,
    const u32* __restrict__ wqk, const u32* __restrict__ wv,
    const int* __restrict__ flag,
    float* __restrict__ qb, float* __restrict__ kraw, float* __restrict__ vb)
{
  const int which = blockIdx.z;
  const u32* A = (which == 0) ? dec : hid;
  const u32* W = (which == 2) ? wv : wqk;
  const int m0 = blockIdx.x * 64;
  const int h  = blockIdx.y;
  const int t  = threadIdx.x;
  const int ty = t >> 4, tx = t & 15;
  const int is32 = flag[0];

  __shared__ float AsT[32][65];     // [kk][row i]
  __shared__ float Wst[32][4][16];  // [kk][c&3][c>>2] = W[kk][col c]

  float acc[4][4];
  #pragma unroll
  for (int r = 0; r < 4; ++r)
    #pragma unroll
    for (int c = 0; c < 4; ++c) acc[r][c] = 0.0f;

  for (int k0 = 0; k0 < HIDK; k0 += 32) {
    if (is32) {
      const float* Af = (const float*)A;
      const float* Wf = (const float*)W;
      #pragma unroll
      for (int it = 0; it < 8; ++it) {
        int idx = t + it * 256;          // 2048: 64 rows x 32 k
        int i = idx >> 5, kk = idx & 31;
        AsT[kk][i] = Af[(size_t)(m0 + i) * HIDK + k0 + kk];
      }
      #pragma unroll
      for (int it = 0; it < 8; ++it) {
        int idx = t + it * 256;          // 2048: 32 rows x 64 cols
        int kk = idx >> 6, c = idx & 63;
        Wst[kk][c & 3][c >> 2] = Wf[(size_t)(k0 + kk) * HIDK + h * 64 + c];
      }
    } else {
      #pragma unroll
      for (int it = 0; it < 4; ++it) {
        int idx = t + it * 256;          // 1024: A tile 64 rows x 16 u32
        int i = idx >> 4, kp = idx & 15;
        u32 uv = A[(size_t)(m0 + i) * (HIDK / 2) + (k0 >> 1) + kp];
        AsT[2 * kp][i]     = bflo(uv);
        AsT[2 * kp + 1][i] = bfhi(uv);
      }
      #pragma unroll
      for (int it = 0; it < 4; ++it) {
        int idx = t + it * 256;          // 1024: W tile 32 rows x 32 u32
        int kk = idx >> 5, cp = idx & 31;
        u32 uv = W[(size_t)(k0 + kk) * (HIDK / 2) + h * 32 + cp];
        int c0 = 2 * cp, c1 = 2 * cp + 1;
        Wst[kk][c0 & 3][c0 >> 2] = bflo(uv);
        Wst[kk][c1 & 3][c1 >> 2] = bfhi(uv);
      }
    }
    __syncthreads();
    for (int kk = 0; kk < 32; ++kk) {
      float a0 = AsT[kk][ty * 4 + 0];
      float a1 = AsT[kk][ty * 4 + 1];
      float a2 = AsT[kk][ty * 4 + 2];
      float a3 = AsT[kk][ty * 4 + 3];
      float w0 = Wst[kk][0][tx];
      float w1 = Wst[kk][1][tx];
      float w2 = Wst[kk][2][tx];
      float w3 = Wst[kk][3][tx];
      acc[0][0] += a0 * w0; acc[0][1] += a0 * w1; acc[0][2] += a0 * w2; acc[0][3] += a0 * w3;
      acc[1][0] += a1 * w0; acc[1][1] += a1 * w1; acc[1][2] += a1 * w2; acc[1][3] += a1 * w3;
      acc[2][0] += a2 * w0; acc[2][1] += a2 * w1; acc[2][2] += a2 * w2; acc[2][3] += a2 * w3;
      acc[3][0] += a3 * w0; acc[3][1] += a3 * w1; acc[3][2] += a3 * w2; acc[3][3] += a3 * w3;
    }
    __syncthreads();
  }

  float* outp = (which == 0) ? qb : ((which == 1) ? kraw : vb);
  #pragma unroll
  for (int r = 0; r < 4; ++r) {
    int m = m0 + ty * 4 + r;
    int b = m >> 12, s = m & 4095;
    float4 o;
    o.x = acc[r][0]; o.y = acc[r][1]; o.z = acc[r][2]; o.w = acc[r][3];
    *reinterpret_cast<float4*>(outp + ((size_t)((b * HH + h) * SS + s)) * DD + tx * 4) = o;
  }
}

// ---------------------------------------------------------------------------
// Kernel 1b: MFMA projection for V ONLY (v = hid @ wv).
// V feeds no argmax; small numerical differences are harmless.
// ---------------------------------------------------------------------------
__global__ __launch_bounds__(256) void k_proj_v(
    const u32* __restrict__ hid,
    const unsigned short* __restrict__ wt0, const unsigned short* __restrict__ wt1,
    const unsigned short* __restrict__ wt2,
    const int* __restrict__ flag,
    float* __restrict__ vb)
{
  const int bid = blockIdx.x;              // grid 1024 = 8 x 128
  const int x = bid & 7, l = bid >> 3;     // l in [0,128)
  const int h = l & 7;
  const int m0 = (x * 16 + ((l >> 3) & 15)) * 64;
  const int t = threadIdx.x;
  const int w = t >> 6;
  const int r = t & 15, g = (t & 63) >> 4;
  const int is32 = flag[0];

  const u32* A = hid;
  const size_t wbase = (size_t)1 * 512 * 512 + (size_t)h * 64 * 512;  // wv plane
  const unsigned short* W0 = wt0 + wbase;
  const unsigned short* W1 = wt1 + wbase;
  const unsigned short* W2 = wt2 + wbase;

  __shared__ __align__(16) unsigned short A0[64][40];  // stride 80B
  __shared__ __align__(16) unsigned short A1[64][40];
  __shared__ __align__(16) unsigned short A2[64][40];
  __shared__ __align__(16) unsigned short B0[64][40];
  __shared__ __align__(16) unsigned short B1[64][40];
  __shared__ __align__(16) unsigned short B2[64][40];

  f32x4 acc[4];
  #pragma unroll
  for (int tn = 0; tn < 4; ++tn) { acc[tn][0] = 0.f; acc[tn][1] = 0.f; acc[tn][2] = 0.f; acc[tn][3] = 0.f; }

  for (int k0 = 0; k0 < HIDK; k0 += 32) {
    {
      const int n = t >> 2, kq = t & 3;
      *reinterpret_cast<uint4*>(&B0[n][kq * 8]) =
          *reinterpret_cast<const uint4*>(W0 + (size_t)n * 512 + k0 + kq * 8);
      if (is32) {
        *reinterpret_cast<uint4*>(&B1[n][kq * 8]) =
            *reinterpret_cast<const uint4*>(W1 + (size_t)n * 512 + k0 + kq * 8);
        *reinterpret_cast<uint4*>(&B2[n][kq * 8]) =
            *reinterpret_cast<const uint4*>(W2 + (size_t)n * 512 + k0 + kq * 8);
      }
    }
    if (is32) {
      const float* Af = (const float*)A;
      #pragma unroll
      for (int it = 0; it < 2; ++it) {
        int idx = t + it * 256;
        int m = idx >> 3, kq = idx & 7;
        float4 a4 = *reinterpret_cast<const float4*>(Af + (size_t)(m0 + m) * HIDK + k0 + kq * 4);
        ushort4 p0, p1, p2;
        bsplit3(a4.x, p0.x, p1.x, p2.x);
        bsplit3(a4.y, p0.y, p1.y, p2.y);
        bsplit3(a4.z, p0.z, p1.z, p2.z);
        bsplit3(a4.w, p0.w, p1.w, p2.w);
        *reinterpret_cast<ushort4*>(&A0[m][kq * 4]) = p0;
        *reinterpret_cast<ushort4*>(&A1[m][kq * 4]) = p1;
        *reinterpret_cast<ushort4*>(&A2[m][kq * 4]) = p2;
      }
    } else {
      #pragma unroll
      for (int it = 0; it < 2; ++it) {
        int idx = t + it * 256;
        int m = idx >> 3, kq = idx & 7;
        uint2 uv = *reinterpret_cast<const uint2*>(A + (size_t)(m0 + m) * (HIDK / 2) + (k0 >> 1) + kq * 2);
        *reinterpret_cast<uint2*>(&A0[m][kq * 4]) = uv;
      }
    }
    __syncthreads();

    bf16x8 a0 = *reinterpret_cast<const bf16x8*>(&A0[w * 16 + r][g * 8]);
    if (is32) {
      bf16x8 a1 = *reinterpret_cast<const bf16x8*>(&A1[w * 16 + r][g * 8]);
      bf16x8 a2 = *reinterpret_cast<const bf16x8*>(&A2[w * 16 + r][g * 8]);
      #pragma unroll
      for (int tn = 0; tn < 4; ++tn) {
        bf16x8 b0 = *reinterpret_cast<const bf16x8*>(&B0[tn * 16 + r][g * 8]);
        bf16x8 b1 = *reinterpret_cast<const bf16x8*>(&B1[tn * 16 + r][g * 8]);
        bf16x8 b2 = *reinterpret_cast<const bf16x8*>(&B2[tn * 16 + r][g * 8]);
        acc[tn] = __builtin_amdgcn_mfma_f32_16x16x32_bf16(a0, b0, acc[tn], 0, 0, 0);
        acc[tn] = __builtin_amdgcn_mfma_f32_16x16x32_bf16(a0, b1, acc[tn], 0, 0, 0);
        acc[tn] = __builtin_amdgcn_mfma_f32_16x16x32_bf16(a1, b0, acc[tn], 0, 0, 0);
        acc[tn] = __builtin_amdgcn_mfma_f32_16x16x32_bf16(a0, b2, acc[tn], 0, 0, 0);
        acc[tn] = __builtin_amdgcn_mfma_f32_16x16x32_bf16(a2, b0, acc[tn], 0, 0, 0);
        acc[tn] = __builtin_amdgcn_mfma_f32_16x16x32_bf16(a1, b1, acc[tn], 0, 0, 0);
      }
    } else {
      #pragma unroll
      for (int tn = 0; tn < 4; ++tn) {
        bf16x8 b0 = *reinterpret_cast<const bf16x8*>(&B0[tn * 16 + r][g * 8]);
        acc[tn] = __builtin_amdgcn_mfma_f32_16x16x32_bf16(a0, b0, acc[tn], 0, 0, 0);
      }
    }
    __syncthreads();
  }

  #pragma unroll
  for (int tn = 0; tn < 4; ++tn)
    #pragma unroll
    for (int rg = 0; rg < 4; ++rg) {
      int m = m0 + w * 16 + g * 4 + rg;
      int b = m >> 12, s = m & 4095;
      vb[((size_t)((b * HH + h) * SS + s)) * DD + tn * 16 + r] = acc[tn][rg];
    }
}

// ---------------------------------------------------------------------------
// Kernel 2: LSH hash, fp32; raw q / raw k. First-index argmax over [rv,-rv].
// ---------------------------------------------------------------------------
__global__ __launch_bounds__(256) void k_hash(
    const float* __restrict__ qb, const float* __restrict__ kraw,
    const u32* __restrict__ rots, const int* __restrict__ flag,
    u8* __restrict__ bucketOut)
{
  const int bhn = blockIdx.x;       // 0..63 : (b*8+h)*4+n
  const int which = blockIdx.y;     // 0=q 1=k
  const int squarter = blockIdx.z;  // 0..3
  const int t = threadIdx.x;
  const int bh = bhn >> 2;
  const int h  = bh & 7;
  const int n  = bhn & 3;
  const int is32 = flag[0];

  __shared__ float rotS[64][65];    // [d][r]
  if (is32) {
    const float* rf = (const float*)rots;
    #pragma unroll
    for (int it = 0; it < 16; ++it) {
      int idx = t + it * 256;       // 4096 floats
      int d = idx >> 6, r = idx & 63;
      rotS[d][r] = rf[((size_t)((h * 64 + d) * 4 + n)) * 64 + r];
    }
  } else {
    #pragma unroll
    for (int it = 0; it < 8; ++it) {
      int idx = t + it * 256;       // 2048 u32 (4096 bf16)
      int d = idx >> 5, rp = idx & 31;
      u32 uv = rots[((size_t)((h * 64 + d) * 4 + n)) * 32 + rp];
      rotS[d][2 * rp]     = bflo(uv);
      rotS[d][2 * rp + 1] = bfhi(uv);
    }
  }
  __syncthreads();

  const float* src = ((which == 0) ? qb : kraw) + (size_t)bh * SS * DD;
  u8* bout = bucketOut + ((size_t)(which * 64 + bhn)) * SS;

  for (int ii = 0; ii < 4; ++ii) {
    int s = squarter * 1024 + ii * 256 + t;
    const float* row = src + (size_t)s * DD;
    float vec[64];
    #pragma unroll
    for (int d4 = 0; d4 < 16; ++d4) {
      float4 v4 = *reinterpret_cast<const float4*>(row + d4 * 4);
      vec[d4 * 4 + 0] = v4.x; vec[d4 * 4 + 1] = v4.y;
      vec[d4 * 4 + 2] = v4.z; vec[d4 * 4 + 3] = v4.w;
    }
    float bestP = -1e30f, bestN = -1e30f;
    int idxP = 0, idxN = 0;
    #pragma unroll 1
    for (int r0 = 0; r0 < 64; r0 += 16) {
      float acc[16];
      #pragma unroll
      for (int rr = 0; rr < 16; ++rr) acc[rr] = 0.0f;
      #pragma unroll
      for (int d = 0; d < 64; ++d) {
        float vd = vec[d];
        #pragma unroll
        for (int rr = 0; rr < 16; ++rr) acc[rr] += vd * rotS[d][r0 + rr];
      }
      #pragma unroll
      for (int rr = 0; rr < 16; ++rr) {
        float a = acc[rr];
        int r = r0 + rr;
        if (a > bestP) { bestP = a; idxP = r; }
        if (-a > bestN) { bestN = -a; idxN = r; }
      }
    }
    int bucket = (bestP >= bestN) ? idxP : (64 + idxN);
    bout[s] = (u8)bucket;
  }
}

// ---------------------------------------------------------------------------
// Kernel 3: PARALLEL stable counting sort per (b,h,round,which).
// ---------------------------------------------------------------------------
__global__ __launch_bounds__(256) void k_sort(
    const u8* __restrict__ bucketIn, int* __restrict__ sq_pos,
    int* __restrict__ sk_pos, int* __restrict__ sk_rank)
{
  const int bhn = blockIdx.x, which = blockIdx.y;
  const int t = threadIdx.x;
  const int bh = bhn >> 2, n = bhn & 3;
  const int lane = t & 63, w = t >> 6;

  __shared__ u8 bk[4096];
  __shared__ u8 rk[4096];
  __shared__ int chunkh[64 * 128];   // [chunk][bin], 32 KB
  __shared__ int hist[128];
  __shared__ int scanS[128];

  const u8* bin = bucketIn + ((size_t)(which * 64 + bhn)) * SS;
  #pragma unroll
  for (int it = 0; it < 4; ++it)
    ((u32*)bk)[t + it * 256] = ((const u32*)bin)[t + it * 256];
  #pragma unroll
  for (int it = 0; it < 32; ++it) chunkh[t + it * 256] = 0;
  if (t < 128) hist[t] = 0;
  __syncthreads();

  const unsigned long long below = (lane == 0) ? 0ull : (~0ull >> (64 - lane));
  #pragma unroll 1
  for (int k = 0; k < 16; ++k) {
    const int c = w * 16 + k;
    const int s = c * 64 + lane;
    const int b = bk[s];
    unsigned long long m = ~0ull;
    #pragma unroll
    for (int bit = 0; bit < 7; ++bit) {
      unsigned long long vote = __ballot((b >> bit) & 1);
      m &= ((b >> bit) & 1) ? vote : ~vote;
    }
    const int r = (int)__popcll(m & below);
    rk[s] = (u8)r;
    if (r == 0) {
      const int cnt = (int)__popcll(m);
      chunkh[c * 128 + b] = cnt;
      atomicAdd(&hist[b], cnt);
    }
  }
  __syncthreads();

  if (t < 128) scanS[t] = hist[t];
  __syncthreads();
  for (int off = 1; off < 128; off <<= 1) {
    int add = 0;
    if (t < 128 && t >= off) add = scanS[t - off];
    __syncthreads();
    if (t < 128) scanS[t] += add;
    __syncthreads();
  }
  if (t < 128) {
    int run = scanS[t] - hist[t];    // global bin start
    #pragma unroll 1
    for (int c = 0; c < 64; ++c) {
      int v = chunkh[c * 128 + t];
      chunkh[c * 128 + t] = run;
      run += v;
    }
  }
  __syncthreads();

  int* outp = ((which == 0) ? sq_pos : sk_pos) + (size_t)bh * RANKS + n * SS;
  int* rnkp = sk_rank + (size_t)bh * RANKS + n * SS;
  #pragma unroll 1
  for (int k = 0; k < 16; ++k) {
    const int c = w * 16 + k;
    const int s = c * 64 + lane;
    const int b = bk[s];
    const int pos = chunkh[c * 128 + b] + (int)rk[s];
    outp[pos] = s;
    if (which) rnkp[s] = pos;
  }
}

// ---------------------------------------------------------------------------
// Kernel 4: single attention pass (R2-proven version, unchanged).
// ---------------------------------------------------------------------------
__global__ __launch_bounds__(256) void k_attn(
    const float* __restrict__ qb, const float* __restrict__ kraw,
    const float* __restrict__ vb,
    const int* __restrict__ sq_pos, const int* __restrict__ sk_pos,
    const int mode,
    float* __restrict__ outA, float* __restrict__ denA,
    float* __restrict__ numB, float* __restrict__ denB)
{
  const int c = blockIdx.x;
  const int h = blockIdx.y, b = blockIdx.z;
  const int bh = b * HH + h;
  const int t = threadIdx.x;
  const int cprev = (c + NCC - 1) & (NCC - 1);

  __shared__ float Qs[64][68];
  __shared__ float KVs[128][68];
  __shared__ float sc[128];
  __shared__ int kposS[128], mposS[128];

  if (t < 128) {
    int slot = (t < 64) ? (cprev * 64 + t) : (c * 64 + (t - 64));
    kposS[t] = sk_pos[(size_t)bh * RANKS + slot];
    mposS[t] = sq_pos[(size_t)bh * RANKS + slot];
  }
  __syncthreads();

  const float* qbase = qb + (size_t)bh * SS * DD;
  const float* kbase = kraw + (size_t)bh * SS * DD;
  const float* vbase = vb + (size_t)bh * SS * DD;

  #pragma unroll
  for (int it = 0; it < 4; ++it) {
    int idx = t + it * 256;
    int i = idx >> 4, d4 = idx & 15;
    *reinterpret_cast<float4*>(&Qs[i][d4 * 4]) =
        *reinterpret_cast<const float4*>(qbase + (size_t)mposS[64 + i] * DD + d4 * 4);
  }
  #pragma unroll
  for (int it = 0; it < 8; ++it) {
    int idx = t + it * 256;
    int j = idx >> 4, d4 = idx & 15;
    *reinterpret_cast<float4*>(&KVs[j][d4 * 4]) =
        *reinterpret_cast<const float4*>(kbase + (size_t)kposS[j] * DD + d4 * 4);
  }
  __syncthreads();
  if (t < 128) {
    float ms = 0.f;
    #pragma unroll
    for (int d4 = 0; d4 < 16; ++d4) {
      float4 x4 = *reinterpret_cast<float4*>(&KVs[t][d4 * 4]);
      ms += x4.x * x4.x + x4.y * x4.y + x4.z * x4.z + x4.w * x4.w;
    }
    sc[t] = 0.125f / sqrtf(ms * (1.0f / 64.0f) + 1e-6f);
  }
  __syncthreads();
  #pragma unroll
  for (int it = 0; it < 8; ++it) {
    int idx = t + it * 256;
    int j = idx >> 4, d4 = idx & 15;
    float s_ = sc[j];
    float4 v4 = *reinterpret_cast<float4*>(&KVs[j][d4 * 4]);
    v4.x *= s_; v4.y *= s_; v4.z *= s_; v4.w *= s_;
    *reinterpret_cast<float4*>(&KVs[j][d4 * 4]) = v4;
  }
  __syncthreads();

  const int i = t >> 2, j0 = t & 3;
  const int myqpos = mposS[64 + i];

  float accD[32];
  #pragma unroll
  for (int jj = 0; jj < 32; ++jj) accD[jj] = 0.f;
  #pragma unroll 4
  for (int d0 = 0; d0 < 16; ++d0) {
    float4 q4 = *reinterpret_cast<const float4*>(&Qs[i][d0 * 4]);
    #pragma unroll
    for (int jj = 0; jj < 32; ++jj) {
      float4 k4 = *reinterpret_cast<const float4*>(&KVs[j0 + 4 * jj][d0 * 4]);
      accD[jj] += q4.x * k4.x + q4.y * k4.y + q4.z * k4.z + q4.w * k4.w;
    }
  }
  #pragma unroll
  for (int jj = 0; jj < 32; ++jj) {
    if (mposS[j0 + 4 * jj] == myqpos) accD[jj] = -100000.0f;
  }
  // un-normalized exp(dot); masked -> expf(-1e5) == 0
  float ssum = 0.f;
  #pragma unroll
  for (int jj = 0; jj < 32; ++jj) { float e = expf(accD[jj]); accD[jj] = e; ssum += e; }
  ssum += __shfl_xor(ssum, 1);
  ssum += __shfl_xor(ssum, 2);

  __syncthreads();  // done with K in LDS; reload V
  #pragma unroll
  for (int it = 0; it < 8; ++it) {
    int idx = t + it * 256;
    int j = idx >> 4, d4 = idx & 15;
    *reinterpret_cast<float4*>(&KVs[j][d4 * 4]) =
        *reinterpret_cast<const float4*>(vbase + (size_t)kposS[j] * DD + d4 * 4);
  }
  __syncthreads();

  const int n = c >> 6;
  const int sr = (c & 63) * 64 + i;
  const int sdst = kposS[64 + i];
  float* nrow = mode ? (numB + ((size_t)(bh * NHH + n) * SS + sr) * DD)
                     : (outA + ((size_t)(b * SS + sdst)) * (HH * DD) + h * DD);
  if (j0 == 0) {
    if (mode) denB[(size_t)(bh * NHH + n) * SS + sr] = ssum;
    else      atomicAdd(&denA[(size_t)bh * SS + sdst], ssum);
  }

  // PV: 4 passes over 16-d blocks; only 4 float4 accumulators live at a time
  #pragma unroll 1
  for (int db = 0; db < 4; ++db) {
    float4 a0 = make_float4(0.f, 0.f, 0.f, 0.f);
    float4 a1 = a0, a2 = a0, a3 = a0;
    #pragma unroll 4
    for (int jj = 0; jj < 32; ++jj) {
      const float p = accD[jj];
      const float* vr = &KVs[j0 + 4 * jj][db * 16];
      float4 v0 = *reinterpret_cast<const float4*>(vr + 0);
      float4 v1 = *reinterpret_cast<const float4*>(vr + 4);
      float4 v2 = *reinterpret_cast<const float4*>(vr + 8);
      float4 v3 = *reinterpret_cast<const float4*>(vr + 12);
      a0.x += p * v0.x; a0.y += p * v0.y; a0.z += p * v0.z; a0.w += p * v0.w;
      a1.x += p * v1.x; a1.y += p * v1.y; a1.z += p * v1.z; a1.w += p * v1.w;
      a2.x += p * v2.x; a2.y += p * v2.y; a2.z += p * v2.z; a2.w += p * v2.w;
      a3.x += p * v3.x; a3.y += p * v3.y; a3.z += p * v3.z; a3.w += p * v3.w;
    }
    a0.x += __shfl_xor(a0.x, 1); a0.x += __shfl_xor(a0.x, 2);
    a0.y += __shfl_xor(a0.y, 1); a0.y += __shfl_xor(a0.y, 2);
    a0.z += __shfl_xor(a0.z, 1); a0.z += __shfl_xor(a0.z, 2);
    a0.w += __shfl_xor(a0.w, 1); a0.w += __shfl_xor(a0.w, 2);
    a1.x += __shfl_xor(a1.x, 1); a1.x += __shfl_xor(a1.x, 2);
    a1.y += __shfl_xor(a1.y, 1); a1.y += __shfl_xor(a1.y, 2);
    a1.z += __shfl_xor(a1.z, 1); a1.z += __shfl_xor(a1.z, 2);
    a1.w += __shfl_xor(a1.w, 1); a1.w += __shfl_xor(a1.w, 2);
    a2.x += __shfl_xor(a2.x, 1); a2.x += __shfl_xor(a2.x, 2);
    a2.y += __shfl_xor(a2.y, 1); a2.y += __shfl_xor(a2.y, 2);
    a2.z += __shfl_xor(a2.z, 1); a2.z += __shfl_xor(a2.z, 2);
    a2.w += __shfl_xor(a2.w, 1); a2.w += __shfl_xor(a2.w, 2);
    a3.x += __shfl_xor(a3.x, 1); a3.x += __shfl_xor(a3.x, 2);
    a3.y += __shfl_xor(a3.y, 1); a3.y += __shfl_xor(a3.y, 2);
    a3.z += __shfl_xor(a3.z, 1); a3.z += __shfl_xor(a3.z, 2);
    a3.w += __shfl_xor(a3.w, 1); a3.w += __shfl_xor(a3.w, 2);
    float4 mine = (j0 == 0) ? a0 : (j0 == 1) ? a1 : (j0 == 2) ? a2 : a3;
    if (mode) {
      *reinterpret_cast<float4*>(nrow + db * 16 + j0 * 4) = mine;
    } else {
      float* p = nrow + db * 16 + j0 * 4;
      atomicAdd(&p[0], mine.x);
      atomicAdd(&p[1], mine.y);
      atomicAdd(&p[2], mine.z);
      atomicAdd(&p[3], mine.w);
    }
  }
}

// ---------------------------------------------------------------------------
// Kernel 5 (big-ws path): gather-combine.
// ---------------------------------------------------------------------------
__global__ __launch_bounds__(256) void k_combine(
    const float* __restrict__ numB, const float* __restrict__ denB,
    const int* __restrict__ sk_rank, float* __restrict__ outp)
{
  const int bh = blockIdx.y;
  const int s = blockIdx.x * 16 + (threadIdx.x >> 4);
  const int lane = threadIdx.x & 15;
  const int b = bh >> 3, h = bh & 7;
  float4 acc = make_float4(0.f, 0.f, 0.f, 0.f);
  float den = 0.f;
  #pragma unroll
  for (int n = 0; n < NHH; ++n) {
    int r = sk_rank[(size_t)bh * RANKS + n * SS + s];
    size_t rowi = (size_t)(bh * NHH + n) * SS + r;
    float4 v = *reinterpret_cast<const float4*>(numB + rowi * DD + lane * 4);
    acc.x += v.x; acc.y += v.y; acc.z += v.z; acc.w += v.w;
    den += denB[rowi];
  }
  float inv = 1.0f / den;
  acc.x *= inv; acc.y *= inv; acc.z *= inv; acc.w *= inv;
  *reinterpret_cast<float4*>(outp + ((size_t)(b * SS + s)) * (HH * DD) + h * DD + lane * 4) = acc;
}

// ---------------------------------------------------------------------------
// Kernel 5' (fallback path): divide accumulated numerator by denominator.
// ---------------------------------------------------------------------------
__global__ __launch_bounds__(256) void k_div(
    const float* __restrict__ den, float* __restrict__ outp)
{
  int idx = blockIdx.x * 256 + threadIdx.x;  // grid 4096 -> 1,048,576 float4
  int f = idx * 4;
  int col = f & 511;
  int h = col >> 6;
  int srow = f >> 9;                          // b*4096+s
  int b = srow >> 12, s = srow & 4095;
  float inv = 1.0f / den[(size_t)(b * HH + h) * SS + s];
  float4 v = *reinterpret_cast<float4*>(outp + (size_t)f);
  v.x *= inv; v.y *= inv; v.z *= inv; v.w *= inv;
  *reinterpret_cast<float4*>(outp + (size_t)f) = v;
}

// ---------------------------------------------------------------------------
// Kernel Z: zero the fp32 output (fallback path; harness poisons d_out).
// ---------------------------------------------------------------------------
__global__ __launch_bounds__(256) void k_zero_out(float* __restrict__ outp)
{
  int flat = blockIdx.x * 256 + threadIdx.x;  // grid 4096 -> 1,048,576 float4
  float4 z = make_float4(0.f, 0.f, 0.f, 0.f);
  *reinterpret_cast<float4*>(outp + (size_t)flat * 4) = z;
}

// ---------------------------------------------------------------------------
extern "C" void kernel_launch(void* const* d_in, const int* in_sizes, int n_in,
                              void* d_out, int out_size, void* d_ws, size_t ws_size,
                              hipStream_t stream)
{
  (void)in_sizes; (void)n_in; (void)out_size;
  const u32* dec = (const u32*)d_in[0];
  const u32* hid = (const u32*)d_in[1];
  const u32* wqk = (const u32*)d_in[2];
  const u32* wv  = (const u32*)d_in[3];
  const u32* rot = (const u32*)d_in[4];

  const size_t QKV  = (size_t)BB * HH * SS * DD;   // 4,194,304 elems
  const size_t LOGU = (size_t)BB * HH * NHH * SS;  // 262,144

  float* qb      = (float*)d_ws;
  float* kraw    = qb + QKV;
  float* vb      = kraw + QKV;
  float* den     = vb + QKV;                  // LOGU floats
  int*   sq_pos  = (int*)(den + LOGU);
  int*   sk_pos  = sq_pos + LOGU;
  int*   sk_rank = sk_pos + LOGU;
  u8*    buckets = (u8*)(sk_rank + LOGU);
  int*   flag    = (int*)(buckets + (size_t)2 * 64 * SS);
  const size_t numb_off = 55050496;           // align_up(low region, 256)
  float* numb    = (float*)((char*)d_ws + numb_off);
  // wt planes live INSIDE the numb region (numb not yet live during proj):
  unsigned short* wt0 = (unsigned short*)numb;
  unsigned short* wt1 = wt0 + (size_t)2 * 512 * 512;
  unsigned short* wt2 = wt1 + (size_t)2 * 512 * 512;
  const size_t need_big = numb_off + (size_t)NHH * QKV * sizeof(float);  // 122,159,360
  const int big = (ws_size >= need_big) ? 1 : 0;

  hipMemsetAsync(flag, 0, sizeof(int), stream);
  k_detect<<<dim3(512), 256, 0, stream>>>(wqk, flag);
  k_prep<<<dim3(256, 2), 256, 0, stream>>>(wqk, wv, flag, wt0, wt1, wt2);
  // q,k: scalar (hash-feeding, R0-R2-proven). v: MFMA.
  k_proj_s<<<dim3(128, 8, 2), 256, 0, stream>>>(dec, hid, wqk, wv, flag, qb, kraw, vb);
  k_proj_v<<<dim3(1024), 256, 0, stream>>>(hid, wt0, wt1, wt2, flag, vb);
  k_hash<<<dim3(64, 2, 4), 256, 0, stream>>>(qb, kraw, rot, flag, buckets);
  k_sort<<<dim3(64, 2), 256, 0, stream>>>(buckets, sq_pos, sk_pos, sk_rank);

  if (big) {
    k_attn<<<dim3(NCC, HH, BB), 256, 0, stream>>>(
        qb, kraw, vb, sq_pos, sk_pos, 1, nullptr, nullptr, numb, den);
    k_combine<<<dim3(SS / 16, BB * HH), 256, 0, stream>>>(
        numb, den, sk_rank, (float*)d_out);
  } else {
    hipMemsetAsync(den, 0, (size_t)BB * HH * SS * sizeof(float), stream);
    k_zero_out<<<dim3(4096), 256, 0, stream>>>((float*)d_out);
    k_attn<<<dim3(NCC, HH, BB), 256, 0, stream>>>(
        qb, kraw, vb, sq_pos, sk_pos, 0, (float*)d_out, den, nullptr, nullptr);
    k_div<<<dim3(4096), 256, 0, stream>>>(den, (float*)d_out);
  }
}

// Round 8
// 643.387 us; speedup vs baseline: 2.9908x; 1.0398x over previous
//
#include <hip/hip_runtime.h>
#include <math.h>

#define BB 2
#define SS 4096
#define HIDK 512
#define HH 8
#define DD 64
#define NHH 4
#define NCC 256      // chunks per (b,h) = NH*S/CHUNK
#define RANKS 16384  // NH*S

typedef unsigned int u32;
typedef unsigned char u8;
typedef __attribute__((ext_vector_type(8))) short bf16x8;
typedef __attribute__((ext_vector_type(4))) float f32x4;

__device__ __forceinline__ float bflo(u32 u){ return __uint_as_float(u << 16); }
__device__ __forceinline__ float bfhi(u32 u){ return __uint_as_float(u & 0xffff0000u); }

// RN fp32 -> bf16 (top of x)
__device__ __forceinline__ unsigned short brn(float x)
{
  u32 u = __float_as_uint(x);
  u32 r = u + 0x7FFFu + ((u >> 16) & 1u);
  return (unsigned short)(r >> 16);
}

// 3-term bf16 split: x ~= b0 + b1 + b2 (Sterbenz-exact residuals).
__device__ __forceinline__ void bsplit3(float x, unsigned short& b0, unsigned short& b1, unsigned short& b2)
{
  b0 = brn(x);
  float x1 = x - __uint_as_float((u32)b0 << 16);
  b1 = brn(x1);
  float x2 = x1 - __uint_as_float((u32)b1 << 16);
  b2 = brn(x2);
}

// ---------------------------------------------------------------------------
// Kernel 0: input dtype detection (bf16 vs fp32 bit patterns in w_qk).
// ---------------------------------------------------------------------------
__global__ __launch_bounds__(256) void k_detect(const u32* __restrict__ w, int* __restrict__ flag)
{
  int i = blockIdx.x * 256 + threadIdx.x;   // grid 512 -> 131072 u32
  float lo = bflo(w[i]);
  bool bad = !(fabsf(lo) <= 1024.0f);       // true also for NaN
  if (__any(bad)) {
    if ((threadIdx.x & 63) == 0) atomicOr(flag, 1);
  }
}

// ---------------------------------------------------------------------------
// Kernel P: prep weights. Transpose W[k][n] -> Wt[n][k], 3-term bf16 split
// for fp32 inputs. wt*: [2][512][512] u16 (plane 0 = wqk, 1 = wv).
// Only the wv plane is consumed (V-projection); wqk plane kept for symmetry.
// ---------------------------------------------------------------------------
__global__ __launch_bounds__(256) void k_prep(
    const u32* __restrict__ wqk, const u32* __restrict__ wv,
    const int* __restrict__ flag,
    unsigned short* __restrict__ wt0, unsigned short* __restrict__ wt1,
    unsigned short* __restrict__ wt2)
{
  const int which = blockIdx.y;
  const u32* W = which ? wv : wqk;
  const int tk = blockIdx.x >> 4, tn = blockIdx.x & 15;
  const int t = threadIdx.x;
  const int is32 = flag[0];
  __shared__ unsigned short h0s[32][36];
  __shared__ unsigned short h1s[32][36];
  __shared__ unsigned short h2s[32][36];
  if (is32) {
    const float* Wf = (const float*)W;
    #pragma unroll
    for (int it = 0; it < 4; ++it) {
      int idx = t + it * 256;           // 1024 = 32 k x 32 n
      int kk = idx >> 5, nn = idx & 31;
      float x = Wf[(size_t)(tk * 32 + kk) * 512 + tn * 32 + nn];
      bsplit3(x, h0s[kk][nn], h1s[kk][nn], h2s[kk][nn]);
    }
  } else {
    #pragma unroll
    for (int it = 0; it < 2; ++it) {
      int idx = t + it * 256;           // 512 u32 = 32 k x 16 pairs
      int kk = idx >> 4, np = idx & 15;
      u32 uv = W[(size_t)(tk * 32 + kk) * 256 + tn * 16 + np];
      h0s[kk][2 * np]     = (unsigned short)(uv & 0xffffu);
      h0s[kk][2 * np + 1] = (unsigned short)(uv >> 16);
      h1s[kk][2 * np] = 0; h1s[kk][2 * np + 1] = 0;
      h2s[kk][2 * np] = 0; h2s[kk][2 * np + 1] = 0;
    }
  }
  __syncthreads();
  size_t obase = ((size_t)which * 512 + tn * 32) * 512 + tk * 32;
  #pragma unroll
  for (int it = 0; it < 4; ++it) {
    int idx = t + it * 256;
    int nn = idx >> 5, kk = idx & 31;
    wt0[obase + (size_t)nn * 512 + kk] = h0s[kk][nn];
    wt1[obase + (size_t)nn * 512 + kk] = h1s[kk][nn];
    wt2[obase + (size_t)nn * 512 + kk] = h2s[kk][nn];
  }
}

// ---------------------------------------------------------------------------
// Kernel 1a: SCALAR projections for q and k (hash-feeding; R0-R2-proven).
// MUST keep per-output sequential-k fp32 FMA order (argmax-critical).
// ---------------------------------------------------------------------------
__global__ __launch_bounds__(256) void k_proj_s(
    const u32* __restrict__ dec, const u32* __restrict__ hid,
    const u32* __restrict__ wqk, const u32* __restrict__ wv,
    const int* __restrict__ flag,
    float* __restrict__ qb, float* __restrict__ kraw, float* __restrict__ vb)
{
  const int which = blockIdx.z;
  const u32* A = (which == 0) ? dec : hid;
  const u32* W = (which == 2) ? wv : wqk;
  const int m0 = blockIdx.x * 64;
  const int h  = blockIdx.y;
  const int t  = threadIdx.x;
  const int ty = t >> 4, tx = t & 15;
  const int is32 = flag[0];

  __shared__ float AsT[32][65];     // [kk][row i]
  __shared__ float Wst[32][4][16];  // [kk][c&3][c>>2] = W[kk][col c]

  float acc[4][4];
  #pragma unroll
  for (int r = 0; r < 4; ++r)
    #pragma unroll
    for (int c = 0; c < 4; ++c) acc[r][c] = 0.0f;

  for (int k0 = 0; k0 < HIDK; k0 += 32) {
    if (is32) {
      const float* Af = (const float*)A;
      const float* Wf = (const float*)W;
      #pragma unroll
      for (int it = 0; it < 8; ++it) {
        int idx = t + it * 256;          // 2048: 64 rows x 32 k
        int i = idx >> 5, kk = idx & 31;
        AsT[kk][i] = Af[(size_t)(m0 + i) * HIDK + k0 + kk];
      }
      #pragma unroll
      for (int it = 0; it < 8; ++it) {
        int idx = t + it * 256;          // 2048: 32 rows x 64 cols
        int kk = idx >> 6, c = idx & 63;
        Wst[kk][c & 3][c >> 2] = Wf[(size_t)(k0 + kk) * HIDK + h * 64 + c];
      }
    } else {
      #pragma unroll
      for (int it = 0; it < 4; ++it) {
        int idx = t + it * 256;          // 1024: A tile 64 rows x 16 u32
        int i = idx >> 4, kp = idx & 15;
        u32 uv = A[(size_t)(m0 + i) * (HIDK / 2) + (k0 >> 1) + kp];
        AsT[2 * kp][i]     = bflo(uv);
        AsT[2 * kp + 1][i] = bfhi(uv);
      }
      #pragma unroll
      for (int it = 0; it < 4; ++it) {
        int idx = t + it * 256;          // 1024: W tile 32 rows x 32 u32
        int kk = idx >> 5, cp = idx & 31;
        u32 uv = W[(size_t)(k0 + kk) * (HIDK / 2) + h * 32 + cp];
        int c0 = 2 * cp, c1 = 2 * cp + 1;
        Wst[kk][c0 & 3][c0 >> 2] = bflo(uv);
        Wst[kk][c1 & 3][c1 >> 2] = bfhi(uv);
      }
    }
    __syncthreads();
    for (int kk = 0; kk < 32; ++kk) {
      float a0 = AsT[kk][ty * 4 + 0];
      float a1 = AsT[kk][ty * 4 + 1];
      float a2 = AsT[kk][ty * 4 + 2];
      float a3 = AsT[kk][ty * 4 + 3];
      float w0 = Wst[kk][0][tx];
      float w1 = Wst[kk][1][tx];
      float w2 = Wst[kk][2][tx];
      float w3 = Wst[kk][3][tx];
      acc[0][0] += a0 * w0; acc[0][1] += a0 * w1; acc[0][2] += a0 * w2; acc[0][3] += a0 * w3;
      acc[1][0] += a1 * w0; acc[1][1] += a1 * w1; acc[1][2] += a1 * w2; acc[1][3] += a1 * w3;
      acc[2][0] += a2 * w0; acc[2][1] += a2 * w1; acc[2][2] += a2 * w2; acc[2][3] += a2 * w3;
      acc[3][0] += a3 * w0; acc[3][1] += a3 * w1; acc[3][2] += a3 * w2; acc[3][3] += a3 * w3;
    }
    __syncthreads();
  }

  float* outp = (which == 0) ? qb : ((which == 1) ? kraw : vb);
  #pragma unroll
  for (int r = 0; r < 4; ++r) {
    int m = m0 + ty * 4 + r;
    int b = m >> 12, s = m & 4095;
    float4 o;
    o.x = acc[r][0]; o.y = acc[r][1]; o.z = acc[r][2]; o.w = acc[r][3];
    *reinterpret_cast<float4*>(outp + ((size_t)((b * HH + h) * SS + s)) * DD + tx * 4) = o;
  }
}

// ---------------------------------------------------------------------------
// Kernel 1b: MFMA projection for V ONLY (v = hid @ wv).
// V feeds no argmax; small numerical differences are harmless (R7-proven).
// ---------------------------------------------------------------------------
__global__ __launch_bounds__(256) void k_proj_v(
    const u32* __restrict__ hid,
    const unsigned short* __restrict__ wt0, const unsigned short* __restrict__ wt1,
    const unsigned short* __restrict__ wt2,
    const int* __restrict__ flag,
    float* __restrict__ vb)
{
  const int bid = blockIdx.x;              // grid 1024 = 8 x 128
  const int x = bid & 7, l = bid >> 3;     // l in [0,128)
  const int h = l & 7;
  const int m0 = (x * 16 + ((l >> 3) & 15)) * 64;
  const int t = threadIdx.x;
  const int w = t >> 6;
  const int r = t & 15, g = (t & 63) >> 4;
  const int is32 = flag[0];

  const u32* A = hid;
  const size_t wbase = (size_t)1 * 512 * 512 + (size_t)h * 64 * 512;  // wv plane
  const unsigned short* W0 = wt0 + wbase;
  const unsigned short* W1 = wt1 + wbase;
  const unsigned short* W2 = wt2 + wbase;

  __shared__ __align__(16) unsigned short A0[64][40];  // stride 80B
  __shared__ __align__(16) unsigned short A1[64][40];
  __shared__ __align__(16) unsigned short A2[64][40];
  __shared__ __align__(16) unsigned short B0[64][40];
  __shared__ __align__(16) unsigned short B1[64][40];
  __shared__ __align__(16) unsigned short B2[64][40];

  f32x4 acc[4];
  #pragma unroll
  for (int tn = 0; tn < 4; ++tn) { acc[tn][0] = 0.f; acc[tn][1] = 0.f; acc[tn][2] = 0.f; acc[tn][3] = 0.f; }

  for (int k0 = 0; k0 < HIDK; k0 += 32) {
    {
      const int n = t >> 2, kq = t & 3;
      *reinterpret_cast<uint4*>(&B0[n][kq * 8]) =
          *reinterpret_cast<const uint4*>(W0 + (size_t)n * 512 + k0 + kq * 8);
      if (is32) {
        *reinterpret_cast<uint4*>(&B1[n][kq * 8]) =
            *reinterpret_cast<const uint4*>(W1 + (size_t)n * 512 + k0 + kq * 8);
        *reinterpret_cast<uint4*>(&B2[n][kq * 8]) =
            *reinterpret_cast<const uint4*>(W2 + (size_t)n * 512 + k0 + kq * 8);
      }
    }
    if (is32) {
      const float* Af = (const float*)A;
      #pragma unroll
      for (int it = 0; it < 2; ++it) {
        int idx = t + it * 256;
        int m = idx >> 3, kq = idx & 7;
        float4 a4 = *reinterpret_cast<const float4*>(Af + (size_t)(m0 + m) * HIDK + k0 + kq * 4);
        ushort4 p0, p1, p2;
        bsplit3(a4.x, p0.x, p1.x, p2.x);
        bsplit3(a4.y, p0.y, p1.y, p2.y);
        bsplit3(a4.z, p0.z, p1.z, p2.z);
        bsplit3(a4.w, p0.w, p1.w, p2.w);
        *reinterpret_cast<ushort4*>(&A0[m][kq * 4]) = p0;
        *reinterpret_cast<ushort4*>(&A1[m][kq * 4]) = p1;
        *reinterpret_cast<ushort4*>(&A2[m][kq * 4]) = p2;
      }
    } else {
      #pragma unroll
      for (int it = 0; it < 2; ++it) {
        int idx = t + it * 256;
        int m = idx >> 3, kq = idx & 7;
        uint2 uv = *reinterpret_cast<const uint2*>(A + (size_t)(m0 + m) * (HIDK / 2) + (k0 >> 1) + kq * 2);
        *reinterpret_cast<uint2*>(&A0[m][kq * 4]) = uv;
      }
    }
    __syncthreads();

    bf16x8 a0 = *reinterpret_cast<const bf16x8*>(&A0[w * 16 + r][g * 8]);
    if (is32) {
      bf16x8 a1 = *reinterpret_cast<const bf16x8*>(&A1[w * 16 + r][g * 8]);
      bf16x8 a2 = *reinterpret_cast<const bf16x8*>(&A2[w * 16 + r][g * 8]);
      #pragma unroll
      for (int tn = 0; tn < 4; ++tn) {
        bf16x8 b0 = *reinterpret_cast<const bf16x8*>(&B0[tn * 16 + r][g * 8]);
        bf16x8 b1 = *reinterpret_cast<const bf16x8*>(&B1[tn * 16 + r][g * 8]);
        bf16x8 b2 = *reinterpret_cast<const bf16x8*>(&B2[tn * 16 + r][g * 8]);
        acc[tn] = __builtin_amdgcn_mfma_f32_16x16x32_bf16(a0, b0, acc[tn], 0, 0, 0);
        acc[tn] = __builtin_amdgcn_mfma_f32_16x16x32_bf16(a0, b1, acc[tn], 0, 0, 0);
        acc[tn] = __builtin_amdgcn_mfma_f32_16x16x32_bf16(a1, b0, acc[tn], 0, 0, 0);
        acc[tn] = __builtin_amdgcn_mfma_f32_16x16x32_bf16(a0, b2, acc[tn], 0, 0, 0);
        acc[tn] = __builtin_amdgcn_mfma_f32_16x16x32_bf16(a2, b0, acc[tn], 0, 0, 0);
        acc[tn] = __builtin_amdgcn_mfma_f32_16x16x32_bf16(a1, b1, acc[tn], 0, 0, 0);
      }
    } else {
      #pragma unroll
      for (int tn = 0; tn < 4; ++tn) {
        bf16x8 b0 = *reinterpret_cast<const bf16x8*>(&B0[tn * 16 + r][g * 8]);
        acc[tn] = __builtin_amdgcn_mfma_f32_16x16x32_bf16(a0, b0, acc[tn], 0, 0, 0);
      }
    }
    __syncthreads();
  }

  #pragma unroll
  for (int tn = 0; tn < 4; ++tn)
    #pragma unroll
    for (int rg = 0; rg < 4; ++rg) {
      int m = m0 + w * 16 + g * 4 + rg;
      int b = m >> 12, s = m & 4095;
      vb[((size_t)((b * HH + h) * SS + s)) * DD + tn * 16 + r] = acc[tn][rg];
    }
}

// ---------------------------------------------------------------------------
// Kernel 2: LSH hash. rotS now [64][64] (no pad: reads are broadcast, never
// conflict) so rotS rows are 16B-aligned -> float4 ds_read_b128 (4x fewer
// LDS instrs). Numerically identical: same values, same per-acc d-order.
// ---------------------------------------------------------------------------
__global__ __launch_bounds__(256) void k_hash(
    const float* __restrict__ qb, const float* __restrict__ kraw,
    const u32* __restrict__ rots, const int* __restrict__ flag,
    u8* __restrict__ bucketOut)
{
  const int bhn = blockIdx.x;       // 0..63 : (b*8+h)*4+n
  const int which = blockIdx.y;     // 0=q 1=k
  const int squarter = blockIdx.z;  // 0..3
  const int t = threadIdx.x;
  const int bh = bhn >> 2;
  const int h  = bh & 7;
  const int n  = bhn & 3;
  const int is32 = flag[0];

  __shared__ __align__(16) float rotS[64][64];   // [d][r], 16 KB
  if (is32) {
    const float* rf = (const float*)rots;
    #pragma unroll
    for (int it = 0; it < 16; ++it) {
      int idx = t + it * 256;       // 4096 floats
      int d = idx >> 6, r = idx & 63;
      rotS[d][r] = rf[((size_t)((h * 64 + d) * 4 + n)) * 64 + r];
    }
  } else {
    #pragma unroll
    for (int it = 0; it < 8; ++it) {
      int idx = t + it * 256;       // 2048 u32 (4096 bf16)
      int d = idx >> 5, rp = idx & 31;
      u32 uv = rots[((size_t)((h * 64 + d) * 4 + n)) * 32 + rp];
      rotS[d][2 * rp]     = bflo(uv);
      rotS[d][2 * rp + 1] = bfhi(uv);
    }
  }
  __syncthreads();

  const float* src = ((which == 0) ? qb : kraw) + (size_t)bh * SS * DD;
  u8* bout = bucketOut + ((size_t)(which * 64 + bhn)) * SS;

  for (int ii = 0; ii < 4; ++ii) {
    int s = squarter * 1024 + ii * 256 + t;
    const float* row = src + (size_t)s * DD;
    float vec[64];
    #pragma unroll
    for (int d4 = 0; d4 < 16; ++d4) {
      float4 v4 = *reinterpret_cast<const float4*>(row + d4 * 4);
      vec[d4 * 4 + 0] = v4.x; vec[d4 * 4 + 1] = v4.y;
      vec[d4 * 4 + 2] = v4.z; vec[d4 * 4 + 3] = v4.w;
    }
    float bestP = -1e30f, bestN = -1e30f;
    int idxP = 0, idxN = 0;
    #pragma unroll 1
    for (int r0 = 0; r0 < 64; r0 += 16) {
      float acc[16];
      #pragma unroll
      for (int rr = 0; rr < 16; ++rr) acc[rr] = 0.0f;
      #pragma unroll
      for (int d = 0; d < 64; ++d) {
        float vd = vec[d];
        #pragma unroll
        for (int q4 = 0; q4 < 4; ++q4) {
          float4 rv4 = *reinterpret_cast<const float4*>(&rotS[d][r0 + q4 * 4]);
          acc[q4 * 4 + 0] += vd * rv4.x;
          acc[q4 * 4 + 1] += vd * rv4.y;
          acc[q4 * 4 + 2] += vd * rv4.z;
          acc[q4 * 4 + 3] += vd * rv4.w;
        }
      }
      #pragma unroll
      for (int rr = 0; rr < 16; ++rr) {
        float a = acc[rr];
        int r = r0 + rr;
        if (a > bestP) { bestP = a; idxP = r; }
        if (-a > bestN) { bestN = -a; idxN = r; }
      }
    }
    int bucket = (bestP >= bestN) ? idxP : (64 + idxN);
    bout[s] = (u8)bucket;
  }
}

// ---------------------------------------------------------------------------
// Kernel 3: PARALLEL stable counting sort per (b,h,round,which).
// ---------------------------------------------------------------------------
__global__ __launch_bounds__(256) void k_sort(
    const u8* __restrict__ bucketIn, int* __restrict__ sq_pos,
    int* __restrict__ sk_pos, int* __restrict__ sk_rank)
{
  const int bhn = blockIdx.x, which = blockIdx.y;
  const int t = threadIdx.x;
  const int bh = bhn >> 2, n = bhn & 3;
  const int lane = t & 63, w = t >> 6;

  __shared__ u8 bk[4096];
  __shared__ u8 rk[4096];
  __shared__ int chunkh[64 * 128];   // [chunk][bin], 32 KB
  __shared__ int hist[128];
  __shared__ int scanS[128];

  const u8* bin = bucketIn + ((size_t)(which * 64 + bhn)) * SS;
  #pragma unroll
  for (int it = 0; it < 4; ++it)
    ((u32*)bk)[t + it * 256] = ((const u32*)bin)[t + it * 256];
  #pragma unroll
  for (int it = 0; it < 32; ++it) chunkh[t + it * 256] = 0;
  if (t < 128) hist[t] = 0;
  __syncthreads();

  const unsigned long long below = (lane == 0) ? 0ull : (~0ull >> (64 - lane));
  #pragma unroll 1
  for (int k = 0; k < 16; ++k) {
    const int c = w * 16 + k;
    const int s = c * 64 + lane;
    const int b = bk[s];
    unsigned long long m = ~0ull;
    #pragma unroll
    for (int bit = 0; bit < 7; ++bit) {
      unsigned long long vote = __ballot((b >> bit) & 1);
      m &= ((b >> bit) & 1) ? vote : ~vote;
    }
    const int r = (int)__popcll(m & below);
    rk[s] = (u8)r;
    if (r == 0) {
      const int cnt = (int)__popcll(m);
      chunkh[c * 128 + b] = cnt;
      atomicAdd(&hist[b], cnt);
    }
  }
  __syncthreads();

  if (t < 128) scanS[t] = hist[t];
  __syncthreads();
  for (int off = 1; off < 128; off <<= 1) {
    int add = 0;
    if (t < 128 && t >= off) add = scanS[t - off];
    __syncthreads();
    if (t < 128) scanS[t] += add;
    __syncthreads();
  }
  if (t < 128) {
    int run = scanS[t] - hist[t];    // global bin start
    #pragma unroll 1
    for (int c = 0; c < 64; ++c) {
      int v = chunkh[c * 128 + t];
      chunkh[c * 128 + t] = run;
      run += v;
    }
  }
  __syncthreads();

  int* outp = ((which == 0) ? sq_pos : sk_pos) + (size_t)bh * RANKS + n * SS;
  int* rnkp = sk_rank + (size_t)bh * RANKS + n * SS;
  #pragma unroll 1
  for (int k = 0; k < 16; ++k) {
    const int c = w * 16 + k;
    const int s = c * 64 + lane;
    const int b = bk[s];
    const int pos = chunkh[c * 128 + b] + (int)rk[s];
    outp[pos] = s;
    if (which) rnkp[s] = pos;
  }
}

// ---------------------------------------------------------------------------
// Kernel 4: single attention pass, 2 q-rows per thread (exonerated by R5/R6
// bisect: identical failure signature with/without it => not at fault).
// 8 lanes per row-pair, 16 keys each: each KVs float4 read feeds 8 FMAs.
// ---------------------------------------------------------------------------
__global__ __launch_bounds__(256) void k_attn(
    const float* __restrict__ qb, const float* __restrict__ kraw,
    const float* __restrict__ vb,
    const int* __restrict__ sq_pos, const int* __restrict__ sk_pos,
    const int mode,
    float* __restrict__ outA, float* __restrict__ denA,
    float* __restrict__ numB, float* __restrict__ denB)
{
  const int c = blockIdx.x;
  const int h = blockIdx.y, b = blockIdx.z;
  const int bh = b * HH + h;
  const int t = threadIdx.x;
  const int cprev = (c + NCC - 1) & (NCC - 1);

  __shared__ float Qs[64][68];
  __shared__ float KVs[128][68];
  __shared__ float sc[128];
  __shared__ int kposS[128], mposS[128];

  if (t < 128) {
    int slot = (t < 64) ? (cprev * 64 + t) : (c * 64 + (t - 64));
    kposS[t] = sk_pos[(size_t)bh * RANKS + slot];
    mposS[t] = sq_pos[(size_t)bh * RANKS + slot];
  }
  __syncthreads();

  const float* qbase = qb + (size_t)bh * SS * DD;
  const float* kbase = kraw + (size_t)bh * SS * DD;
  const float* vbase = vb + (size_t)bh * SS * DD;

  #pragma unroll
  for (int it = 0; it < 4; ++it) {
    int idx = t + it * 256;
    int i = idx >> 4, d4 = idx & 15;
    *reinterpret_cast<float4*>(&Qs[i][d4 * 4]) =
        *reinterpret_cast<const float4*>(qbase + (size_t)mposS[64 + i] * DD + d4 * 4);
  }
  #pragma unroll
  for (int it = 0; it < 8; ++it) {
    int idx = t + it * 256;
    int j = idx >> 4, d4 = idx & 15;
    *reinterpret_cast<float4*>(&KVs[j][d4 * 4]) =
        *reinterpret_cast<const float4*>(kbase + (size_t)kposS[j] * DD + d4 * 4);
  }
  __syncthreads();
  if (t < 128) {
    float ms = 0.f;
    #pragma unroll
    for (int d4 = 0; d4 < 16; ++d4) {
      float4 x4 = *reinterpret_cast<float4*>(&KVs[t][d4 * 4]);
      ms += x4.x * x4.x + x4.y * x4.y + x4.z * x4.z + x4.w * x4.w;
    }
    sc[t] = 0.125f / sqrtf(ms * (1.0f / 64.0f) + 1e-6f);
  }
  __syncthreads();
  #pragma unroll
  for (int it = 0; it < 8; ++it) {
    int idx = t + it * 256;
    int j = idx >> 4, d4 = idx & 15;
    float s_ = sc[j];
    float4 v4 = *reinterpret_cast<float4*>(&KVs[j][d4 * 4]);
    v4.x *= s_; v4.y *= s_; v4.z *= s_; v4.w *= s_;
    *reinterpret_cast<float4*>(&KVs[j][d4 * 4]) = v4;
  }
  __syncthreads();

  const int i2 = t >> 3;            // row pair 0..31
  const int qr = i2 * 2;
  const int j0 = t & 7;             // key lane 0..7 (keys j0 + 8*jj)
  const int qpa = mposS[64 + qr];
  const int qpb = mposS[64 + qr + 1];

  float accA[16], accB[16];
  #pragma unroll
  for (int jj = 0; jj < 16; ++jj) { accA[jj] = 0.f; accB[jj] = 0.f; }
  #pragma unroll 2
  for (int d0 = 0; d0 < 16; ++d0) {
    float4 qa = *reinterpret_cast<const float4*>(&Qs[qr][d0 * 4]);
    float4 qb_ = *reinterpret_cast<const float4*>(&Qs[qr + 1][d0 * 4]);
    #pragma unroll
    for (int jj = 0; jj < 16; ++jj) {
      float4 k4 = *reinterpret_cast<const float4*>(&KVs[j0 + 8 * jj][d0 * 4]);
      accA[jj] += qa.x * k4.x + qa.y * k4.y + qa.z * k4.z + qa.w * k4.w;
      accB[jj] += qb_.x * k4.x + qb_.y * k4.y + qb_.z * k4.z + qb_.w * k4.w;
    }
  }
  #pragma unroll
  for (int jj = 0; jj < 16; ++jj) {
    int mp = mposS[j0 + 8 * jj];
    if (mp == qpa) accA[jj] = -100000.0f;
    if (mp == qpb) accB[jj] = -100000.0f;
  }
  // un-normalized exp(dot); masked -> expf(-1e5) == 0
  float sa = 0.f, sb = 0.f;
  #pragma unroll
  for (int jj = 0; jj < 16; ++jj) {
    float ea = expf(accA[jj]); accA[jj] = ea; sa += ea;
    float eb = expf(accB[jj]); accB[jj] = eb; sb += eb;
  }
  sa += __shfl_xor(sa, 1); sa += __shfl_xor(sa, 2); sa += __shfl_xor(sa, 4);
  sb += __shfl_xor(sb, 1); sb += __shfl_xor(sb, 2); sb += __shfl_xor(sb, 4);

  const int n = c >> 6;
  if (j0 == 0) {
    if (mode) {
      denB[(size_t)(bh * NHH + n) * SS + (c & 63) * 64 + qr]     = sa;
      denB[(size_t)(bh * NHH + n) * SS + (c & 63) * 64 + qr + 1] = sb;
    } else {
      atomicAdd(&denA[(size_t)bh * SS + kposS[64 + qr]], sa);
      atomicAdd(&denA[(size_t)bh * SS + kposS[64 + qr + 1]], sb);
    }
  }

  __syncthreads();  // done with K in LDS; reload V
  #pragma unroll
  for (int it = 0; it < 8; ++it) {
    int idx = t + it * 256;
    int j = idx >> 4, d4 = idx & 15;
    *reinterpret_cast<float4*>(&KVs[j][d4 * 4]) =
        *reinterpret_cast<const float4*>(vbase + (size_t)kposS[j] * DD + d4 * 4);
  }
  __syncthreads();

  // this lane writes row qr + (j0>>2), d-chunk (j0&3)
  const int row = qr + (j0 >> 2);
  float* nrow = mode ? (numB + ((size_t)(bh * NHH + n) * SS + (c & 63) * 64 + row) * DD)
                     : (outA + ((size_t)(b * SS + kposS[64 + row])) * (HH * DD) + h * DD);

  #pragma unroll 1
  for (int db = 0; db < 4; ++db) {
    float4 aA0 = make_float4(0.f, 0.f, 0.f, 0.f);
    float4 aA1 = aA0, aA2 = aA0, aA3 = aA0;
    float4 aB0 = aA0, aB1 = aA0, aB2 = aA0, aB3 = aA0;
    #pragma unroll 4
    for (int jj = 0; jj < 16; ++jj) {
      const float pa = accA[jj];
      const float pb = accB[jj];
      const float* vr = &KVs[j0 + 8 * jj][db * 16];
      float4 v0 = *reinterpret_cast<const float4*>(vr + 0);
      float4 v1 = *reinterpret_cast<const float4*>(vr + 4);
      float4 v2 = *reinterpret_cast<const float4*>(vr + 8);
      float4 v3 = *reinterpret_cast<const float4*>(vr + 12);
      aA0.x += pa * v0.x; aA0.y += pa * v0.y; aA0.z += pa * v0.z; aA0.w += pa * v0.w;
      aA1.x += pa * v1.x; aA1.y += pa * v1.y; aA1.z += pa * v1.z; aA1.w += pa * v1.w;
      aA2.x += pa * v2.x; aA2.y += pa * v2.y; aA2.z += pa * v2.z; aA2.w += pa * v2.w;
      aA3.x += pa * v3.x; aA3.y += pa * v3.y; aA3.z += pa * v3.z; aA3.w += pa * v3.w;
      aB0.x += pb * v0.x; aB0.y += pb * v0.y; aB0.z += pb * v0.z; aB0.w += pb * v0.w;
      aB1.x += pb * v1.x; aB1.y += pb * v1.y; aB1.z += pb * v1.z; aB1.w += pb * v1.w;
      aB2.x += pb * v2.x; aB2.y += pb * v2.y; aB2.z += pb * v2.z; aB2.w += pb * v2.w;
      aB3.x += pb * v3.x; aB3.y += pb * v3.y; aB3.z += pb * v3.z; aB3.w += pb * v3.w;
    }
    #pragma unroll
    for (int st = 1; st <= 4; st <<= 1) {
      aA0.x += __shfl_xor(aA0.x, st); aA0.y += __shfl_xor(aA0.y, st);
      aA0.z += __shfl_xor(aA0.z, st); aA0.w += __shfl_xor(aA0.w, st);
      aA1.x += __shfl_xor(aA1.x, st); aA1.y += __shfl_xor(aA1.y, st);
      aA1.z += __shfl_xor(aA1.z, st); aA1.w += __shfl_xor(aA1.w, st);
      aA2.x += __shfl_xor(aA2.x, st); aA2.y += __shfl_xor(aA2.y, st);
      aA2.z += __shfl_xor(aA2.z, st); aA2.w += __shfl_xor(aA2.w, st);
      aA3.x += __shfl_xor(aA3.x, st); aA3.y += __shfl_xor(aA3.y, st);
      aA3.z += __shfl_xor(aA3.z, st); aA3.w += __shfl_xor(aA3.w, st);
      aB0.x += __shfl_xor(aB0.x, st); aB0.y += __shfl_xor(aB0.y, st);
      aB0.z += __shfl_xor(aB0.z, st); aB0.w += __shfl_xor(aB0.w, st);
      aB1.x += __shfl_xor(aB1.x, st); aB1.y += __shfl_xor(aB1.y, st);
      aB1.z += __shfl_xor(aB1.z, st); aB1.w += __shfl_xor(aB1.w, st);
      aB2.x += __shfl_xor(aB2.x, st); aB2.y += __shfl_xor(aB2.y, st);
      aB2.z += __shfl_xor(aB2.z, st); aB2.w += __shfl_xor(aB2.w, st);
      aB3.x += __shfl_xor(aB3.x, st); aB3.y += __shfl_xor(aB3.y, st);
      aB3.z += __shfl_xor(aB3.z, st); aB3.w += __shfl_xor(aB3.w, st);
    }
    // static selection (no runtime-indexed register arrays)
    float4 m0_ = (j0 & 4) ? aB0 : aA0;
    float4 m1_ = (j0 & 4) ? aB1 : aA1;
    float4 m2_ = (j0 & 4) ? aB2 : aA2;
    float4 m3_ = (j0 & 4) ? aB3 : aA3;
    float4 mine = (j0 & 2) ? ((j0 & 1) ? m3_ : m2_) : ((j0 & 1) ? m1_ : m0_);
    if (mode) {
      *reinterpret_cast<float4*>(nrow + db * 16 + (j0 & 3) * 4) = mine;
    } else {
      float* p = nrow + db * 16 + (j0 & 3) * 4;
      atomicAdd(&p[0], mine.x);
      atomicAdd(&p[1], mine.y);
      atomicAdd(&p[2], mine.z);
      atomicAdd(&p[3], mine.w);
    }
  }
}

// ---------------------------------------------------------------------------
// Kernel 5 (big-ws path): gather-combine.
// ---------------------------------------------------------------------------
__global__ __launch_bounds__(256) void k_combine(
    const float* __restrict__ numB, const float* __restrict__ denB,
    const int* __restrict__ sk_rank, float* __restrict__ outp)
{
  const int bh = blockIdx.y;
  const int s = blockIdx.x * 16 + (threadIdx.x >> 4);
  const int lane = threadIdx.x & 15;
  const int b = bh >> 3, h = bh & 7;
  float4 acc = make_float4(0.f, 0.f, 0.f, 0.f);
  float den = 0.f;
  #pragma unroll
  for (int n = 0; n < NHH; ++n) {
    int r = sk_rank[(size_t)bh * RANKS + n * SS + s];
    size_t rowi = (size_t)(bh * NHH + n) * SS + r;
    float4 v = *reinterpret_cast<const float4*>(numB + rowi * DD + lane * 4);
    acc.x += v.x; acc.y += v.y; acc.z += v.z; acc.w += v.w;
    den += denB[rowi];
  }
  float inv = 1.0f / den;
  acc.x *= inv; acc.y *= inv; acc.z *= inv; acc.w *= inv;
  *reinterpret_cast<float4*>(outp + ((size_t)(b * SS + s)) * (HH * DD) + h * DD + lane * 4) = acc;
}

// ---------------------------------------------------------------------------
// Kernel 5' (fallback path): divide accumulated numerator by denominator.
// ---------------------------------------------------------------------------
__global__ __launch_bounds__(256) void k_div(
    const float* __restrict__ den, float* __restrict__ outp)
{
  int idx = blockIdx.x * 256 + threadIdx.x;  // grid 4096 -> 1,048,576 float4
  int f = idx * 4;
  int col = f & 511;
  int h = col >> 6;
  int srow = f >> 9;                          // b*4096+s
  int b = srow >> 12, s = srow & 4095;
  float inv = 1.0f / den[(size_t)(b * HH + h) * SS + s];
  float4 v = *reinterpret_cast<float4*>(outp + (size_t)f);
  v.x *= inv; v.y *= inv; v.z *= inv; v.w *= inv;
  *reinterpret_cast<float4*>(outp + (size_t)f) = v;
}

// ---------------------------------------------------------------------------
// Kernel Z: zero the fp32 output (fallback path; harness poisons d_out).
// ---------------------------------------------------------------------------
__global__ __launch_bounds__(256) void k_zero_out(float* __restrict__ outp)
{
  int flat = blockIdx.x * 256 + threadIdx.x;  // grid 4096 -> 1,048,576 float4
  float4 z = make_float4(0.f, 0.f, 0.f, 0.f);
  *reinterpret_cast<float4*>(outp + (size_t)flat * 4) = z;
}

// ---------------------------------------------------------------------------
extern "C" void kernel_launch(void* const* d_in, const int* in_sizes, int n_in,
                              void* d_out, int out_size, void* d_ws, size_t ws_size,
                              hipStream_t stream)
{
  (void)in_sizes; (void)n_in; (void)out_size;
  const u32* dec = (const u32*)d_in[0];
  const u32* hid = (const u32*)d_in[1];
  const u32* wqk = (const u32*)d_in[2];
  const u32* wv  = (const u32*)d_in[3];
  const u32* rot = (const u32*)d_in[4];

  const size_t QKV  = (size_t)BB * HH * SS * DD;   // 4,194,304 elems
  const size_t LOGU = (size_t)BB * HH * NHH * SS;  // 262,144

  float* qb      = (float*)d_ws;
  float* kraw    = qb + QKV;
  float* vb      = kraw + QKV;
  float* den     = vb + QKV;                  // LOGU floats
  int*   sq_pos  = (int*)(den + LOGU);
  int*   sk_pos  = sq_pos + LOGU;
  int*   sk_rank = sk_pos + LOGU;
  u8*    buckets = (u8*)(sk_rank + LOGU);
  int*   flag    = (int*)(buckets + (size_t)2 * 64 * SS);
  const size_t numb_off = 55050496;           // align_up(low region, 256)
  float* numb    = (float*)((char*)d_ws + numb_off);
  // wt planes live INSIDE the numb region (numb not yet live during proj):
  unsigned short* wt0 = (unsigned short*)numb;
  unsigned short* wt1 = wt0 + (size_t)2 * 512 * 512;
  unsigned short* wt2 = wt1 + (size_t)2 * 512 * 512;
  const size_t need_big = numb_off + (size_t)NHH * QKV * sizeof(float);  // 122,159,360
  const int big = (ws_size >= need_big) ? 1 : 0;

  hipMemsetAsync(flag, 0, sizeof(int), stream);
  k_detect<<<dim3(512), 256, 0, stream>>>(wqk, flag);
  k_prep<<<dim3(256, 2), 256, 0, stream>>>(wqk, wv, flag, wt0, wt1, wt2);
  // q,k: scalar (hash-feeding, R0-R2-proven). v: MFMA (R7-proven).
  k_proj_s<<<dim3(128, 8, 2), 256, 0, stream>>>(dec, hid, wqk, wv, flag, qb, kraw, vb);
  k_proj_v<<<dim3(1024), 256, 0, stream>>>(hid, wt0, wt1, wt2, flag, vb);
  k_hash<<<dim3(64, 2, 4), 256, 0, stream>>>(qb, kraw, rot, flag, buckets);
  k_sort<<<dim3(64, 2), 256, 0, stream>>>(buckets, sq_pos, sk_pos, sk_rank);

  if (big) {
    k_attn<<<dim3(NCC, HH, BB), 256, 0, stream>>>(
        qb, kraw, vb, sq_pos, sk_pos, 1, nullptr, nullptr, numb, den);
    k_combine<<<dim3(SS / 16, BB * HH), 256, 0, stream>>>(
        numb, den, sk_rank, (float*)d_out);
  } else {
    hipMemsetAsync(den, 0, (size_t)BB * HH * SS * sizeof(float), stream);
    k_zero_out<<<dim3(4096), 256, 0, stream>>>((float*)d_out);
    k_attn<<<dim3(NCC, HH, BB), 256, 0, stream>>>(
        qb, kraw, vb, sq_pos, sk_pos, 0, (float*)d_out, den, nullptr, nullptr);
    k_div<<<dim3(4096), 256, 0, stream>>>(den, (float*)d_out);
  }
}

// Round 9
// 636.135 us; speedup vs baseline: 3.0249x; 1.0114x over previous
//
#include <hip/hip_runtime.h>
#include <math.h>

#define BB 2
#define SS 4096
#define HIDK 512
#define HH 8
#define DD 64
#define NHH 4
#define NCC 256      // chunks per (b,h) = NH*S/CHUNK
#define RANKS 16384  // NH*S

typedef unsigned int u32;
typedef unsigned char u8;
typedef __attribute__((ext_vector_type(8))) short bf16x8;
typedef __attribute__((ext_vector_type(4))) float f32x4;

__device__ __forceinline__ float bflo(u32 u){ return __uint_as_float(u << 16); }
__device__ __forceinline__ float bfhi(u32 u){ return __uint_as_float(u & 0xffff0000u); }

// RN fp32 -> bf16 (top of x)
__device__ __forceinline__ unsigned short brn(float x)
{
  u32 u = __float_as_uint(x);
  u32 r = u + 0x7FFFu + ((u >> 16) & 1u);
  return (unsigned short)(r >> 16);
}

// 3-term bf16 split: x ~= b0 + b1 + b2 (Sterbenz-exact residuals).
__device__ __forceinline__ void bsplit3(float x, unsigned short& b0, unsigned short& b1, unsigned short& b2)
{
  b0 = brn(x);
  float x1 = x - __uint_as_float((u32)b0 << 16);
  b1 = brn(x1);
  float x2 = x1 - __uint_as_float((u32)b1 << 16);
  b2 = brn(x2);
}

// ---------------------------------------------------------------------------
// Kernel 0: input dtype detection (bf16 vs fp32 bit patterns in w_qk).
// ---------------------------------------------------------------------------
__global__ __launch_bounds__(256) void k_detect(const u32* __restrict__ w, int* __restrict__ flag)
{
  int i = blockIdx.x * 256 + threadIdx.x;   // grid 512 -> 131072 u32
  float lo = bflo(w[i]);
  bool bad = !(fabsf(lo) <= 1024.0f);       // true also for NaN
  if (__any(bad)) {
    if ((threadIdx.x & 63) == 0) atomicOr(flag, 1);
  }
}

// ---------------------------------------------------------------------------
// Kernel P: prep weights. Transpose W[k][n] -> Wt[n][k], 3-term bf16 split
// for fp32 inputs. wt*: [2][512][512] u16 (plane 0 = wqk, 1 = wv).
// ---------------------------------------------------------------------------
__global__ __launch_bounds__(256) void k_prep(
    const u32* __restrict__ wqk, const u32* __restrict__ wv,
    const int* __restrict__ flag,
    unsigned short* __restrict__ wt0, unsigned short* __restrict__ wt1,
    unsigned short* __restrict__ wt2)
{
  const int which = blockIdx.y;
  const u32* W = which ? wv : wqk;
  const int tk = blockIdx.x >> 4, tn = blockIdx.x & 15;
  const int t = threadIdx.x;
  const int is32 = flag[0];
  __shared__ unsigned short h0s[32][36];
  __shared__ unsigned short h1s[32][36];
  __shared__ unsigned short h2s[32][36];
  if (is32) {
    const float* Wf = (const float*)W;
    #pragma unroll
    for (int it = 0; it < 4; ++it) {
      int idx = t + it * 256;           // 1024 = 32 k x 32 n
      int kk = idx >> 5, nn = idx & 31;
      float x = Wf[(size_t)(tk * 32 + kk) * 512 + tn * 32 + nn];
      bsplit3(x, h0s[kk][nn], h1s[kk][nn], h2s[kk][nn]);
    }
  } else {
    #pragma unroll
    for (int it = 0; it < 2; ++it) {
      int idx = t + it * 256;           // 512 u32 = 32 k x 16 pairs
      int kk = idx >> 4, np = idx & 15;
      u32 uv = W[(size_t)(tk * 32 + kk) * 256 + tn * 16 + np];
      h0s[kk][2 * np]     = (unsigned short)(uv & 0xffffu);
      h0s[kk][2 * np + 1] = (unsigned short)(uv >> 16);
      h1s[kk][2 * np] = 0; h1s[kk][2 * np + 1] = 0;
      h2s[kk][2 * np] = 0; h2s[kk][2 * np + 1] = 0;
    }
  }
  __syncthreads();
  size_t obase = ((size_t)which * 512 + tn * 32) * 512 + tk * 32;
  #pragma unroll
  for (int it = 0; it < 4; ++it) {
    int idx = t + it * 256;
    int nn = idx >> 5, kk = idx & 31;
    wt0[obase + (size_t)nn * 512 + kk] = h0s[kk][nn];
    wt1[obase + (size_t)nn * 512 + kk] = h1s[kk][nn];
    wt2[obase + (size_t)nn * 512 + kk] = h2s[kk][nn];
  }
}

// ---------------------------------------------------------------------------
// Kernel 1a: SCALAR projections for q and k (hash-feeding).
// Accumulation is bit-identical to the R0-R2/R7/R8-proven kernel: per output,
// one fp32 fmac per k, k = 0..511 sequential. Only the LDS layout/access
// width changed: AsT stride 65->68 (16B-aligned rows -> float4 reads of 4
// consecutive A rows), Wst [kk][c&3][c>>2] -> direct [kk][c] (float4 reads of
// 4 consecutive cols; staging now c-fast coalesced + bank-clean).
// ---------------------------------------------------------------------------
__global__ __launch_bounds__(256) void k_proj_s(
    const u32* __restrict__ dec, const u32* __restrict__ hid,
    const u32* __restrict__ wqk, const u32* __restrict__ wv,
    const int* __restrict__ flag,
    float* __restrict__ qb, float* __restrict__ kraw, float* __restrict__ vb)
{
  const int which = blockIdx.z;
  const u32* A = (which == 0) ? dec : hid;
  const u32* W = (which == 2) ? wv : wqk;
  const int m0 = blockIdx.x * 64;
  const int h  = blockIdx.y;
  const int t  = threadIdx.x;
  const int ty = t >> 4, tx = t & 15;
  const int is32 = flag[0];

  __shared__ __align__(16) float AsT[32][68];  // [kk][row i]; 272B stride
  __shared__ __align__(16) float Wst[32][64];  // [kk][col c]

  float acc[4][4];
  #pragma unroll
  for (int r = 0; r < 4; ++r)
    #pragma unroll
    for (int c = 0; c < 4; ++c) acc[r][c] = 0.0f;

  for (int k0 = 0; k0 < HIDK; k0 += 32) {
    if (is32) {
      const float* Af = (const float*)A;
      const float* Wf = (const float*)W;
      #pragma unroll
      for (int it = 0; it < 8; ++it) {
        int idx = t + it * 256;          // 2048: 64 rows x 32 k
        int i = idx >> 5, kk = idx & 31;
        AsT[kk][i] = Af[(size_t)(m0 + i) * HIDK + k0 + kk];
      }
      #pragma unroll
      for (int it = 0; it < 8; ++it) {
        int idx = t + it * 256;          // 2048: 32 k x 64 cols, c-fast
        int kk = idx >> 6, c = idx & 63;
        Wst[kk][c] = Wf[(size_t)(k0 + kk) * HIDK + h * 64 + c];
      }
    } else {
      #pragma unroll
      for (int it = 0; it < 4; ++it) {
        int idx = t + it * 256;          // 1024: A tile 64 rows x 16 u32
        int i = idx >> 4, kp = idx & 15;
        u32 uv = A[(size_t)(m0 + i) * (HIDK / 2) + (k0 >> 1) + kp];
        AsT[2 * kp][i]     = bflo(uv);
        AsT[2 * kp + 1][i] = bfhi(uv);
      }
      #pragma unroll
      for (int it = 0; it < 4; ++it) {
        int idx = t + it * 256;          // 1024: W tile 32 k x 32 u32, cp-fast
        int kk = idx >> 5, cp = idx & 31;
        u32 uv = W[(size_t)(k0 + kk) * (HIDK / 2) + h * 32 + cp];
        Wst[kk][2 * cp]     = bflo(uv);
        Wst[kk][2 * cp + 1] = bfhi(uv);
      }
    }
    __syncthreads();
    for (int kk = 0; kk < 32; ++kk) {
      float4 a4 = *reinterpret_cast<const float4*>(&AsT[kk][ty * 4]);  // rows ty*4..+3
      float4 w4 = *reinterpret_cast<const float4*>(&Wst[kk][tx * 4]);  // cols tx*4..+3
      acc[0][0] += a4.x * w4.x; acc[0][1] += a4.x * w4.y; acc[0][2] += a4.x * w4.z; acc[0][3] += a4.x * w4.w;
      acc[1][0] += a4.y * w4.x; acc[1][1] += a4.y * w4.y; acc[1][2] += a4.y * w4.z; acc[1][3] += a4.y * w4.w;
      acc[2][0] += a4.z * w4.x; acc[2][1] += a4.z * w4.y; acc[2][2] += a4.z * w4.z; acc[2][3] += a4.z * w4.w;
      acc[3][0] += a4.w * w4.x; acc[3][1] += a4.w * w4.y; acc[3][2] += a4.w * w4.z; acc[3][3] += a4.w * w4.w;
    }
    __syncthreads();
  }

  float* outp = (which == 0) ? qb : ((which == 1) ? kraw : vb);
  #pragma unroll
  for (int r = 0; r < 4; ++r) {
    int m = m0 + ty * 4 + r;
    int b = m >> 12, s = m & 4095;
    float4 o;
    o.x = acc[r][0]; o.y = acc[r][1]; o.z = acc[r][2]; o.w = acc[r][3];
    *reinterpret_cast<float4*>(outp + ((size_t)((b * HH + h) * SS + s)) * DD + tx * 4) = o;
  }
}

// ---------------------------------------------------------------------------
// Kernel 1b: MFMA projection for V ONLY (v = hid @ wv).
// V feeds no argmax; small numerical differences are harmless (R7-proven).
// ---------------------------------------------------------------------------
__global__ __launch_bounds__(256) void k_proj_v(
    const u32* __restrict__ hid,
    const unsigned short* __restrict__ wt0, const unsigned short* __restrict__ wt1,
    const unsigned short* __restrict__ wt2,
    const int* __restrict__ flag,
    float* __restrict__ vb)
{
  const int bid = blockIdx.x;              // grid 1024 = 8 x 128
  const int x = bid & 7, l = bid >> 3;     // l in [0,128)
  const int h = l & 7;
  const int m0 = (x * 16 + ((l >> 3) & 15)) * 64;
  const int t = threadIdx.x;
  const int w = t >> 6;
  const int r = t & 15, g = (t & 63) >> 4;
  const int is32 = flag[0];

  const u32* A = hid;
  const size_t wbase = (size_t)1 * 512 * 512 + (size_t)h * 64 * 512;  // wv plane
  const unsigned short* W0 = wt0 + wbase;
  const unsigned short* W1 = wt1 + wbase;
  const unsigned short* W2 = wt2 + wbase;

  __shared__ __align__(16) unsigned short A0[64][40];  // stride 80B
  __shared__ __align__(16) unsigned short A1[64][40];
  __shared__ __align__(16) unsigned short A2[64][40];
  __shared__ __align__(16) unsigned short B0[64][40];
  __shared__ __align__(16) unsigned short B1[64][40];
  __shared__ __align__(16) unsigned short B2[64][40];

  f32x4 acc[4];
  #pragma unroll
  for (int tn = 0; tn < 4; ++tn) { acc[tn][0] = 0.f; acc[tn][1] = 0.f; acc[tn][2] = 0.f; acc[tn][3] = 0.f; }

  for (int k0 = 0; k0 < HIDK; k0 += 32) {
    {
      const int n = t >> 2, kq = t & 3;
      *reinterpret_cast<uint4*>(&B0[n][kq * 8]) =
          *reinterpret_cast<const uint4*>(W0 + (size_t)n * 512 + k0 + kq * 8);
      if (is32) {
        *reinterpret_cast<uint4*>(&B1[n][kq * 8]) =
            *reinterpret_cast<const uint4*>(W1 + (size_t)n * 512 + k0 + kq * 8);
        *reinterpret_cast<uint4*>(&B2[n][kq * 8]) =
            *reinterpret_cast<const uint4*>(W2 + (size_t)n * 512 + k0 + kq * 8);
      }
    }
    if (is32) {
      const float* Af = (const float*)A;
      #pragma unroll
      for (int it = 0; it < 2; ++it) {
        int idx = t + it * 256;
        int m = idx >> 3, kq = idx & 7;
        float4 a4 = *reinterpret_cast<const float4*>(Af + (size_t)(m0 + m) * HIDK + k0 + kq * 4);
        ushort4 p0, p1, p2;
        bsplit3(a4.x, p0.x, p1.x, p2.x);
        bsplit3(a4.y, p0.y, p1.y, p2.y);
        bsplit3(a4.z, p0.z, p1.z, p2.z);
        bsplit3(a4.w, p0.w, p1.w, p2.w);
        *reinterpret_cast<ushort4*>(&A0[m][kq * 4]) = p0;
        *reinterpret_cast<ushort4*>(&A1[m][kq * 4]) = p1;
        *reinterpret_cast<ushort4*>(&A2[m][kq * 4]) = p2;
      }
    } else {
      #pragma unroll
      for (int it = 0; it < 2; ++it) {
        int idx = t + it * 256;
        int m = idx >> 3, kq = idx & 7;
        uint2 uv = *reinterpret_cast<const uint2*>(A + (size_t)(m0 + m) * (HIDK / 2) + (k0 >> 1) + kq * 2);
        *reinterpret_cast<uint2*>(&A0[m][kq * 4]) = uv;
      }
    }
    __syncthreads();

    bf16x8 a0 = *reinterpret_cast<const bf16x8*>(&A0[w * 16 + r][g * 8]);
    if (is32) {
      bf16x8 a1 = *reinterpret_cast<const bf16x8*>(&A1[w * 16 + r][g * 8]);
      bf16x8 a2 = *reinterpret_cast<const bf16x8*>(&A2[w * 16 + r][g * 8]);
      #pragma unroll
      for (int tn = 0; tn < 4; ++tn) {
        bf16x8 b0 = *reinterpret_cast<const bf16x8*>(&B0[tn * 16 + r][g * 8]);
        bf16x8 b1 = *reinterpret_cast<const bf16x8*>(&B1[tn * 16 + r][g * 8]);
        bf16x8 b2 = *reinterpret_cast<const bf16x8*>(&B2[tn * 16 + r][g * 8]);
        acc[tn] = __builtin_amdgcn_mfma_f32_16x16x32_bf16(a0, b0, acc[tn], 0, 0, 0);
        acc[tn] = __builtin_amdgcn_mfma_f32_16x16x32_bf16(a0, b1, acc[tn], 0, 0, 0);
        acc[tn] = __builtin_amdgcn_mfma_f32_16x16x32_bf16(a1, b0, acc[tn], 0, 0, 0);
        acc[tn] = __builtin_amdgcn_mfma_f32_16x16x32_bf16(a0, b2, acc[tn], 0, 0, 0);
        acc[tn] = __builtin_amdgcn_mfma_f32_16x16x32_bf16(a2, b0, acc[tn], 0, 0, 0);
        acc[tn] = __builtin_amdgcn_mfma_f32_16x16x32_bf16(a1, b1, acc[tn], 0, 0, 0);
      }
    } else {
      #pragma unroll
      for (int tn = 0; tn < 4; ++tn) {
        bf16x8 b0 = *reinterpret_cast<const bf16x8*>(&B0[tn * 16 + r][g * 8]);
        acc[tn] = __builtin_amdgcn_mfma_f32_16x16x32_bf16(a0, b0, acc[tn], 0, 0, 0);
      }
    }
    __syncthreads();
  }

  #pragma unroll
  for (int tn = 0; tn < 4; ++tn)
    #pragma unroll
    for (int rg = 0; rg < 4; ++rg) {
      int m = m0 + w * 16 + g * 4 + rg;
      int b = m >> 12, s = m & 4095;
      vb[((size_t)((b * HH + h) * SS + s)) * DD + tn * 16 + r] = acc[tn][rg];
    }
}

// ---------------------------------------------------------------------------
// Kernel 2: LSH hash. rotS [64][64], float4 LDS reads (R8-proven).
// ---------------------------------------------------------------------------
__global__ __launch_bounds__(256) void k_hash(
    const float* __restrict__ qb, const float* __restrict__ kraw,
    const u32* __restrict__ rots, const int* __restrict__ flag,
    u8* __restrict__ bucketOut)
{
  const int bhn = blockIdx.x;       // 0..63 : (b*8+h)*4+n
  const int which = blockIdx.y;     // 0=q 1=k
  const int squarter = blockIdx.z;  // 0..3
  const int t = threadIdx.x;
  const int bh = bhn >> 2;
  const int h  = bh & 7;
  const int n  = bhn & 3;
  const int is32 = flag[0];

  __shared__ __align__(16) float rotS[64][64];   // [d][r], 16 KB
  if (is32) {
    const float* rf = (const float*)rots;
    #pragma unroll
    for (int it = 0; it < 16; ++it) {
      int idx = t + it * 256;       // 4096 floats
      int d = idx >> 6, r = idx & 63;
      rotS[d][r] = rf[((size_t)((h * 64 + d) * 4 + n)) * 64 + r];
    }
  } else {
    #pragma unroll
    for (int it = 0; it < 8; ++it) {
      int idx = t + it * 256;       // 2048 u32 (4096 bf16)
      int d = idx >> 5, rp = idx & 31;
      u32 uv = rots[((size_t)((h * 64 + d) * 4 + n)) * 32 + rp];
      rotS[d][2 * rp]     = bflo(uv);
      rotS[d][2 * rp + 1] = bfhi(uv);
    }
  }
  __syncthreads();

  const float* src = ((which == 0) ? qb : kraw) + (size_t)bh * SS * DD;
  u8* bout = bucketOut + ((size_t)(which * 64 + bhn)) * SS;

  for (int ii = 0; ii < 4; ++ii) {
    int s = squarter * 1024 + ii * 256 + t;
    const float* row = src + (size_t)s * DD;
    float vec[64];
    #pragma unroll
    for (int d4 = 0; d4 < 16; ++d4) {
      float4 v4 = *reinterpret_cast<const float4*>(row + d4 * 4);
      vec[d4 * 4 + 0] = v4.x; vec[d4 * 4 + 1] = v4.y;
      vec[d4 * 4 + 2] = v4.z; vec[d4 * 4 + 3] = v4.w;
    }
    float bestP = -1e30f, bestN = -1e30f;
    int idxP = 0, idxN = 0;
    #pragma unroll 1
    for (int r0 = 0; r0 < 64; r0 += 16) {
      float acc[16];
      #pragma unroll
      for (int rr = 0; rr < 16; ++rr) acc[rr] = 0.0f;
      #pragma unroll
      for (int d = 0; d < 64; ++d) {
        float vd = vec[d];
        #pragma unroll
        for (int q4 = 0; q4 < 4; ++q4) {
          float4 rv4 = *reinterpret_cast<const float4*>(&rotS[d][r0 + q4 * 4]);
          acc[q4 * 4 + 0] += vd * rv4.x;
          acc[q4 * 4 + 1] += vd * rv4.y;
          acc[q4 * 4 + 2] += vd * rv4.z;
          acc[q4 * 4 + 3] += vd * rv4.w;
        }
      }
      #pragma unroll
      for (int rr = 0; rr < 16; ++rr) {
        float a = acc[rr];
        int r = r0 + rr;
        if (a > bestP) { bestP = a; idxP = r; }
        if (-a > bestN) { bestN = -a; idxN = r; }
      }
    }
    int bucket = (bestP >= bestN) ? idxP : (64 + idxN);
    bout[s] = (u8)bucket;
  }
}

// ---------------------------------------------------------------------------
// Kernel 3: PARALLEL stable counting sort per (b,h,round,which).
// ---------------------------------------------------------------------------
__global__ __launch_bounds__(256) void k_sort(
    const u8* __restrict__ bucketIn, int* __restrict__ sq_pos,
    int* __restrict__ sk_pos, int* __restrict__ sk_rank)
{
  const int bhn = blockIdx.x, which = blockIdx.y;
  const int t = threadIdx.x;
  const int bh = bhn >> 2, n = bhn & 3;
  const int lane = t & 63, w = t >> 6;

  __shared__ u8 bk[4096];
  __shared__ u8 rk[4096];
  __shared__ int chunkh[64 * 128];   // [chunk][bin], 32 KB
  __shared__ int hist[128];
  __shared__ int scanS[128];

  const u8* bin = bucketIn + ((size_t)(which * 64 + bhn)) * SS;
  #pragma unroll
  for (int it = 0; it < 4; ++it)
    ((u32*)bk)[t + it * 256] = ((const u32*)bin)[t + it * 256];
  #pragma unroll
  for (int it = 0; it < 32; ++it) chunkh[t + it * 256] = 0;
  if (t < 128) hist[t] = 0;
  __syncthreads();

  const unsigned long long below = (lane == 0) ? 0ull : (~0ull >> (64 - lane));
  #pragma unroll 1
  for (int k = 0; k < 16; ++k) {
    const int c = w * 16 + k;
    const int s = c * 64 + lane;
    const int b = bk[s];
    unsigned long long m = ~0ull;
    #pragma unroll
    for (int bit = 0; bit < 7; ++bit) {
      unsigned long long vote = __ballot((b >> bit) & 1);
      m &= ((b >> bit) & 1) ? vote : ~vote;
    }
    const int r = (int)__popcll(m & below);
    rk[s] = (u8)r;
    if (r == 0) {
      const int cnt = (int)__popcll(m);
      chunkh[c * 128 + b] = cnt;
      atomicAdd(&hist[b], cnt);
    }
  }
  __syncthreads();

  if (t < 128) scanS[t] = hist[t];
  __syncthreads();
  for (int off = 1; off < 128; off <<= 1) {
    int add = 0;
    if (t < 128 && t >= off) add = scanS[t - off];
    __syncthreads();
    if (t < 128) scanS[t] += add;
    __syncthreads();
  }
  if (t < 128) {
    int run = scanS[t] - hist[t];    // global bin start
    #pragma unroll 1
    for (int c = 0; c < 64; ++c) {
      int v = chunkh[c * 128 + t];
      chunkh[c * 128 + t] = run;
      run += v;
    }
  }
  __syncthreads();

  int* outp = ((which == 0) ? sq_pos : sk_pos) + (size_t)bh * RANKS + n * SS;
  int* rnkp = sk_rank + (size_t)bh * RANKS + n * SS;
  #pragma unroll 1
  for (int k = 0; k < 16; ++k) {
    const int c = w * 16 + k;
    const int s = c * 64 + lane;
    const int b = bk[s];
    const int pos = chunkh[c * 128 + b] + (int)rk[s];
    outp[pos] = s;
    if (which) rnkp[s] = pos;
  }
}

// ---------------------------------------------------------------------------
// Kernel 4: single attention pass, 2 q-rows per thread (R8-proven).
// ---------------------------------------------------------------------------
__global__ __launch_bounds__(256) void k_attn(
    const float* __restrict__ qb, const float* __restrict__ kraw,
    const float* __restrict__ vb,
    const int* __restrict__ sq_pos, const int* __restrict__ sk_pos,
    const int mode,
    float* __restrict__ outA, float* __restrict__ denA,
    float* __restrict__ numB, float* __restrict__ denB)
{
  const int c = blockIdx.x;
  const int h = blockIdx.y, b = blockIdx.z;
  const int bh = b * HH + h;
  const int t = threadIdx.x;
  const int cprev = (c + NCC - 1) & (NCC - 1);

  __shared__ float Qs[64][68];
  __shared__ float KVs[128][68];
  __shared__ float sc[128];
  __shared__ int kposS[128], mposS[128];

  if (t < 128) {
    int slot = (t < 64) ? (cprev * 64 + t) : (c * 64 + (t - 64));
    kposS[t] = sk_pos[(size_t)bh * RANKS + slot];
    mposS[t] = sq_pos[(size_t)bh * RANKS + slot];
  }
  __syncthreads();

  const float* qbase = qb + (size_t)bh * SS * DD;
  const float* kbase = kraw + (size_t)bh * SS * DD;
  const float* vbase = vb + (size_t)bh * SS * DD;

  #pragma unroll
  for (int it = 0; it < 4; ++it) {
    int idx = t + it * 256;
    int i = idx >> 4, d4 = idx & 15;
    *reinterpret_cast<float4*>(&Qs[i][d4 * 4]) =
        *reinterpret_cast<const float4*>(qbase + (size_t)mposS[64 + i] * DD + d4 * 4);
  }
  #pragma unroll
  for (int it = 0; it < 8; ++it) {
    int idx = t + it * 256;
    int j = idx >> 4, d4 = idx & 15;
    *reinterpret_cast<float4*>(&KVs[j][d4 * 4]) =
        *reinterpret_cast<const float4*>(kbase + (size_t)kposS[j] * DD + d4 * 4);
  }
  __syncthreads();
  if (t < 128) {
    float ms = 0.f;
    #pragma unroll
    for (int d4 = 0; d4 < 16; ++d4) {
      float4 x4 = *reinterpret_cast<float4*>(&KVs[t][d4 * 4]);
      ms += x4.x * x4.x + x4.y * x4.y + x4.z * x4.z + x4.w * x4.w;
    }
    sc[t] = 0.125f / sqrtf(ms * (1.0f / 64.0f) + 1e-6f);
  }
  __syncthreads();
  #pragma unroll
  for (int it = 0; it < 8; ++it) {
    int idx = t + it * 256;
    int j = idx >> 4, d4 = idx & 15;
    float s_ = sc[j];
    float4 v4 = *reinterpret_cast<float4*>(&KVs[j][d4 * 4]);
    v4.x *= s_; v4.y *= s_; v4.z *= s_; v4.w *= s_;
    *reinterpret_cast<float4*>(&KVs[j][d4 * 4]) = v4;
  }
  __syncthreads();

  const int i2 = t >> 3;            // row pair 0..31
  const int qr = i2 * 2;
  const int j0 = t & 7;             // key lane 0..7 (keys j0 + 8*jj)
  const int qpa = mposS[64 + qr];
  const int qpb = mposS[64 + qr + 1];

  float accA[16], accB[16];
  #pragma unroll
  for (int jj = 0; jj < 16; ++jj) { accA[jj] = 0.f; accB[jj] = 0.f; }
  #pragma unroll 2
  for (int d0 = 0; d0 < 16; ++d0) {
    float4 qa = *reinterpret_cast<const float4*>(&Qs[qr][d0 * 4]);
    float4 qb_ = *reinterpret_cast<const float4*>(&Qs[qr + 1][d0 * 4]);
    #pragma unroll
    for (int jj = 0; jj < 16; ++jj) {
      float4 k4 = *reinterpret_cast<const float4*>(&KVs[j0 + 8 * jj][d0 * 4]);
      accA[jj] += qa.x * k4.x + qa.y * k4.y + qa.z * k4.z + qa.w * k4.w;
      accB[jj] += qb_.x * k4.x + qb_.y * k4.y + qb_.z * k4.z + qb_.w * k4.w;
    }
  }
  #pragma unroll
  for (int jj = 0; jj < 16; ++jj) {
    int mp = mposS[j0 + 8 * jj];
    if (mp == qpa) accA[jj] = -100000.0f;
    if (mp == qpb) accB[jj] = -100000.0f;
  }
  // un-normalized exp(dot); masked -> expf(-1e5) == 0
  float sa = 0.f, sb = 0.f;
  #pragma unroll
  for (int jj = 0; jj < 16; ++jj) {
    float ea = expf(accA[jj]); accA[jj] = ea; sa += ea;
    float eb = expf(accB[jj]); accB[jj] = eb; sb += eb;
  }
  sa += __shfl_xor(sa, 1); sa += __shfl_xor(sa, 2); sa += __shfl_xor(sa, 4);
  sb += __shfl_xor(sb, 1); sb += __shfl_xor(sb, 2); sb += __shfl_xor(sb, 4);

  const int n = c >> 6;
  if (j0 == 0) {
    if (mode) {
      denB[(size_t)(bh * NHH + n) * SS + (c & 63) * 64 + qr]     = sa;
      denB[(size_t)(bh * NHH + n) * SS + (c & 63) * 64 + qr + 1] = sb;
    } else {
      atomicAdd(&denA[(size_t)bh * SS + kposS[64 + qr]], sa);
      atomicAdd(&denA[(size_t)bh * SS + kposS[64 + qr + 1]], sb);
    }
  }

  __syncthreads();  // done with K in LDS; reload V
  #pragma unroll
  for (int it = 0; it < 8; ++it) {
    int idx = t + it * 256;
    int j = idx >> 4, d4 = idx & 15;
    *reinterpret_cast<float4*>(&KVs[j][d4 * 4]) =
        *reinterpret_cast<const float4*>(vbase + (size_t)kposS[j] * DD + d4 * 4);
  }
  __syncthreads();

  // this lane writes row qr + (j0>>2), d-chunk (j0&3)
  const int row = qr + (j0 >> 2);
  float* nrow = mode ? (numB + ((size_t)(bh * NHH + n) * SS + (c & 63) * 64 + row) * DD)
                     : (outA + ((size_t)(b * SS + kposS[64 + row])) * (HH * DD) + h * DD);

  #pragma unroll 1
  for (int db = 0; db < 4; ++db) {
    float4 aA0 = make_float4(0.f, 0.f, 0.f, 0.f);
    float4 aA1 = aA0, aA2 = aA0, aA3 = aA0;
    float4 aB0 = aA0, aB1 = aA0, aB2 = aA0, aB3 = aA0;
    #pragma unroll 4
    for (int jj = 0; jj < 16; ++jj) {
      const float pa = accA[jj];
      const float pb = accB[jj];
      const float* vr = &KVs[j0 + 8 * jj][db * 16];
      float4 v0 = *reinterpret_cast<const float4*>(vr + 0);
      float4 v1 = *reinterpret_cast<const float4*>(vr + 4);
      float4 v2 = *reinterpret_cast<const float4*>(vr + 8);
      float4 v3 = *reinterpret_cast<const float4*>(vr + 12);
      aA0.x += pa * v0.x; aA0.y += pa * v0.y; aA0.z += pa * v0.z; aA0.w += pa * v0.w;
      aA1.x += pa * v1.x; aA1.y += pa * v1.y; aA1.z += pa * v1.z; aA1.w += pa * v1.w;
      aA2.x += pa * v2.x; aA2.y += pa * v2.y; aA2.z += pa * v2.z; aA2.w += pa * v2.w;
      aA3.x += pa * v3.x; aA3.y += pa * v3.y; aA3.z += pa * v3.z; aA3.w += pa * v3.w;
      aB0.x += pb * v0.x; aB0.y += pb * v0.y; aB0.z += pb * v0.z; aB0.w += pb * v0.w;
      aB1.x += pb * v1.x; aB1.y += pb * v1.y; aB1.z += pb * v1.z; aB1.w += pb * v1.w;
      aB2.x += pb * v2.x; aB2.y += pb * v2.y; aB2.z += pb * v2.z; aB2.w += pb * v2.w;
      aB3.x += pb * v3.x; aB3.y += pb * v3.y; aB3.z += pb * v3.z; aB3.w += pb * v3.w;
    }
    #pragma unroll
    for (int st = 1; st <= 4; st <<= 1) {
      aA0.x += __shfl_xor(aA0.x, st); aA0.y += __shfl_xor(aA0.y, st);
      aA0.z += __shfl_xor(aA0.z, st); aA0.w += __shfl_xor(aA0.w, st);
      aA1.x += __shfl_xor(aA1.x, st); aA1.y += __shfl_xor(aA1.y, st);
      aA1.z += __shfl_xor(aA1.z, st); aA1.w += __shfl_xor(aA1.w, st);
      aA2.x += __shfl_xor(aA2.x, st); aA2.y += __shfl_xor(aA2.y, st);
      aA2.z += __shfl_xor(aA2.z, st); aA2.w += __shfl_xor(aA2.w, st);
      aA3.x += __shfl_xor(aA3.x, st); aA3.y += __shfl_xor(aA3.y, st);
      aA3.z += __shfl_xor(aA3.z, st); aA3.w += __shfl_xor(aA3.w, st);
      aB0.x += __shfl_xor(aB0.x, st); aB0.y += __shfl_xor(aB0.y, st);
      aB0.z += __shfl_xor(aB0.z, st); aB0.w += __shfl_xor(aB0.w, st);
      aB1.x += __shfl_xor(aB1.x, st); aB1.y += __shfl_xor(aB1.y, st);
      aB1.z += __shfl_xor(aB1.z, st); aB1.w += __shfl_xor(aB1.w, st);
      aB2.x += __shfl_xor(aB2.x, st); aB2.y += __shfl_xor(aB2.y, st);
      aB2.z += __shfl_xor(aB2.z, st); aB2.w += __shfl_xor(aB2.w, st);
      aB3.x += __shfl_xor(aB3.x, st); aB3.y += __shfl_xor(aB3.y, st);
      aB3.z += __shfl_xor(aB3.z, st); aB3.w += __shfl_xor(aB3.w, st);
    }
    // static selection (no runtime-indexed register arrays)
    float4 m0_ = (j0 & 4) ? aB0 : aA0;
    float4 m1_ = (j0 & 4) ? aB1 : aA1;
    float4 m2_ = (j0 & 4) ? aB2 : aA2;
    float4 m3_ = (j0 & 4) ? aB3 : aA3;
    float4 mine = (j0 & 2) ? ((j0 & 1) ? m3_ : m2_) : ((j0 & 1) ? m1_ : m0_);
    if (mode) {
      *reinterpret_cast<float4*>(nrow + db * 16 + (j0 & 3) * 4) = mine;
    } else {
      float* p = nrow + db * 16 + (j0 & 3) * 4;
      atomicAdd(&p[0], mine.x);
      atomicAdd(&p[1], mine.y);
      atomicAdd(&p[2], mine.z);
      atomicAdd(&p[3], mine.w);
    }
  }
}

// ---------------------------------------------------------------------------
// Kernel 5 (big-ws path): gather-combine.
// ---------------------------------------------------------------------------
__global__ __launch_bounds__(256) void k_combine(
    const float* __restrict__ numB, const float* __restrict__ denB,
    const int* __restrict__ sk_rank, float* __restrict__ outp)
{
  const int bh = blockIdx.y;
  const int s = blockIdx.x * 16 + (threadIdx.x >> 4);
  const int lane = threadIdx.x & 15;
  const int b = bh >> 3, h = bh & 7;
  float4 acc = make_float4(0.f, 0.f, 0.f, 0.f);
  float den = 0.f;
  #pragma unroll
  for (int n = 0; n < NHH; ++n) {
    int r = sk_rank[(size_t)bh * RANKS + n * SS + s];
    size_t rowi = (size_t)(bh * NHH + n) * SS + r;
    float4 v = *reinterpret_cast<const float4*>(numB + rowi * DD + lane * 4);
    acc.x += v.x; acc.y += v.y; acc.z += v.z; acc.w += v.w;
    den += denB[rowi];
  }
  float inv = 1.0f / den;
  acc.x *= inv; acc.y *= inv; acc.z *= inv; acc.w *= inv;
  *reinterpret_cast<float4*>(outp + ((size_t)(b * SS + s)) * (HH * DD) + h * DD + lane * 4) = acc;
}

// ---------------------------------------------------------------------------
// Kernel 5' (fallback path): divide accumulated numerator by denominator.
// ---------------------------------------------------------------------------
__global__ __launch_bounds__(256) void k_div(
    const float* __restrict__ den, float* __restrict__ outp)
{
  int idx = blockIdx.x * 256 + threadIdx.x;  // grid 4096 -> 1,048,576 float4
  int f = idx * 4;
  int col = f & 511;
  int h = col >> 6;
  int srow = f >> 9;                          // b*4096+s
  int b = srow >> 12, s = srow & 4095;
  float inv = 1.0f / den[(size_t)(b * HH + h) * SS + s];
  float4 v = *reinterpret_cast<float4*>(outp + (size_t)f);
  v.x *= inv; v.y *= inv; v.z *= inv; v.w *= inv;
  *reinterpret_cast<float4*>(outp + (size_t)f) = v;
}

// ---------------------------------------------------------------------------
// Kernel Z: zero the fp32 output (fallback path; harness poisons d_out).
// ---------------------------------------------------------------------------
__global__ __launch_bounds__(256) void k_zero_out(float* __restrict__ outp)
{
  int flat = blockIdx.x * 256 + threadIdx.x;  // grid 4096 -> 1,048,576 float4
  float4 z = make_float4(0.f, 0.f, 0.f, 0.f);
  *reinterpret_cast<float4*>(outp + (size_t)flat * 4) = z;
}

// ---------------------------------------------------------------------------
extern "C" void kernel_launch(void* const* d_in, const int* in_sizes, int n_in,
                              void* d_out, int out_size, void* d_ws, size_t ws_size,
                              hipStream_t stream)
{
  (void)in_sizes; (void)n_in; (void)out_size;
  const u32* dec = (const u32*)d_in[0];
  const u32* hid = (const u32*)d_in[1];
  const u32* wqk = (const u32*)d_in[2];
  const u32* wv  = (const u32*)d_in[3];
  const u32* rot = (const u32*)d_in[4];

  const size_t QKV  = (size_t)BB * HH * SS * DD;   // 4,194,304 elems
  const size_t LOGU = (size_t)BB * HH * NHH * SS;  // 262,144

  float* qb      = (float*)d_ws;
  float* kraw    = qb + QKV;
  float* vb      = kraw + QKV;
  float* den     = vb + QKV;                  // LOGU floats
  int*   sq_pos  = (int*)(den + LOGU);
  int*   sk_pos  = sq_pos + LOGU;
  int*   sk_rank = sk_pos + LOGU;
  u8*    buckets = (u8*)(sk_rank + LOGU);
  int*   flag    = (int*)(buckets + (size_t)2 * 64 * SS);
  const size_t numb_off = 55050496;           // align_up(low region, 256)
  float* numb    = (float*)((char*)d_ws + numb_off);
  // wt planes live INSIDE the numb region (numb not yet live during proj):
  unsigned short* wt0 = (unsigned short*)numb;
  unsigned short* wt1 = wt0 + (size_t)2 * 512 * 512;
  unsigned short* wt2 = wt1 + (size_t)2 * 512 * 512;
  const size_t need_big = numb_off + (size_t)NHH * QKV * sizeof(float);  // 122,159,360
  const int big = (ws_size >= need_big) ? 1 : 0;

  hipMemsetAsync(flag, 0, sizeof(int), stream);
  k_detect<<<dim3(512), 256, 0, stream>>>(wqk, flag);
  k_prep<<<dim3(256, 2), 256, 0, stream>>>(wqk, wv, flag, wt0, wt1, wt2);
  // q,k: scalar (hash-feeding, bit-identical accumulation). v: MFMA (R7-proven).
  k_proj_s<<<dim3(128, 8, 2), 256, 0, stream>>>(dec, hid, wqk, wv, flag, qb, kraw, vb);
  k_proj_v<<<dim3(1024), 256, 0, stream>>>(hid, wt0, wt1, wt2, flag, vb);
  k_hash<<<dim3(64, 2, 4), 256, 0, stream>>>(qb, kraw, rot, flag, buckets);
  k_sort<<<dim3(64, 2), 256, 0, stream>>>(buckets, sq_pos, sk_pos, sk_rank);

  if (big) {
    k_attn<<<dim3(NCC, HH, BB), 256, 0, stream>>>(
        qb, kraw, vb, sq_pos, sk_pos, 1, nullptr, nullptr, numb, den);
    k_combine<<<dim3(SS / 16, BB * HH), 256, 0, stream>>>(
        numb, den, sk_rank, (float*)d_out);
  } else {
    hipMemsetAsync(den, 0, (size_t)BB * HH * SS * sizeof(float), stream);
    k_zero_out<<<dim3(4096), 256, 0, stream>>>((float*)d_out);
    k_attn<<<dim3(NCC, HH, BB), 256, 0, stream>>>(
        qb, kraw, vb, sq_pos, sk_pos, 0, (float*)d_out, den, nullptr, nullptr);
    k_div<<<dim3(4096), 256, 0, stream>>>(den, (float*)d_out);
  }
}

// Round 10
// 605.837 us; speedup vs baseline: 3.1762x; 1.0500x over previous
//
#include <hip/hip_runtime.h>
#include <math.h>

#define BB 2
#define SS 4096
#define HIDK 512
#define HH 8
#define DD 64
#define NHH 4
#define NCC 256      // chunks per (b,h) = NH*S/CHUNK
#define RANKS 16384  // NH*S

typedef unsigned int u32;
typedef unsigned char u8;
typedef __attribute__((ext_vector_type(8))) short bf16x8;
typedef __attribute__((ext_vector_type(4))) float f32x4;

__device__ __forceinline__ float bflo(u32 u){ return __uint_as_float(u << 16); }
__device__ __forceinline__ float bfhi(u32 u){ return __uint_as_float(u & 0xffff0000u); }

// RN fp32 -> bf16 (top of x)
__device__ __forceinline__ unsigned short brn(float x)
{
  u32 u = __float_as_uint(x);
  u32 r = u + 0x7FFFu + ((u >> 16) & 1u);
  return (unsigned short)(r >> 16);
}

// 2-term bf16 split: x ~= b0 + b1 (residual ~2^-17 |x|).
__device__ __forceinline__ void bsplit2(float x, unsigned short& b0, unsigned short& b1)
{
  b0 = brn(x);
  float x1 = x - __uint_as_float((u32)b0 << 16);
  b1 = brn(x1);
}

// 3-term bf16 split: x ~= b0 + b1 + b2 (Sterbenz-exact residuals).
__device__ __forceinline__ void bsplit3(float x, unsigned short& b0, unsigned short& b1, unsigned short& b2)
{
  b0 = brn(x);
  float x1 = x - __uint_as_float((u32)b0 << 16);
  b1 = brn(x1);
  float x2 = x1 - __uint_as_float((u32)b1 << 16);
  b2 = brn(x2);
}

// ---------------------------------------------------------------------------
// Kernel 0: input dtype detection (bf16 vs fp32 bit patterns in w_qk).
// ---------------------------------------------------------------------------
__global__ __launch_bounds__(256) void k_detect(const u32* __restrict__ w, int* __restrict__ flag)
{
  int i = blockIdx.x * 256 + threadIdx.x;   // grid 512 -> 131072 u32
  float lo = bflo(w[i]);
  bool bad = !(fabsf(lo) <= 1024.0f);       // true also for NaN
  if (__any(bad)) {
    if ((threadIdx.x & 63) == 0) atomicOr(flag, 1);
  }
}

// ---------------------------------------------------------------------------
// Kernel P: prep weights. Transpose W[k][n] -> Wt[n][k], 3-term bf16 split
// for fp32 inputs. wt*: [2][512][512] u16 (plane 0 = wqk, 1 = wv).
// ---------------------------------------------------------------------------
__global__ __launch_bounds__(256) void k_prep(
    const u32* __restrict__ wqk, const u32* __restrict__ wv,
    const int* __restrict__ flag,
    unsigned short* __restrict__ wt0, unsigned short* __restrict__ wt1,
    unsigned short* __restrict__ wt2)
{
  const int which = blockIdx.y;
  const u32* W = which ? wv : wqk;
  const int tk = blockIdx.x >> 4, tn = blockIdx.x & 15;
  const int t = threadIdx.x;
  const int is32 = flag[0];
  __shared__ unsigned short h0s[32][36];
  __shared__ unsigned short h1s[32][36];
  __shared__ unsigned short h2s[32][36];
  if (is32) {
    const float* Wf = (const float*)W;
    #pragma unroll
    for (int it = 0; it < 4; ++it) {
      int idx = t + it * 256;           // 1024 = 32 k x 32 n
      int kk = idx >> 5, nn = idx & 31;
      float x = Wf[(size_t)(tk * 32 + kk) * 512 + tn * 32 + nn];
      bsplit3(x, h0s[kk][nn], h1s[kk][nn], h2s[kk][nn]);
    }
  } else {
    #pragma unroll
    for (int it = 0; it < 2; ++it) {
      int idx = t + it * 256;           // 512 u32 = 32 k x 16 pairs
      int kk = idx >> 4, np = idx & 15;
      u32 uv = W[(size_t)(tk * 32 + kk) * 256 + tn * 16 + np];
      h0s[kk][2 * np]     = (unsigned short)(uv & 0xffffu);
      h0s[kk][2 * np + 1] = (unsigned short)(uv >> 16);
      h1s[kk][2 * np] = 0; h1s[kk][2 * np + 1] = 0;
      h2s[kk][2 * np] = 0; h2s[kk][2 * np + 1] = 0;
    }
  }
  __syncthreads();
  size_t obase = ((size_t)which * 512 + tn * 32) * 512 + tk * 32;
  #pragma unroll
  for (int it = 0; it < 4; ++it) {
    int idx = t + it * 256;
    int nn = idx >> 5, kk = idx & 31;
    wt0[obase + (size_t)nn * 512 + kk] = h0s[kk][nn];
    wt1[obase + (size_t)nn * 512 + kk] = h1s[kk][nn];
    wt2[obase + (size_t)nn * 512 + kk] = h2s[kk][nn];
  }
}

// ---------------------------------------------------------------------------
// Kernel 1a: SCALAR projections for q and k (hash-feeding).
// Accumulation bit-identical to the R0-R2/R7/R8/R9-proven kernel.
// ---------------------------------------------------------------------------
__global__ __launch_bounds__(256) void k_proj_s(
    const u32* __restrict__ dec, const u32* __restrict__ hid,
    const u32* __restrict__ wqk, const u32* __restrict__ wv,
    const int* __restrict__ flag,
    float* __restrict__ qb, float* __restrict__ kraw, float* __restrict__ vb)
{
  const int which = blockIdx.z;
  const u32* A = (which == 0) ? dec : hid;
  const u32* W = (which == 2) ? wv : wqk;
  const int m0 = blockIdx.x * 64;
  const int h  = blockIdx.y;
  const int t  = threadIdx.x;
  const int ty = t >> 4, tx = t & 15;
  const int is32 = flag[0];

  __shared__ __align__(16) float AsT[32][68];  // [kk][row i]; 272B stride
  __shared__ __align__(16) float Wst[32][64];  // [kk][col c]

  float acc[4][4];
  #pragma unroll
  for (int r = 0; r < 4; ++r)
    #pragma unroll
    for (int c = 0; c < 4; ++c) acc[r][c] = 0.0f;

  for (int k0 = 0; k0 < HIDK; k0 += 32) {
    if (is32) {
      const float* Af = (const float*)A;
      const float* Wf = (const float*)W;
      #pragma unroll
      for (int it = 0; it < 8; ++it) {
        int idx = t + it * 256;          // 2048: 64 rows x 32 k
        int i = idx >> 5, kk = idx & 31;
        AsT[kk][i] = Af[(size_t)(m0 + i) * HIDK + k0 + kk];
      }
      #pragma unroll
      for (int it = 0; it < 8; ++it) {
        int idx = t + it * 256;          // 2048: 32 k x 64 cols, c-fast
        int kk = idx >> 6, c = idx & 63;
        Wst[kk][c] = Wf[(size_t)(k0 + kk) * HIDK + h * 64 + c];
      }
    } else {
      #pragma unroll
      for (int it = 0; it < 4; ++it) {
        int idx = t + it * 256;          // 1024: A tile 64 rows x 16 u32
        int i = idx >> 4, kp = idx & 15;
        u32 uv = A[(size_t)(m0 + i) * (HIDK / 2) + (k0 >> 1) + kp];
        AsT[2 * kp][i]     = bflo(uv);
        AsT[2 * kp + 1][i] = bfhi(uv);
      }
      #pragma unroll
      for (int it = 0; it < 4; ++it) {
        int idx = t + it * 256;          // 1024: W tile 32 k x 32 u32, cp-fast
        int kk = idx >> 5, cp = idx & 31;
        u32 uv = W[(size_t)(k0 + kk) * (HIDK / 2) + h * 32 + cp];
        Wst[kk][2 * cp]     = bflo(uv);
        Wst[kk][2 * cp + 1] = bfhi(uv);
      }
    }
    __syncthreads();
    for (int kk = 0; kk < 32; ++kk) {
      float4 a4 = *reinterpret_cast<const float4*>(&AsT[kk][ty * 4]);  // rows ty*4..+3
      float4 w4 = *reinterpret_cast<const float4*>(&Wst[kk][tx * 4]);  // cols tx*4..+3
      acc[0][0] += a4.x * w4.x; acc[0][1] += a4.x * w4.y; acc[0][2] += a4.x * w4.z; acc[0][3] += a4.x * w4.w;
      acc[1][0] += a4.y * w4.x; acc[1][1] += a4.y * w4.y; acc[1][2] += a4.y * w4.z; acc[1][3] += a4.y * w4.w;
      acc[2][0] += a4.z * w4.x; acc[2][1] += a4.z * w4.y; acc[2][2] += a4.z * w4.z; acc[2][3] += a4.z * w4.w;
      acc[3][0] += a4.w * w4.x; acc[3][1] += a4.w * w4.y; acc[3][2] += a4.w * w4.z; acc[3][3] += a4.w * w4.w;
    }
    __syncthreads();
  }

  float* outp = (which == 0) ? qb : ((which == 1) ? kraw : vb);
  #pragma unroll
  for (int r = 0; r < 4; ++r) {
    int m = m0 + ty * 4 + r;
    int b = m >> 12, s = m & 4095;
    float4 o;
    o.x = acc[r][0]; o.y = acc[r][1]; o.z = acc[r][2]; o.w = acc[r][3];
    *reinterpret_cast<float4*>(outp + ((size_t)((b * HH + h) * SS + s)) * DD + tx * 4) = o;
  }
}

// ---------------------------------------------------------------------------
// Kernel 1b: MFMA projection for V ONLY (v = hid @ wv). R7-proven.
// ---------------------------------------------------------------------------
__global__ __launch_bounds__(256) void k_proj_v(
    const u32* __restrict__ hid,
    const unsigned short* __restrict__ wt0, const unsigned short* __restrict__ wt1,
    const unsigned short* __restrict__ wt2,
    const int* __restrict__ flag,
    float* __restrict__ vb)
{
  const int bid = blockIdx.x;              // grid 1024 = 8 x 128
  const int x = bid & 7, l = bid >> 3;     // l in [0,128)
  const int h = l & 7;
  const int m0 = (x * 16 + ((l >> 3) & 15)) * 64;
  const int t = threadIdx.x;
  const int w = t >> 6;
  const int r = t & 15, g = (t & 63) >> 4;
  const int is32 = flag[0];

  const u32* A = hid;
  const size_t wbase = (size_t)1 * 512 * 512 + (size_t)h * 64 * 512;  // wv plane
  const unsigned short* W0 = wt0 + wbase;
  const unsigned short* W1 = wt1 + wbase;
  const unsigned short* W2 = wt2 + wbase;

  __shared__ __align__(16) unsigned short A0[64][40];  // stride 80B
  __shared__ __align__(16) unsigned short A1[64][40];
  __shared__ __align__(16) unsigned short A2[64][40];
  __shared__ __align__(16) unsigned short B0[64][40];
  __shared__ __align__(16) unsigned short B1[64][40];
  __shared__ __align__(16) unsigned short B2[64][40];

  f32x4 acc[4];
  #pragma unroll
  for (int tn = 0; tn < 4; ++tn) { acc[tn][0] = 0.f; acc[tn][1] = 0.f; acc[tn][2] = 0.f; acc[tn][3] = 0.f; }

  for (int k0 = 0; k0 < HIDK; k0 += 32) {
    {
      const int n = t >> 2, kq = t & 3;
      *reinterpret_cast<uint4*>(&B0[n][kq * 8]) =
          *reinterpret_cast<const uint4*>(W0 + (size_t)n * 512 + k0 + kq * 8);
      if (is32) {
        *reinterpret_cast<uint4*>(&B1[n][kq * 8]) =
            *reinterpret_cast<const uint4*>(W1 + (size_t)n * 512 + k0 + kq * 8);
        *reinterpret_cast<uint4*>(&B2[n][kq * 8]) =
            *reinterpret_cast<const uint4*>(W2 + (size_t)n * 512 + k0 + kq * 8);
      }
    }
    if (is32) {
      const float* Af = (const float*)A;
      #pragma unroll
      for (int it = 0; it < 2; ++it) {
        int idx = t + it * 256;
        int m = idx >> 3, kq = idx & 7;
        float4 a4 = *reinterpret_cast<const float4*>(Af + (size_t)(m0 + m) * HIDK + k0 + kq * 4);
        ushort4 p0, p1, p2;
        bsplit3(a4.x, p0.x, p1.x, p2.x);
        bsplit3(a4.y, p0.y, p1.y, p2.y);
        bsplit3(a4.z, p0.z, p1.z, p2.z);
        bsplit3(a4.w, p0.w, p1.w, p2.w);
        *reinterpret_cast<ushort4*>(&A0[m][kq * 4]) = p0;
        *reinterpret_cast<ushort4*>(&A1[m][kq * 4]) = p1;
        *reinterpret_cast<ushort4*>(&A2[m][kq * 4]) = p2;
      }
    } else {
      #pragma unroll
      for (int it = 0; it < 2; ++it) {
        int idx = t + it * 256;
        int m = idx >> 3, kq = idx & 7;
        uint2 uv = *reinterpret_cast<const uint2*>(A + (size_t)(m0 + m) * (HIDK / 2) + (k0 >> 1) + kq * 2);
        *reinterpret_cast<uint2*>(&A0[m][kq * 4]) = uv;
      }
    }
    __syncthreads();

    bf16x8 a0 = *reinterpret_cast<const bf16x8*>(&A0[w * 16 + r][g * 8]);
    if (is32) {
      bf16x8 a1 = *reinterpret_cast<const bf16x8*>(&A1[w * 16 + r][g * 8]);
      bf16x8 a2 = *reinterpret_cast<const bf16x8*>(&A2[w * 16 + r][g * 8]);
      #pragma unroll
      for (int tn = 0; tn < 4; ++tn) {
        bf16x8 b0 = *reinterpret_cast<const bf16x8*>(&B0[tn * 16 + r][g * 8]);
        bf16x8 b1 = *reinterpret_cast<const bf16x8*>(&B1[tn * 16 + r][g * 8]);
        bf16x8 b2 = *reinterpret_cast<const bf16x8*>(&B2[tn * 16 + r][g * 8]);
        acc[tn] = __builtin_amdgcn_mfma_f32_16x16x32_bf16(a0, b0, acc[tn], 0, 0, 0);
        acc[tn] = __builtin_amdgcn_mfma_f32_16x16x32_bf16(a0, b1, acc[tn], 0, 0, 0);
        acc[tn] = __builtin_amdgcn_mfma_f32_16x16x32_bf16(a1, b0, acc[tn], 0, 0, 0);
        acc[tn] = __builtin_amdgcn_mfma_f32_16x16x32_bf16(a0, b2, acc[tn], 0, 0, 0);
        acc[tn] = __builtin_amdgcn_mfma_f32_16x16x32_bf16(a2, b0, acc[tn], 0, 0, 0);
        acc[tn] = __builtin_amdgcn_mfma_f32_16x16x32_bf16(a1, b1, acc[tn], 0, 0, 0);
      }
    } else {
      #pragma unroll
      for (int tn = 0; tn < 4; ++tn) {
        bf16x8 b0 = *reinterpret_cast<const bf16x8*>(&B0[tn * 16 + r][g * 8]);
        acc[tn] = __builtin_amdgcn_mfma_f32_16x16x32_bf16(a0, b0, acc[tn], 0, 0, 0);
      }
    }
    __syncthreads();
  }

  #pragma unroll
  for (int tn = 0; tn < 4; ++tn)
    #pragma unroll
    for (int rg = 0; rg < 4; ++rg) {
      int m = m0 + w * 16 + g * 4 + rg;
      int b = m >> 12, s = m & 4095;
      vb[((size_t)((b * HH + h) * SS + s)) * DD + tn * 16 + r] = acc[tn][rg];
    }
}

// ---------------------------------------------------------------------------
// Kernel 2: LSH hash. rotS [64][64], float4 LDS reads (R8-proven).
// ---------------------------------------------------------------------------
__global__ __launch_bounds__(256) void k_hash(
    const float* __restrict__ qb, const float* __restrict__ kraw,
    const u32* __restrict__ rots, const int* __restrict__ flag,
    u8* __restrict__ bucketOut)
{
  const int bhn = blockIdx.x;       // 0..63 : (b*8+h)*4+n
  const int which = blockIdx.y;     // 0=q 1=k
  const int squarter = blockIdx.z;  // 0..3
  const int t = threadIdx.x;
  const int bh = bhn >> 2;
  const int h  = bh & 7;
  const int n  = bhn & 3;
  const int is32 = flag[0];

  __shared__ __align__(16) float rotS[64][64];   // [d][r], 16 KB
  if (is32) {
    const float* rf = (const float*)rots;
    #pragma unroll
    for (int it = 0; it < 16; ++it) {
      int idx = t + it * 256;       // 4096 floats
      int d = idx >> 6, r = idx & 63;
      rotS[d][r] = rf[((size_t)((h * 64 + d) * 4 + n)) * 64 + r];
    }
  } else {
    #pragma unroll
    for (int it = 0; it < 8; ++it) {
      int idx = t + it * 256;       // 2048 u32 (4096 bf16)
      int d = idx >> 5, rp = idx & 31;
      u32 uv = rots[((size_t)((h * 64 + d) * 4 + n)) * 32 + rp];
      rotS[d][2 * rp]     = bflo(uv);
      rotS[d][2 * rp + 1] = bfhi(uv);
    }
  }
  __syncthreads();

  const float* src = ((which == 0) ? qb : kraw) + (size_t)bh * SS * DD;
  u8* bout = bucketOut + ((size_t)(which * 64 + bhn)) * SS;

  for (int ii = 0; ii < 4; ++ii) {
    int s = squarter * 1024 + ii * 256 + t;
    const float* row = src + (size_t)s * DD;
    float vec[64];
    #pragma unroll
    for (int d4 = 0; d4 < 16; ++d4) {
      float4 v4 = *reinterpret_cast<const float4*>(row + d4 * 4);
      vec[d4 * 4 + 0] = v4.x; vec[d4 * 4 + 1] = v4.y;
      vec[d4 * 4 + 2] = v4.z; vec[d4 * 4 + 3] = v4.w;
    }
    float bestP = -1e30f, bestN = -1e30f;
    int idxP = 0, idxN = 0;
    #pragma unroll 1
    for (int r0 = 0; r0 < 64; r0 += 16) {
      float acc[16];
      #pragma unroll
      for (int rr = 0; rr < 16; ++rr) acc[rr] = 0.0f;
      #pragma unroll
      for (int d = 0; d < 64; ++d) {
        float vd = vec[d];
        #pragma unroll
        for (int q4 = 0; q4 < 4; ++q4) {
          float4 rv4 = *reinterpret_cast<const float4*>(&rotS[d][r0 + q4 * 4]);
          acc[q4 * 4 + 0] += vd * rv4.x;
          acc[q4 * 4 + 1] += vd * rv4.y;
          acc[q4 * 4 + 2] += vd * rv4.z;
          acc[q4 * 4 + 3] += vd * rv4.w;
        }
      }
      #pragma unroll
      for (int rr = 0; rr < 16; ++rr) {
        float a = acc[rr];
        int r = r0 + rr;
        if (a > bestP) { bestP = a; idxP = r; }
        if (-a > bestN) { bestN = -a; idxN = r; }
      }
    }
    int bucket = (bestP >= bestN) ? idxP : (64 + idxN);
    bout[s] = (u8)bucket;
  }
}

// ---------------------------------------------------------------------------
// Kernel 3: PARALLEL stable counting sort per (b,h,round,which).
// ---------------------------------------------------------------------------
__global__ __launch_bounds__(256) void k_sort(
    const u8* __restrict__ bucketIn, int* __restrict__ sq_pos,
    int* __restrict__ sk_pos, int* __restrict__ sk_rank)
{
  const int bhn = blockIdx.x, which = blockIdx.y;
  const int t = threadIdx.x;
  const int bh = bhn >> 2, n = bhn & 3;
  const int lane = t & 63, w = t >> 6;

  __shared__ u8 bk[4096];
  __shared__ u8 rk[4096];
  __shared__ int chunkh[64 * 128];   // [chunk][bin], 32 KB
  __shared__ int hist[128];
  __shared__ int scanS[128];

  const u8* bin = bucketIn + ((size_t)(which * 64 + bhn)) * SS;
  #pragma unroll
  for (int it = 0; it < 4; ++it)
    ((u32*)bk)[t + it * 256] = ((const u32*)bin)[t + it * 256];
  #pragma unroll
  for (int it = 0; it < 32; ++it) chunkh[t + it * 256] = 0;
  if (t < 128) hist[t] = 0;
  __syncthreads();

  const unsigned long long below = (lane == 0) ? 0ull : (~0ull >> (64 - lane));
  #pragma unroll 1
  for (int k = 0; k < 16; ++k) {
    const int c = w * 16 + k;
    const int s = c * 64 + lane;
    const int b = bk[s];
    unsigned long long m = ~0ull;
    #pragma unroll
    for (int bit = 0; bit < 7; ++bit) {
      unsigned long long vote = __ballot((b >> bit) & 1);
      m &= ((b >> bit) & 1) ? vote : ~vote;
    }
    const int r = (int)__popcll(m & below);
    rk[s] = (u8)r;
    if (r == 0) {
      const int cnt = (int)__popcll(m);
      chunkh[c * 128 + b] = cnt;
      atomicAdd(&hist[b], cnt);
    }
  }
  __syncthreads();

  if (t < 128) scanS[t] = hist[t];
  __syncthreads();
  for (int off = 1; off < 128; off <<= 1) {
    int add = 0;
    if (t < 128 && t >= off) add = scanS[t - off];
    __syncthreads();
    if (t < 128) scanS[t] += add;
    __syncthreads();
  }
  if (t < 128) {
    int run = scanS[t] - hist[t];    // global bin start
    #pragma unroll 1
    for (int c = 0; c < 64; ++c) {
      int v = chunkh[c * 128 + t];
      chunkh[c * 128 + t] = run;
      run += v;
    }
  }
  __syncthreads();

  int* outp = ((which == 0) ? sq_pos : sk_pos) + (size_t)bh * RANKS + n * SS;
  int* rnkp = sk_rank + (size_t)bh * RANKS + n * SS;
  #pragma unroll 1
  for (int k = 0; k < 16; ++k) {
    const int c = w * 16 + k;
    const int s = c * 64 + lane;
    const int b = bk[s];
    const int pos = chunkh[c * 128 + b] + (int)rk[s];
    outp[pos] = s;
    if (which) rnkp[s] = pos;
  }
}

// ---------------------------------------------------------------------------
// Kernel 4: single attention pass. QK^T now on MFMA (2-term bf16 split of Q
// and normalized K; 3 MFMAs hh+hl+lh -> dot rel err ~2e-5, value-path only,
// no argmax downstream). Raw dots go to LDS P; the R8/R9-proven PV/mask/exp
// code is unchanged except it reads accA/accB from P. LDS phase-overlaid:
//   phase 1 (QK): Qh,Ql [64][72]b | Kh,Kl [128][72]b       (55.3 KB)
//   phase 2 (PV): P [64][138]f32  | V [128][68]f32         (70.1 KB)
// ---------------------------------------------------------------------------
__global__ __launch_bounds__(256) void k_attn(
    const float* __restrict__ qb, const float* __restrict__ kraw,
    const float* __restrict__ vb,
    const int* __restrict__ sq_pos, const int* __restrict__ sk_pos,
    const int mode,
    float* __restrict__ outA, float* __restrict__ denA,
    float* __restrict__ numB, float* __restrict__ denB)
{
  const int c = blockIdx.x;
  const int h = blockIdx.y, b = blockIdx.z;
  const int bh = b * HH + h;
  const int t = threadIdx.x;
  const int cprev = (c + NCC - 1) & (NCC - 1);

  __shared__ __align__(16) char smem[70144];
  __shared__ int kposS[128], mposS[128];

  unsigned short* Qh = (unsigned short*)smem;            // [64][72]
  unsigned short* Ql = (unsigned short*)(smem + 9216);   // [64][72]
  unsigned short* Kh = (unsigned short*)(smem + 18432);  // [128][72]
  unsigned short* Kl = (unsigned short*)(smem + 36864);  // [128][72]
  float* Pf = (float*)smem;                              // [64][138]
  float* Vs = (float*)(smem + 35328);                    // [128][68]

  if (t < 128) {
    int slot = (t < 64) ? (cprev * 64 + t) : (c * 64 + (t - 64));
    kposS[t] = sk_pos[(size_t)bh * RANKS + slot];
    mposS[t] = sq_pos[(size_t)bh * RANKS + slot];
  }
  __syncthreads();

  const float* qbase = qb + (size_t)bh * SS * DD;
  const float* kbase = kraw + (size_t)bh * SS * DD;
  const float* vbase = vb + (size_t)bh * SS * DD;

  // stage Q: gather rows, 2-term split
  #pragma unroll
  for (int it = 0; it < 4; ++it) {
    int idx = t + it * 256;
    int i = idx >> 4, d4 = idx & 15;
    float4 q4 = *reinterpret_cast<const float4*>(qbase + (size_t)mposS[64 + i] * DD + d4 * 4);
    ushort4 hh, ll;
    bsplit2(q4.x, hh.x, ll.x); bsplit2(q4.y, hh.y, ll.y);
    bsplit2(q4.z, hh.z, ll.z); bsplit2(q4.w, hh.w, ll.w);
    *reinterpret_cast<ushort4*>(Qh + (size_t)i * 72 + d4 * 4) = hh;
    *reinterpret_cast<ushort4*>(Ql + (size_t)i * 72 + d4 * 4) = ll;
  }
  // stage K: gather rows, normalize (16-lane shuffle row-sumsq), 2-term split
  #pragma unroll
  for (int it = 0; it < 8; ++it) {
    int idx = t + it * 256;
    int j = idx >> 4, d4 = idx & 15;
    float4 k4 = *reinterpret_cast<const float4*>(kbase + (size_t)kposS[j] * DD + d4 * 4);
    float ss = k4.x * k4.x + k4.y * k4.y + k4.z * k4.z + k4.w * k4.w;
    ss += __shfl_xor(ss, 1); ss += __shfl_xor(ss, 2);
    ss += __shfl_xor(ss, 4); ss += __shfl_xor(ss, 8);
    float scj = 0.125f / sqrtf(ss * (1.0f / 64.0f) + 1e-6f);
    k4.x *= scj; k4.y *= scj; k4.z *= scj; k4.w *= scj;
    ushort4 hh, ll;
    bsplit2(k4.x, hh.x, ll.x); bsplit2(k4.y, hh.y, ll.y);
    bsplit2(k4.z, hh.z, ll.z); bsplit2(k4.w, hh.w, ll.w);
    *reinterpret_cast<ushort4*>(Kh + (size_t)j * 72 + d4 * 4) = hh;
    *reinterpret_cast<ushort4*>(Kl + (size_t)j * 72 + d4 * 4) = ll;
  }
  __syncthreads();

  // QK^T via MFMA: wave w owns q-rows w*16..+15; tiles kt over 128 keys.
  // Fragment pattern identical to k_proj_v (R7-proven):
  //   A[row=w*16+r][g*8+ks*32], B[col-row=kt*16+r][g*8+ks*32]
  //   C/D: dots[w*16+g*4+reg][kt*16+r]
  const int w = t >> 6, r = t & 15, g = (t & 63) >> 4;
  f32x4 dacc[8];
  #pragma unroll
  for (int kt = 0; kt < 8; ++kt) {
    f32x4 a; a[0] = 0.f; a[1] = 0.f; a[2] = 0.f; a[3] = 0.f;
    #pragma unroll
    for (int ks = 0; ks < 2; ++ks) {
      const int qo = (w * 16 + r) * 72 + ks * 32 + g * 8;
      const int ko = (kt * 16 + r) * 72 + ks * 32 + g * 8;
      bf16x8 qh_ = *reinterpret_cast<const bf16x8*>(Qh + qo);
      bf16x8 ql_ = *reinterpret_cast<const bf16x8*>(Ql + qo);
      bf16x8 kh_ = *reinterpret_cast<const bf16x8*>(Kh + ko);
      bf16x8 kl_ = *reinterpret_cast<const bf16x8*>(Kl + ko);
      a = __builtin_amdgcn_mfma_f32_16x16x32_bf16(qh_, kh_, a, 0, 0, 0);
      a = __builtin_amdgcn_mfma_f32_16x16x32_bf16(qh_, kl_, a, 0, 0, 0);
      a = __builtin_amdgcn_mfma_f32_16x16x32_bf16(ql_, kh_, a, 0, 0, 0);
    }
    dacc[kt] = a;
  }
  __syncthreads();  // all frag reads done; P/V may overwrite Q/K planes

  // write raw dots to P + stage V
  #pragma unroll
  for (int kt = 0; kt < 8; ++kt)
    #pragma unroll
    for (int rg = 0; rg < 4; ++rg)
      Pf[(size_t)(w * 16 + g * 4 + rg) * 138 + kt * 16 + r] = dacc[kt][rg];
  #pragma unroll
  for (int it = 0; it < 8; ++it) {
    int idx = t + it * 256;
    int j = idx >> 4, d4 = idx & 15;
    *reinterpret_cast<float4*>(Vs + (size_t)j * 68 + d4 * 4) =
        *reinterpret_cast<const float4*>(vbase + (size_t)kposS[j] * DD + d4 * 4);
  }
  __syncthreads();

  // PV: identical to R9 except accA/accB come from P and V from Vs.
  const int i2 = t >> 3;            // row pair 0..31
  const int qr = i2 * 2;
  const int j0 = t & 7;             // key lane 0..7 (keys j0 + 8*jj)
  const int qpa = mposS[64 + qr];
  const int qpb = mposS[64 + qr + 1];

  float accA[16], accB[16];
  #pragma unroll
  for (int jj = 0; jj < 16; ++jj) {
    accA[jj] = Pf[(size_t)qr * 138 + j0 + 8 * jj];
    accB[jj] = Pf[(size_t)(qr + 1) * 138 + j0 + 8 * jj];
  }
  #pragma unroll
  for (int jj = 0; jj < 16; ++jj) {
    int mp = mposS[j0 + 8 * jj];
    if (mp == qpa) accA[jj] = -100000.0f;
    if (mp == qpb) accB[jj] = -100000.0f;
  }
  // un-normalized exp(dot); masked -> expf(-1e5) == 0
  float sa = 0.f, sb = 0.f;
  #pragma unroll
  for (int jj = 0; jj < 16; ++jj) {
    float ea = expf(accA[jj]); accA[jj] = ea; sa += ea;
    float eb = expf(accB[jj]); accB[jj] = eb; sb += eb;
  }
  sa += __shfl_xor(sa, 1); sa += __shfl_xor(sa, 2); sa += __shfl_xor(sa, 4);
  sb += __shfl_xor(sb, 1); sb += __shfl_xor(sb, 2); sb += __shfl_xor(sb, 4);

  const int n = c >> 6;
  if (j0 == 0) {
    if (mode) {
      denB[(size_t)(bh * NHH + n) * SS + (c & 63) * 64 + qr]     = sa;
      denB[(size_t)(bh * NHH + n) * SS + (c & 63) * 64 + qr + 1] = sb;
    } else {
      atomicAdd(&denA[(size_t)bh * SS + kposS[64 + qr]], sa);
      atomicAdd(&denA[(size_t)bh * SS + kposS[64 + qr + 1]], sb);
    }
  }

  // this lane writes row qr + (j0>>2), d-chunk (j0&3)
  const int row = qr + (j0 >> 2);
  float* nrow = mode ? (numB + ((size_t)(bh * NHH + n) * SS + (c & 63) * 64 + row) * DD)
                     : (outA + ((size_t)(b * SS + kposS[64 + row])) * (HH * DD) + h * DD);

  #pragma unroll 1
  for (int db = 0; db < 4; ++db) {
    float4 aA0 = make_float4(0.f, 0.f, 0.f, 0.f);
    float4 aA1 = aA0, aA2 = aA0, aA3 = aA0;
    float4 aB0 = aA0, aB1 = aA0, aB2 = aA0, aB3 = aA0;
    #pragma unroll 4
    for (int jj = 0; jj < 16; ++jj) {
      const float pa = accA[jj];
      const float pb = accB[jj];
      const float* vr = Vs + (size_t)(j0 + 8 * jj) * 68 + db * 16;
      float4 v0 = *reinterpret_cast<const float4*>(vr + 0);
      float4 v1 = *reinterpret_cast<const float4*>(vr + 4);
      float4 v2 = *reinterpret_cast<const float4*>(vr + 8);
      float4 v3 = *reinterpret_cast<const float4*>(vr + 12);
      aA0.x += pa * v0.x; aA0.y += pa * v0.y; aA0.z += pa * v0.z; aA0.w += pa * v0.w;
      aA1.x += pa * v1.x; aA1.y += pa * v1.y; aA1.z += pa * v1.z; aA1.w += pa * v1.w;
      aA2.x += pa * v2.x; aA2.y += pa * v2.y; aA2.z += pa * v2.z; aA2.w += pa * v2.w;
      aA3.x += pa * v3.x; aA3.y += pa * v3.y; aA3.z += pa * v3.z; aA3.w += pa * v3.w;
      aB0.x += pb * v0.x; aB0.y += pb * v0.y; aB0.z += pb * v0.z; aB0.w += pb * v0.w;
      aB1.x += pb * v1.x; aB1.y += pb * v1.y; aB1.z += pb * v1.z; aB1.w += pb * v1.w;
      aB2.x += pb * v2.x; aB2.y += pb * v2.y; aB2.z += pb * v2.z; aB2.w += pb * v2.w;
      aB3.x += pb * v3.x; aB3.y += pb * v3.y; aB3.z += pb * v3.z; aB3.w += pb * v3.w;
    }
    #pragma unroll
    for (int st = 1; st <= 4; st <<= 1) {
      aA0.x += __shfl_xor(aA0.x, st); aA0.y += __shfl_xor(aA0.y, st);
      aA0.z += __shfl_xor(aA0.z, st); aA0.w += __shfl_xor(aA0.w, st);
      aA1.x += __shfl_xor(aA1.x, st); aA1.y += __shfl_xor(aA1.y, st);
      aA1.z += __shfl_xor(aA1.z, st); aA1.w += __shfl_xor(aA1.w, st);
      aA2.x += __shfl_xor(aA2.x, st); aA2.y += __shfl_xor(aA2.y, st);
      aA2.z += __shfl_xor(aA2.z, st); aA2.w += __shfl_xor(aA2.w, st);
      aA3.x += __shfl_xor(aA3.x, st); aA3.y += __shfl_xor(aA3.y, st);
      aA3.z += __shfl_xor(aA3.z, st); aA3.w += __shfl_xor(aA3.w, st);
      aB0.x += __shfl_xor(aB0.x, st); aB0.y += __shfl_xor(aB0.y, st);
      aB0.z += __shfl_xor(aB0.z, st); aB0.w += __shfl_xor(aB0.w, st);
      aB1.x += __shfl_xor(aB1.x, st); aB1.y += __shfl_xor(aB1.y, st);
      aB1.z += __shfl_xor(aB1.z, st); aB1.w += __shfl_xor(aB1.w, st);
      aB2.x += __shfl_xor(aB2.x, st); aB2.y += __shfl_xor(aB2.y, st);
      aB2.z += __shfl_xor(aB2.z, st); aB2.w += __shfl_xor(aB2.w, st);
      aB3.x += __shfl_xor(aB3.x, st); aB3.y += __shfl_xor(aB3.y, st);
      aB3.z += __shfl_xor(aB3.z, st); aB3.w += __shfl_xor(aB3.w, st);
    }
    // static selection (no runtime-indexed register arrays)
    float4 m0_ = (j0 & 4) ? aB0 : aA0;
    float4 m1_ = (j0 & 4) ? aB1 : aA1;
    float4 m2_ = (j0 & 4) ? aB2 : aA2;
    float4 m3_ = (j0 & 4) ? aB3 : aA3;
    float4 mine = (j0 & 2) ? ((j0 & 1) ? m3_ : m2_) : ((j0 & 1) ? m1_ : m0_);
    if (mode) {
      *reinterpret_cast<float4*>(nrow + db * 16 + (j0 & 3) * 4) = mine;
    } else {
      float* p = nrow + db * 16 + (j0 & 3) * 4;
      atomicAdd(&p[0], mine.x);
      atomicAdd(&p[1], mine.y);
      atomicAdd(&p[2], mine.z);
      atomicAdd(&p[3], mine.w);
    }
  }
}

// ---------------------------------------------------------------------------
// Kernel 5 (big-ws path): gather-combine.
// ---------------------------------------------------------------------------
__global__ __launch_bounds__(256) void k_combine(
    const float* __restrict__ numB, const float* __restrict__ denB,
    const int* __restrict__ sk_rank, float* __restrict__ outp)
{
  const int bh = blockIdx.y;
  const int s = blockIdx.x * 16 + (threadIdx.x >> 4);
  const int lane = threadIdx.x & 15;
  const int b = bh >> 3, h = bh & 7;
  float4 acc = make_float4(0.f, 0.f, 0.f, 0.f);
  float den = 0.f;
  #pragma unroll
  for (int n = 0; n < NHH; ++n) {
    int r = sk_rank[(size_t)bh * RANKS + n * SS + s];
    size_t rowi = (size_t)(bh * NHH + n) * SS + r;
    float4 v = *reinterpret_cast<const float4*>(numB + rowi * DD + lane * 4);
    acc.x += v.x; acc.y += v.y; acc.z += v.z; acc.w += v.w;
    den += denB[rowi];
  }
  float inv = 1.0f / den;
  acc.x *= inv; acc.y *= inv; acc.z *= inv; acc.w *= inv;
  *reinterpret_cast<float4*>(outp + ((size_t)(b * SS + s)) * (HH * DD) + h * DD + lane * 4) = acc;
}

// ---------------------------------------------------------------------------
// Kernel 5' (fallback path): divide accumulated numerator by denominator.
// ---------------------------------------------------------------------------
__global__ __launch_bounds__(256) void k_div(
    const float* __restrict__ den, float* __restrict__ outp)
{
  int idx = blockIdx.x * 256 + threadIdx.x;  // grid 4096 -> 1,048,576 float4
  int f = idx * 4;
  int col = f & 511;
  int h = col >> 6;
  int srow = f >> 9;                          // b*4096+s
  int b = srow >> 12, s = srow & 4095;
  float inv = 1.0f / den[(size_t)(b * HH + h) * SS + s];
  float4 v = *reinterpret_cast<float4*>(outp + (size_t)f);
  v.x *= inv; v.y *= inv; v.z *= inv; v.w *= inv;
  *reinterpret_cast<float4*>(outp + (size_t)f) = v;
}

// ---------------------------------------------------------------------------
// Kernel Z: zero the fp32 output (fallback path; harness poisons d_out).
// ---------------------------------------------------------------------------
__global__ __launch_bounds__(256) void k_zero_out(float* __restrict__ outp)
{
  int flat = blockIdx.x * 256 + threadIdx.x;  // grid 4096 -> 1,048,576 float4
  float4 z = make_float4(0.f, 0.f, 0.f, 0.f);
  *reinterpret_cast<float4*>(outp + (size_t)flat * 4) = z;
}

// ---------------------------------------------------------------------------
extern "C" void kernel_launch(void* const* d_in, const int* in_sizes, int n_in,
                              void* d_out, int out_size, void* d_ws, size_t ws_size,
                              hipStream_t stream)
{
  (void)in_sizes; (void)n_in; (void)out_size;
  const u32* dec = (const u32*)d_in[0];
  const u32* hid = (const u32*)d_in[1];
  const u32* wqk = (const u32*)d_in[2];
  const u32* wv  = (const u32*)d_in[3];
  const u32* rot = (const u32*)d_in[4];

  const size_t QKV  = (size_t)BB * HH * SS * DD;   // 4,194,304 elems
  const size_t LOGU = (size_t)BB * HH * NHH * SS;  // 262,144

  float* qb      = (float*)d_ws;
  float* kraw    = qb + QKV;
  float* vb      = kraw + QKV;
  float* den     = vb + QKV;                  // LOGU floats
  int*   sq_pos  = (int*)(den + LOGU);
  int*   sk_pos  = sq_pos + LOGU;
  int*   sk_rank = sk_pos + LOGU;
  u8*    buckets = (u8*)(sk_rank + LOGU);
  int*   flag    = (int*)(buckets + (size_t)2 * 64 * SS);
  const size_t numb_off = 55050496;           // align_up(low region, 256)
  float* numb    = (float*)((char*)d_ws + numb_off);
  // wt planes live INSIDE the numb region (numb not yet live during proj):
  unsigned short* wt0 = (unsigned short*)numb;
  unsigned short* wt1 = wt0 + (size_t)2 * 512 * 512;
  unsigned short* wt2 = wt1 + (size_t)2 * 512 * 512;
  const size_t need_big = numb_off + (size_t)NHH * QKV * sizeof(float);  // 122,159,360
  const int big = (ws_size >= need_big) ? 1 : 0;

  hipMemsetAsync(flag, 0, sizeof(int), stream);
  k_detect<<<dim3(512), 256, 0, stream>>>(wqk, flag);
  k_prep<<<dim3(256, 2), 256, 0, stream>>>(wqk, wv, flag, wt0, wt1, wt2);
  // q,k: scalar (hash-feeding, bit-identical accumulation). v: MFMA (R7-proven).
  k_proj_s<<<dim3(128, 8, 2), 256, 0, stream>>>(dec, hid, wqk, wv, flag, qb, kraw, vb);
  k_proj_v<<<dim3(1024), 256, 0, stream>>>(hid, wt0, wt1, wt2, flag, vb);
  k_hash<<<dim3(64, 2, 4), 256, 0, stream>>>(qb, kraw, rot, flag, buckets);
  k_sort<<<dim3(64, 2), 256, 0, stream>>>(buckets, sq_pos, sk_pos, sk_rank);

  if (big) {
    k_attn<<<dim3(NCC, HH, BB), 256, 0, stream>>>(
        qb, kraw, vb, sq_pos, sk_pos, 1, nullptr, nullptr, numb, den);
    k_combine<<<dim3(SS / 16, BB * HH), 256, 0, stream>>>(
        numb, den, sk_rank, (float*)d_out);
  } else {
    hipMemsetAsync(den, 0, (size_t)BB * HH * SS * sizeof(float), stream);
    k_zero_out<<<dim3(4096), 256, 0, stream>>>((float*)d_out);
    k_attn<<<dim3(NCC, HH, BB), 256, 0, stream>>>(
        qb, kraw, vb, sq_pos, sk_pos, 0, (float*)d_out, den, nullptr, nullptr);
    k_div<<<dim3(4096), 256, 0, stream>>>(den, (float*)d_out);
  }
}

// Round 11
// 541.421 us; speedup vs baseline: 3.5541x; 1.1190x over previous
//
#include <hip/hip_runtime.h>
#include <math.h>

#define BB 2
#define SS 4096
#define HIDK 512
#define HH 8
#define DD 64
#define NHH 4
#define NCC 256      // chunks per (b,h) = NH*S/CHUNK
#define RANKS 16384  // NH*S

typedef unsigned int u32;
typedef unsigned char u8;
typedef __attribute__((ext_vector_type(8))) short bf16x8;
typedef __attribute__((ext_vector_type(4))) float f32x4;

__device__ __forceinline__ float bflo(u32 u){ return __uint_as_float(u << 16); }
__device__ __forceinline__ float bfhi(u32 u){ return __uint_as_float(u & 0xffff0000u); }

// RN fp32 -> bf16 (top of x)
__device__ __forceinline__ unsigned short brn(float x)
{
  u32 u = __float_as_uint(x);
  u32 r = u + 0x7FFFu + ((u >> 16) & 1u);
  return (unsigned short)(r >> 16);
}

// 2-term bf16 split: x ~= b0 + b1 (residual ~2^-17 |x|).
__device__ __forceinline__ void bsplit2(float x, unsigned short& b0, unsigned short& b1)
{
  b0 = brn(x);
  float x1 = x - __uint_as_float((u32)b0 << 16);
  b1 = brn(x1);
}

// 3-term bf16 split: x ~= b0 + b1 + b2 (Sterbenz-exact residuals).
__device__ __forceinline__ void bsplit3(float x, unsigned short& b0, unsigned short& b1, unsigned short& b2)
{
  b0 = brn(x);
  float x1 = x - __uint_as_float((u32)b0 << 16);
  b1 = brn(x1);
  float x2 = x1 - __uint_as_float((u32)b1 << 16);
  b2 = brn(x2);
}

// ---------------------------------------------------------------------------
// Kernel 0: input dtype detection (bf16 vs fp32 bit patterns in w_qk).
// ---------------------------------------------------------------------------
__global__ __launch_bounds__(256) void k_detect(const u32* __restrict__ w, int* __restrict__ flag)
{
  int i = blockIdx.x * 256 + threadIdx.x;   // grid 512 -> 131072 u32
  float lo = bflo(w[i]);
  bool bad = !(fabsf(lo) <= 1024.0f);       // true also for NaN
  if (__any(bad)) {
    if ((threadIdx.x & 63) == 0) atomicOr(flag, 1);
  }
}

// ---------------------------------------------------------------------------
// Kernel P: prep weights. Transpose W[k][n] -> Wt[n][k], 3-term bf16 split
// for fp32 inputs. wt*: [2][512][512] u16 (plane 0 = wqk, 1 = wv).
// ---------------------------------------------------------------------------
__global__ __launch_bounds__(256) void k_prep(
    const u32* __restrict__ wqk, const u32* __restrict__ wv,
    const int* __restrict__ flag,
    unsigned short* __restrict__ wt0, unsigned short* __restrict__ wt1,
    unsigned short* __restrict__ wt2)
{
  const int which = blockIdx.y;
  const u32* W = which ? wv : wqk;
  const int tk = blockIdx.x >> 4, tn = blockIdx.x & 15;
  const int t = threadIdx.x;
  const int is32 = flag[0];
  __shared__ unsigned short h0s[32][36];
  __shared__ unsigned short h1s[32][36];
  __shared__ unsigned short h2s[32][36];
  if (is32) {
    const float* Wf = (const float*)W;
    #pragma unroll
    for (int it = 0; it < 4; ++it) {
      int idx = t + it * 256;           // 1024 = 32 k x 32 n
      int kk = idx >> 5, nn = idx & 31;
      float x = Wf[(size_t)(tk * 32 + kk) * 512 + tn * 32 + nn];
      bsplit3(x, h0s[kk][nn], h1s[kk][nn], h2s[kk][nn]);
    }
  } else {
    #pragma unroll
    for (int it = 0; it < 2; ++it) {
      int idx = t + it * 256;           // 512 u32 = 32 k x 16 pairs
      int kk = idx >> 4, np = idx & 15;
      u32 uv = W[(size_t)(tk * 32 + kk) * 256 + tn * 16 + np];
      h0s[kk][2 * np]     = (unsigned short)(uv & 0xffffu);
      h0s[kk][2 * np + 1] = (unsigned short)(uv >> 16);
      h1s[kk][2 * np] = 0; h1s[kk][2 * np + 1] = 0;
      h2s[kk][2 * np] = 0; h2s[kk][2 * np + 1] = 0;
    }
  }
  __syncthreads();
  size_t obase = ((size_t)which * 512 + tn * 32) * 512 + tk * 32;
  #pragma unroll
  for (int it = 0; it < 4; ++it) {
    int idx = t + it * 256;
    int nn = idx >> 5, kk = idx & 31;
    wt0[obase + (size_t)nn * 512 + kk] = h0s[kk][nn];
    wt1[obase + (size_t)nn * 512 + kk] = h1s[kk][nn];
    wt2[obase + (size_t)nn * 512 + kk] = h2s[kk][nn];
  }
}

// ---------------------------------------------------------------------------
// Kernel 1a: SCALAR projections for q and k (hash-feeding).
// Accumulation bit-identical to the R0-R2/R7-R10-proven kernel.
// ---------------------------------------------------------------------------
__global__ __launch_bounds__(256) void k_proj_s(
    const u32* __restrict__ dec, const u32* __restrict__ hid,
    const u32* __restrict__ wqk, const u32* __restrict__ wv,
    const int* __restrict__ flag,
    float* __restrict__ qb, float* __restrict__ kraw, float* __restrict__ vb)
{
  const int which = blockIdx.z;
  const u32* A = (which == 0) ? dec : hid;
  const u32* W = (which == 2) ? wv : wqk;
  const int m0 = blockIdx.x * 64;
  const int h  = blockIdx.y;
  const int t  = threadIdx.x;
  const int ty = t >> 4, tx = t & 15;
  const int is32 = flag[0];

  __shared__ __align__(16) float AsT[32][68];  // [kk][row i]; 272B stride
  __shared__ __align__(16) float Wst[32][64];  // [kk][col c]

  float acc[4][4];
  #pragma unroll
  for (int r = 0; r < 4; ++r)
    #pragma unroll
    for (int c = 0; c < 4; ++c) acc[r][c] = 0.0f;

  for (int k0 = 0; k0 < HIDK; k0 += 32) {
    if (is32) {
      const float* Af = (const float*)A;
      const float* Wf = (const float*)W;
      #pragma unroll
      for (int it = 0; it < 8; ++it) {
        int idx = t + it * 256;          // 2048: 64 rows x 32 k
        int i = idx >> 5, kk = idx & 31;
        AsT[kk][i] = Af[(size_t)(m0 + i) * HIDK + k0 + kk];
      }
      #pragma unroll
      for (int it = 0; it < 8; ++it) {
        int idx = t + it * 256;          // 2048: 32 k x 64 cols, c-fast
        int kk = idx >> 6, c = idx & 63;
        Wst[kk][c] = Wf[(size_t)(k0 + kk) * HIDK + h * 64 + c];
      }
    } else {
      #pragma unroll
      for (int it = 0; it < 4; ++it) {
        int idx = t + it * 256;          // 1024: A tile 64 rows x 16 u32
        int i = idx >> 4, kp = idx & 15;
        u32 uv = A[(size_t)(m0 + i) * (HIDK / 2) + (k0 >> 1) + kp];
        AsT[2 * kp][i]     = bflo(uv);
        AsT[2 * kp + 1][i] = bfhi(uv);
      }
      #pragma unroll
      for (int it = 0; it < 4; ++it) {
        int idx = t + it * 256;          // 1024: W tile 32 k x 32 u32, cp-fast
        int kk = idx >> 5, cp = idx & 31;
        u32 uv = W[(size_t)(k0 + kk) * (HIDK / 2) + h * 32 + cp];
        Wst[kk][2 * cp]     = bflo(uv);
        Wst[kk][2 * cp + 1] = bfhi(uv);
      }
    }
    __syncthreads();
    for (int kk = 0; kk < 32; ++kk) {
      float4 a4 = *reinterpret_cast<const float4*>(&AsT[kk][ty * 4]);  // rows ty*4..+3
      float4 w4 = *reinterpret_cast<const float4*>(&Wst[kk][tx * 4]);  // cols tx*4..+3
      acc[0][0] += a4.x * w4.x; acc[0][1] += a4.x * w4.y; acc[0][2] += a4.x * w4.z; acc[0][3] += a4.x * w4.w;
      acc[1][0] += a4.y * w4.x; acc[1][1] += a4.y * w4.y; acc[1][2] += a4.y * w4.z; acc[1][3] += a4.y * w4.w;
      acc[2][0] += a4.z * w4.x; acc[2][1] += a4.z * w4.y; acc[2][2] += a4.z * w4.z; acc[2][3] += a4.z * w4.w;
      acc[3][0] += a4.w * w4.x; acc[3][1] += a4.w * w4.y; acc[3][2] += a4.w * w4.z; acc[3][3] += a4.w * w4.w;
    }
    __syncthreads();
  }

  float* outp = (which == 0) ? qb : ((which == 1) ? kraw : vb);
  #pragma unroll
  for (int r = 0; r < 4; ++r) {
    int m = m0 + ty * 4 + r;
    int b = m >> 12, s = m & 4095;
    float4 o;
    o.x = acc[r][0]; o.y = acc[r][1]; o.z = acc[r][2]; o.w = acc[r][3];
    *reinterpret_cast<float4*>(outp + ((size_t)((b * HH + h) * SS + s)) * DD + tx * 4) = o;
  }
}

// ---------------------------------------------------------------------------
// Kernel 1b: MFMA projection for V ONLY (v = hid @ wv). R7-proven.
// ---------------------------------------------------------------------------
__global__ __launch_bounds__(256) void k_proj_v(
    const u32* __restrict__ hid,
    const unsigned short* __restrict__ wt0, const unsigned short* __restrict__ wt1,
    const unsigned short* __restrict__ wt2,
    const int* __restrict__ flag,
    float* __restrict__ vb)
{
  const int bid = blockIdx.x;              // grid 1024 = 8 x 128
  const int x = bid & 7, l = bid >> 3;     // l in [0,128)
  const int h = l & 7;
  const int m0 = (x * 16 + ((l >> 3) & 15)) * 64;
  const int t = threadIdx.x;
  const int w = t >> 6;
  const int r = t & 15, g = (t & 63) >> 4;
  const int is32 = flag[0];

  const u32* A = hid;
  const size_t wbase = (size_t)1 * 512 * 512 + (size_t)h * 64 * 512;  // wv plane
  const unsigned short* W0 = wt0 + wbase;
  const unsigned short* W1 = wt1 + wbase;
  const unsigned short* W2 = wt2 + wbase;

  __shared__ __align__(16) unsigned short A0[64][40];  // stride 80B
  __shared__ __align__(16) unsigned short A1[64][40];
  __shared__ __align__(16) unsigned short A2[64][40];
  __shared__ __align__(16) unsigned short B0[64][40];
  __shared__ __align__(16) unsigned short B1[64][40];
  __shared__ __align__(16) unsigned short B2[64][40];

  f32x4 acc[4];
  #pragma unroll
  for (int tn = 0; tn < 4; ++tn) { acc[tn][0] = 0.f; acc[tn][1] = 0.f; acc[tn][2] = 0.f; acc[tn][3] = 0.f; }

  for (int k0 = 0; k0 < HIDK; k0 += 32) {
    {
      const int n = t >> 2, kq = t & 3;
      *reinterpret_cast<uint4*>(&B0[n][kq * 8]) =
          *reinterpret_cast<const uint4*>(W0 + (size_t)n * 512 + k0 + kq * 8);
      if (is32) {
        *reinterpret_cast<uint4*>(&B1[n][kq * 8]) =
            *reinterpret_cast<const uint4*>(W1 + (size_t)n * 512 + k0 + kq * 8);
        *reinterpret_cast<uint4*>(&B2[n][kq * 8]) =
            *reinterpret_cast<const uint4*>(W2 + (size_t)n * 512 + k0 + kq * 8);
      }
    }
    if (is32) {
      const float* Af = (const float*)A;
      #pragma unroll
      for (int it = 0; it < 2; ++it) {
        int idx = t + it * 256;
        int m = idx >> 3, kq = idx & 7;
        float4 a4 = *reinterpret_cast<const float4*>(Af + (size_t)(m0 + m) * HIDK + k0 + kq * 4);
        ushort4 p0, p1, p2;
        bsplit3(a4.x, p0.x, p1.x, p2.x);
        bsplit3(a4.y, p0.y, p1.y, p2.y);
        bsplit3(a4.z, p0.z, p1.z, p2.z);
        bsplit3(a4.w, p0.w, p1.w, p2.w);
        *reinterpret_cast<ushort4*>(&A0[m][kq * 4]) = p0;
        *reinterpret_cast<ushort4*>(&A1[m][kq * 4]) = p1;
        *reinterpret_cast<ushort4*>(&A2[m][kq * 4]) = p2;
      }
    } else {
      #pragma unroll
      for (int it = 0; it < 2; ++it) {
        int idx = t + it * 256;
        int m = idx >> 3, kq = idx & 7;
        uint2 uv = *reinterpret_cast<const uint2*>(A + (size_t)(m0 + m) * (HIDK / 2) + (k0 >> 1) + kq * 2);
        *reinterpret_cast<uint2*>(&A0[m][kq * 4]) = uv;
      }
    }
    __syncthreads();

    bf16x8 a0 = *reinterpret_cast<const bf16x8*>(&A0[w * 16 + r][g * 8]);
    if (is32) {
      bf16x8 a1 = *reinterpret_cast<const bf16x8*>(&A1[w * 16 + r][g * 8]);
      bf16x8 a2 = *reinterpret_cast<const bf16x8*>(&A2[w * 16 + r][g * 8]);
      #pragma unroll
      for (int tn = 0; tn < 4; ++tn) {
        bf16x8 b0 = *reinterpret_cast<const bf16x8*>(&B0[tn * 16 + r][g * 8]);
        bf16x8 b1 = *reinterpret_cast<const bf16x8*>(&B1[tn * 16 + r][g * 8]);
        bf16x8 b2 = *reinterpret_cast<const bf16x8*>(&B2[tn * 16 + r][g * 8]);
        acc[tn] = __builtin_amdgcn_mfma_f32_16x16x32_bf16(a0, b0, acc[tn], 0, 0, 0);
        acc[tn] = __builtin_amdgcn_mfma_f32_16x16x32_bf16(a0, b1, acc[tn], 0, 0, 0);
        acc[tn] = __builtin_amdgcn_mfma_f32_16x16x32_bf16(a1, b0, acc[tn], 0, 0, 0);
        acc[tn] = __builtin_amdgcn_mfma_f32_16x16x32_bf16(a0, b2, acc[tn], 0, 0, 0);
        acc[tn] = __builtin_amdgcn_mfma_f32_16x16x32_bf16(a2, b0, acc[tn], 0, 0, 0);
        acc[tn] = __builtin_amdgcn_mfma_f32_16x16x32_bf16(a1, b1, acc[tn], 0, 0, 0);
      }
    } else {
      #pragma unroll
      for (int tn = 0; tn < 4; ++tn) {
        bf16x8 b0 = *reinterpret_cast<const bf16x8*>(&B0[tn * 16 + r][g * 8]);
        acc[tn] = __builtin_amdgcn_mfma_f32_16x16x32_bf16(a0, b0, acc[tn], 0, 0, 0);
      }
    }
    __syncthreads();
  }

  #pragma unroll
  for (int tn = 0; tn < 4; ++tn)
    #pragma unroll
    for (int rg = 0; rg < 4; ++rg) {
      int m = m0 + w * 16 + g * 4 + rg;
      int b = m >> 12, s = m & 4095;
      vb[((size_t)((b * HH + h) * SS + s)) * DD + tn * 16 + r] = acc[tn][rg];
    }
}

// ---------------------------------------------------------------------------
// Kernel 2: LSH hash. rotS [64][64], float4 LDS reads (R8-proven).
// ---------------------------------------------------------------------------
__global__ __launch_bounds__(256) void k_hash(
    const float* __restrict__ qb, const float* __restrict__ kraw,
    const u32* __restrict__ rots, const int* __restrict__ flag,
    u8* __restrict__ bucketOut)
{
  const int bhn = blockIdx.x;       // 0..63 : (b*8+h)*4+n
  const int which = blockIdx.y;     // 0=q 1=k
  const int squarter = blockIdx.z;  // 0..3
  const int t = threadIdx.x;
  const int bh = bhn >> 2;
  const int h  = bh & 7;
  const int n  = bhn & 3;
  const int is32 = flag[0];

  __shared__ __align__(16) float rotS[64][64];   // [d][r], 16 KB
  if (is32) {
    const float* rf = (const float*)rots;
    #pragma unroll
    for (int it = 0; it < 16; ++it) {
      int idx = t + it * 256;       // 4096 floats
      int d = idx >> 6, r = idx & 63;
      rotS[d][r] = rf[((size_t)((h * 64 + d) * 4 + n)) * 64 + r];
    }
  } else {
    #pragma unroll
    for (int it = 0; it < 8; ++it) {
      int idx = t + it * 256;       // 2048 u32 (4096 bf16)
      int d = idx >> 5, rp = idx & 31;
      u32 uv = rots[((size_t)((h * 64 + d) * 4 + n)) * 32 + rp];
      rotS[d][2 * rp]     = bflo(uv);
      rotS[d][2 * rp + 1] = bfhi(uv);
    }
  }
  __syncthreads();

  const float* src = ((which == 0) ? qb : kraw) + (size_t)bh * SS * DD;
  u8* bout = bucketOut + ((size_t)(which * 64 + bhn)) * SS;

  for (int ii = 0; ii < 4; ++ii) {
    int s = squarter * 1024 + ii * 256 + t;
    const float* row = src + (size_t)s * DD;
    float vec[64];
    #pragma unroll
    for (int d4 = 0; d4 < 16; ++d4) {
      float4 v4 = *reinterpret_cast<const float4*>(row + d4 * 4);
      vec[d4 * 4 + 0] = v4.x; vec[d4 * 4 + 1] = v4.y;
      vec[d4 * 4 + 2] = v4.z; vec[d4 * 4 + 3] = v4.w;
    }
    float bestP = -1e30f, bestN = -1e30f;
    int idxP = 0, idxN = 0;
    #pragma unroll 1
    for (int r0 = 0; r0 < 64; r0 += 16) {
      float acc[16];
      #pragma unroll
      for (int rr = 0; rr < 16; ++rr) acc[rr] = 0.0f;
      #pragma unroll
      for (int d = 0; d < 64; ++d) {
        float vd = vec[d];
        #pragma unroll
        for (int q4 = 0; q4 < 4; ++q4) {
          float4 rv4 = *reinterpret_cast<const float4*>(&rotS[d][r0 + q4 * 4]);
          acc[q4 * 4 + 0] += vd * rv4.x;
          acc[q4 * 4 + 1] += vd * rv4.y;
          acc[q4 * 4 + 2] += vd * rv4.z;
          acc[q4 * 4 + 3] += vd * rv4.w;
        }
      }
      #pragma unroll
      for (int rr = 0; rr < 16; ++rr) {
        float a = acc[rr];
        int r = r0 + rr;
        if (a > bestP) { bestP = a; idxP = r; }
        if (-a > bestN) { bestN = -a; idxN = r; }
      }
    }
    int bucket = (bestP >= bestN) ? idxP : (64 + idxN);
    bout[s] = (u8)bucket;
  }
}

// ---------------------------------------------------------------------------
// Kernel 3: PARALLEL stable counting sort per (b,h,round,which).
// ---------------------------------------------------------------------------
__global__ __launch_bounds__(256) void k_sort(
    const u8* __restrict__ bucketIn, int* __restrict__ sq_pos,
    int* __restrict__ sk_pos, int* __restrict__ sk_rank)
{
  const int bhn = blockIdx.x, which = blockIdx.y;
  const int t = threadIdx.x;
  const int bh = bhn >> 2, n = bhn & 3;
  const int lane = t & 63, w = t >> 6;

  __shared__ u8 bk[4096];
  __shared__ u8 rk[4096];
  __shared__ int chunkh[64 * 128];   // [chunk][bin], 32 KB
  __shared__ int hist[128];
  __shared__ int scanS[128];

  const u8* bin = bucketIn + ((size_t)(which * 64 + bhn)) * SS;
  #pragma unroll
  for (int it = 0; it < 4; ++it)
    ((u32*)bk)[t + it * 256] = ((const u32*)bin)[t + it * 256];
  #pragma unroll
  for (int it = 0; it < 32; ++it) chunkh[t + it * 256] = 0;
  if (t < 128) hist[t] = 0;
  __syncthreads();

  const unsigned long long below = (lane == 0) ? 0ull : (~0ull >> (64 - lane));
  #pragma unroll 1
  for (int k = 0; k < 16; ++k) {
    const int c = w * 16 + k;
    const int s = c * 64 + lane;
    const int b = bk[s];
    unsigned long long m = ~0ull;
    #pragma unroll
    for (int bit = 0; bit < 7; ++bit) {
      unsigned long long vote = __ballot((b >> bit) & 1);
      m &= ((b >> bit) & 1) ? vote : ~vote;
    }
    const int r = (int)__popcll(m & below);
    rk[s] = (u8)r;
    if (r == 0) {
      const int cnt = (int)__popcll(m);
      chunkh[c * 128 + b] = cnt;
      atomicAdd(&hist[b], cnt);
    }
  }
  __syncthreads();

  if (t < 128) scanS[t] = hist[t];
  __syncthreads();
  for (int off = 1; off < 128; off <<= 1) {
    int add = 0;
    if (t < 128 && t >= off) add = scanS[t - off];
    __syncthreads();
    if (t < 128) scanS[t] += add;
    __syncthreads();
  }
  if (t < 128) {
    int run = scanS[t] - hist[t];    // global bin start
    #pragma unroll 1
    for (int c = 0; c < 64; ++c) {
      int v = chunkh[c * 128 + t];
      chunkh[c * 128 + t] = run;
      run += v;
    }
  }
  __syncthreads();

  int* outp = ((which == 0) ? sq_pos : sk_pos) + (size_t)bh * RANKS + n * SS;
  int* rnkp = sk_rank + (size_t)bh * RANKS + n * SS;
  #pragma unroll 1
  for (int k = 0; k < 16; ++k) {
    const int c = w * 16 + k;
    const int s = c * 64 + lane;
    const int b = bk[s];
    const int pos = chunkh[c * 128 + b] + (int)rk[s];
    outp[pos] = s;
    if (which) rnkp[s] = pos;
  }
}

// ---------------------------------------------------------------------------
// Kernel 4: single attention pass, BOTH matmuls on MFMA.
//   QK: 2-term bf16 split of Q and normalized K, 3 MFMAs (R10-proven).
//   PV: P = exp(dots) 2-term split x V 2-term split, 3 MFMAs; den exact fp32.
// LDS overlay (byte offsets):
//   phase A: Qh@0 Ql@9216 [64][72]u16, Kh@18432 Kl@36864 [128][72]u16 (55.3KB)
//   phase B: Ph@0 Pl@17408 [64][136]u16, Vth@34816 Vtl@52224 [64][136]u16 (69.6KB)
// C/D layouts use the HW-verified col=lane&15, row=(lane>>4)*4+reg mapping.
// ---------------------------------------------------------------------------
__global__ __launch_bounds__(256) void k_attn(
    const float* __restrict__ qb, const float* __restrict__ kraw,
    const float* __restrict__ vb,
    const int* __restrict__ sq_pos, const int* __restrict__ sk_pos,
    const int mode,
    float* __restrict__ outA, float* __restrict__ denA,
    float* __restrict__ numB, float* __restrict__ denB)
{
  const int c = blockIdx.x;
  const int h = blockIdx.y, b = blockIdx.z;
  const int bh = b * HH + h;
  const int t = threadIdx.x;
  const int cprev = (c + NCC - 1) & (NCC - 1);

  __shared__ __align__(16) char smem[69632];
  __shared__ int kposS[128], mposS[128];

  unsigned short* Qh = (unsigned short*)smem;            // [64][72]
  unsigned short* Ql = (unsigned short*)(smem + 9216);   // [64][72]
  unsigned short* Kh = (unsigned short*)(smem + 18432);  // [128][72]
  unsigned short* Kl = (unsigned short*)(smem + 36864);  // [128][72]
  unsigned short* Ph  = (unsigned short*)smem;           // [64][136]
  unsigned short* Pl  = (unsigned short*)(smem + 17408); // [64][136]
  unsigned short* Vth = (unsigned short*)(smem + 34816); // [64][136]
  unsigned short* Vtl = (unsigned short*)(smem + 52224); // [64][136]

  if (t < 128) {
    int slot = (t < 64) ? (cprev * 64 + t) : (c * 64 + (t - 64));
    kposS[t] = sk_pos[(size_t)bh * RANKS + slot];
    mposS[t] = sq_pos[(size_t)bh * RANKS + slot];
  }
  __syncthreads();

  const float* qbase = qb + (size_t)bh * SS * DD;
  const float* kbase = kraw + (size_t)bh * SS * DD;
  const float* vbase = vb + (size_t)bh * SS * DD;

  // stage Q: gather rows, 2-term split
  #pragma unroll
  for (int it = 0; it < 4; ++it) {
    int idx = t + it * 256;
    int i = idx >> 4, d4 = idx & 15;
    float4 q4 = *reinterpret_cast<const float4*>(qbase + (size_t)mposS[64 + i] * DD + d4 * 4);
    ushort4 hh, ll;
    bsplit2(q4.x, hh.x, ll.x); bsplit2(q4.y, hh.y, ll.y);
    bsplit2(q4.z, hh.z, ll.z); bsplit2(q4.w, hh.w, ll.w);
    *reinterpret_cast<ushort4*>(Qh + (size_t)i * 72 + d4 * 4) = hh;
    *reinterpret_cast<ushort4*>(Ql + (size_t)i * 72 + d4 * 4) = ll;
  }
  // stage K: gather rows, normalize (16-lane shuffle row-sumsq), 2-term split
  #pragma unroll
  for (int it = 0; it < 8; ++it) {
    int idx = t + it * 256;
    int j = idx >> 4, d4 = idx & 15;
    float4 k4 = *reinterpret_cast<const float4*>(kbase + (size_t)kposS[j] * DD + d4 * 4);
    float ss = k4.x * k4.x + k4.y * k4.y + k4.z * k4.z + k4.w * k4.w;
    ss += __shfl_xor(ss, 1); ss += __shfl_xor(ss, 2);
    ss += __shfl_xor(ss, 4); ss += __shfl_xor(ss, 8);
    float scj = 0.125f / sqrtf(ss * (1.0f / 64.0f) + 1e-6f);
    k4.x *= scj; k4.y *= scj; k4.z *= scj; k4.w *= scj;
    ushort4 hh, ll;
    bsplit2(k4.x, hh.x, ll.x); bsplit2(k4.y, hh.y, ll.y);
    bsplit2(k4.z, hh.z, ll.z); bsplit2(k4.w, hh.w, ll.w);
    *reinterpret_cast<ushort4*>(Kh + (size_t)j * 72 + d4 * 4) = hh;
    *reinterpret_cast<ushort4*>(Kl + (size_t)j * 72 + d4 * 4) = ll;
  }
  __syncthreads();

  // QK^T via MFMA (R10-proven): dots[w*16+g*4+reg][kt*16+r]
  const int w = t >> 6, r = t & 15, g = (t & 63) >> 4;
  f32x4 dacc[8];
  #pragma unroll
  for (int kt = 0; kt < 8; ++kt) {
    f32x4 a; a[0] = 0.f; a[1] = 0.f; a[2] = 0.f; a[3] = 0.f;
    #pragma unroll
    for (int ks = 0; ks < 2; ++ks) {
      const int qo = (w * 16 + r) * 72 + ks * 32 + g * 8;
      const int ko = (kt * 16 + r) * 72 + ks * 32 + g * 8;
      bf16x8 qh_ = *reinterpret_cast<const bf16x8*>(Qh + qo);
      bf16x8 ql_ = *reinterpret_cast<const bf16x8*>(Ql + qo);
      bf16x8 kh_ = *reinterpret_cast<const bf16x8*>(Kh + ko);
      bf16x8 kl_ = *reinterpret_cast<const bf16x8*>(Kl + ko);
      a = __builtin_amdgcn_mfma_f32_16x16x32_bf16(qh_, kh_, a, 0, 0, 0);
      a = __builtin_amdgcn_mfma_f32_16x16x32_bf16(qh_, kl_, a, 0, 0, 0);
      a = __builtin_amdgcn_mfma_f32_16x16x32_bf16(ql_, kh_, a, 0, 0, 0);
    }
    dacc[kt] = a;
  }
  __syncthreads();  // all frag reads done; phase-B buffers may overwrite

  // issue V gather early (j = idx&127 row, d4 = idx>>7 16B-chunk)
  float4 vld[8];
  #pragma unroll
  for (int it = 0; it < 8; ++it) {
    int idx = t + it * 256;
    int j = idx & 127, d4 = idx >> 7;
    vld[it] = *reinterpret_cast<const float4*>(vbase + (size_t)kposS[j] * DD + d4 * 4);
  }

  // mask + exp + den in registers (rows w*16+g*4+rg, cols kt*16+r)
  int qp0 = mposS[64 + w * 16 + g * 4 + 0];
  int qp1 = mposS[64 + w * 16 + g * 4 + 1];
  int qp2 = mposS[64 + w * 16 + g * 4 + 2];
  int qp3 = mposS[64 + w * 16 + g * 4 + 3];
  float ex[8][4];
  float rs0 = 0.f, rs1 = 0.f, rs2 = 0.f, rs3 = 0.f;
  #pragma unroll
  for (int kt = 0; kt < 8; ++kt) {
    int cp = mposS[kt * 16 + r];
    float d0 = (cp == qp0) ? -100000.0f : dacc[kt][0];
    float d1 = (cp == qp1) ? -100000.0f : dacc[kt][1];
    float d2 = (cp == qp2) ? -100000.0f : dacc[kt][2];
    float d3 = (cp == qp3) ? -100000.0f : dacc[kt][3];
    float e0 = expf(d0), e1 = expf(d1), e2 = expf(d2), e3 = expf(d3);
    ex[kt][0] = e0; ex[kt][1] = e1; ex[kt][2] = e2; ex[kt][3] = e3;
    rs0 += e0; rs1 += e1; rs2 += e2; rs3 += e3;
  }
  #pragma unroll
  for (int st = 1; st <= 8; st <<= 1) {
    rs0 += __shfl_xor(rs0, st); rs1 += __shfl_xor(rs1, st);
    rs2 += __shfl_xor(rs2, st); rs3 += __shfl_xor(rs3, st);
  }
  const int n = c >> 6;
  if (r == 0) {
    #pragma unroll
    for (int rg = 0; rg < 4; ++rg) {
      float rsv = (rg == 0) ? rs0 : (rg == 1) ? rs1 : (rg == 2) ? rs2 : rs3;
      int q = w * 16 + g * 4 + rg;
      if (mode) denB[(size_t)(bh * NHH + n) * SS + (c & 63) * 64 + q] = rsv;
      else      atomicAdd(&denA[(size_t)bh * SS + kposS[64 + q]], rsv);
    }
  }

  // write P planes (2-term split of exp values)
  #pragma unroll
  for (int kt = 0; kt < 8; ++kt)
    #pragma unroll
    for (int rg = 0; rg < 4; ++rg) {
      unsigned short hi, lo;
      bsplit2(ex[kt][rg], hi, lo);
      size_t po = (size_t)(w * 16 + g * 4 + rg) * 136 + kt * 16 + r;
      Ph[po] = hi;
      Pl[po] = lo;
    }
  // write V^T planes (2-term split); per (d,j): 2-way bank access (free)
  #pragma unroll
  for (int it = 0; it < 8; ++it) {
    int idx = t + it * 256;
    int j = idx & 127, d4 = idx >> 7;
    float4 v4 = vld[it];
    unsigned short h0, l0, h1, l1, h2, l2, h3, l3;
    bsplit2(v4.x, h0, l0); bsplit2(v4.y, h1, l1);
    bsplit2(v4.z, h2, l2); bsplit2(v4.w, h3, l3);
    Vth[(size_t)(d4 * 4 + 0) * 136 + j] = h0; Vtl[(size_t)(d4 * 4 + 0) * 136 + j] = l0;
    Vth[(size_t)(d4 * 4 + 1) * 136 + j] = h1; Vtl[(size_t)(d4 * 4 + 1) * 136 + j] = l1;
    Vth[(size_t)(d4 * 4 + 2) * 136 + j] = h2; Vtl[(size_t)(d4 * 4 + 2) * 136 + j] = l2;
    Vth[(size_t)(d4 * 4 + 3) * 136 + j] = h3; Vtl[(size_t)(d4 * 4 + 3) * 136 + j] = l3;
  }
  __syncthreads();

  // PV via MFMA: O[w*16+g*4+reg][tn*16+r] = sum_k P[q][k] V[k][d]
  #pragma unroll
  for (int tn = 0; tn < 4; ++tn) {
    f32x4 a; a[0] = 0.f; a[1] = 0.f; a[2] = 0.f; a[3] = 0.f;
    #pragma unroll
    for (int ks = 0; ks < 4; ++ks) {
      const int po = (w * 16 + r) * 136 + ks * 32 + g * 8;
      const int vo = (tn * 16 + r) * 136 + ks * 32 + g * 8;
      bf16x8 ph_ = *reinterpret_cast<const bf16x8*>(Ph + po);
      bf16x8 pl_ = *reinterpret_cast<const bf16x8*>(Pl + po);
      bf16x8 vh_ = *reinterpret_cast<const bf16x8*>(Vth + vo);
      bf16x8 vl_ = *reinterpret_cast<const bf16x8*>(Vtl + vo);
      a = __builtin_amdgcn_mfma_f32_16x16x32_bf16(ph_, vh_, a, 0, 0, 0);
      a = __builtin_amdgcn_mfma_f32_16x16x32_bf16(ph_, vl_, a, 0, 0, 0);
      a = __builtin_amdgcn_mfma_f32_16x16x32_bf16(pl_, vh_, a, 0, 0, 0);
    }
    // epilogue for this d-tile
    #pragma unroll
    for (int reg = 0; reg < 4; ++reg) {
      int q = w * 16 + g * 4 + reg;
      int d = tn * 16 + r;
      if (mode) {
        numB[((size_t)(bh * NHH + n) * SS + (c & 63) * 64 + q) * DD + d] = a[reg];
      } else {
        atomicAdd(&outA[((size_t)(b * SS + kposS[64 + q])) * (HH * DD) + h * DD + d], a[reg]);
      }
    }
  }
}

// ---------------------------------------------------------------------------
// Kernel 5 (big-ws path): gather-combine.
// ---------------------------------------------------------------------------
__global__ __launch_bounds__(256) void k_combine(
    const float* __restrict__ numB, const float* __restrict__ denB,
    const int* __restrict__ sk_rank, float* __restrict__ outp)
{
  const int bh = blockIdx.y;
  const int s = blockIdx.x * 16 + (threadIdx.x >> 4);
  const int lane = threadIdx.x & 15;
  const int b = bh >> 3, h = bh & 7;
  float4 acc = make_float4(0.f, 0.f, 0.f, 0.f);
  float den = 0.f;
  #pragma unroll
  for (int n = 0; n < NHH; ++n) {
    int r = sk_rank[(size_t)bh * RANKS + n * SS + s];
    size_t rowi = (size_t)(bh * NHH + n) * SS + r;
    float4 v = *reinterpret_cast<const float4*>(numB + rowi * DD + lane * 4);
    acc.x += v.x; acc.y += v.y; acc.z += v.z; acc.w += v.w;
    den += denB[rowi];
  }
  float inv = 1.0f / den;
  acc.x *= inv; acc.y *= inv; acc.z *= inv; acc.w *= inv;
  *reinterpret_cast<float4*>(outp + ((size_t)(b * SS + s)) * (HH * DD) + h * DD + lane * 4) = acc;
}

// ---------------------------------------------------------------------------
// Kernel 5' (fallback path): divide accumulated numerator by denominator.
// ---------------------------------------------------------------------------
__global__ __launch_bounds__(256) void k_div(
    const float* __restrict__ den, float* __restrict__ outp)
{
  int idx = blockIdx.x * 256 + threadIdx.x;  // grid 4096 -> 1,048,576 float4
  int f = idx * 4;
  int col = f & 511;
  int h = col >> 6;
  int srow = f >> 9;                          // b*4096+s
  int b = srow >> 12, s = srow & 4095;
  float inv = 1.0f / den[(size_t)(b * HH + h) * SS + s];
  float4 v = *reinterpret_cast<float4*>(outp + (size_t)f);
  v.x *= inv; v.y *= inv; v.z *= inv; v.w *= inv;
  *reinterpret_cast<float4*>(outp + (size_t)f) = v;
}

// ---------------------------------------------------------------------------
// Kernel Z: zero the fp32 output (fallback path; harness poisons d_out).
// ---------------------------------------------------------------------------
__global__ __launch_bounds__(256) void k_zero_out(float* __restrict__ outp)
{
  int flat = blockIdx.x * 256 + threadIdx.x;  // grid 4096 -> 1,048,576 float4
  float4 z = make_float4(0.f, 0.f, 0.f, 0.f);
  *reinterpret_cast<float4*>(outp + (size_t)flat * 4) = z;
}

// ---------------------------------------------------------------------------
extern "C" void kernel_launch(void* const* d_in, const int* in_sizes, int n_in,
                              void* d_out, int out_size, void* d_ws, size_t ws_size,
                              hipStream_t stream)
{
  (void)in_sizes; (void)n_in; (void)out_size;
  const u32* dec = (const u32*)d_in[0];
  const u32* hid = (const u32*)d_in[1];
  const u32* wqk = (const u32*)d_in[2];
  const u32* wv  = (const u32*)d_in[3];
  const u32* rot = (const u32*)d_in[4];

  const size_t QKV  = (size_t)BB * HH * SS * DD;   // 4,194,304 elems
  const size_t LOGU = (size_t)BB * HH * NHH * SS;  // 262,144

  float* qb      = (float*)d_ws;
  float* kraw    = qb + QKV;
  float* vb      = kraw + QKV;
  float* den     = vb + QKV;                  // LOGU floats
  int*   sq_pos  = (int*)(den + LOGU);
  int*   sk_pos  = sq_pos + LOGU;
  int*   sk_rank = sk_pos + LOGU;
  u8*    buckets = (u8*)(sk_rank + LOGU);
  int*   flag    = (int*)(buckets + (size_t)2 * 64 * SS);
  const size_t numb_off = 55050496;           // align_up(low region, 256)
  float* numb    = (float*)((char*)d_ws + numb_off);
  // wt planes live INSIDE the numb region (numb not yet live during proj):
  unsigned short* wt0 = (unsigned short*)numb;
  unsigned short* wt1 = wt0 + (size_t)2 * 512 * 512;
  unsigned short* wt2 = wt1 + (size_t)2 * 512 * 512;
  const size_t need_big = numb_off + (size_t)NHH * QKV * sizeof(float);  // 122,159,360
  const int big = (ws_size >= need_big) ? 1 : 0;

  hipMemsetAsync(flag, 0, sizeof(int), stream);
  k_detect<<<dim3(512), 256, 0, stream>>>(wqk, flag);
  k_prep<<<dim3(256, 2), 256, 0, stream>>>(wqk, wv, flag, wt0, wt1, wt2);
  // q,k: scalar (hash-feeding, bit-identical accumulation). v: MFMA (R7-proven).
  k_proj_s<<<dim3(128, 8, 2), 256, 0, stream>>>(dec, hid, wqk, wv, flag, qb, kraw, vb);
  k_proj_v<<<dim3(1024), 256, 0, stream>>>(hid, wt0, wt1, wt2, flag, vb);
  k_hash<<<dim3(64, 2, 4), 256, 0, stream>>>(qb, kraw, rot, flag, buckets);
  k_sort<<<dim3(64, 2), 256, 0, stream>>>(buckets, sq_pos, sk_pos, sk_rank);

  if (big) {
    k_attn<<<dim3(NCC, HH, BB), 256, 0, stream>>>(
        qb, kraw, vb, sq_pos, sk_pos, 1, nullptr, nullptr, numb, den);
    k_combine<<<dim3(SS / 16, BB * HH), 256, 0, stream>>>(
        numb, den, sk_rank, (float*)d_out);
  } else {
    hipMemsetAsync(den, 0, (size_t)BB * HH * SS * sizeof(float), stream);
    k_zero_out<<<dim3(4096), 256, 0, stream>>>((float*)d_out);
    k_attn<<<dim3(NCC, HH, BB), 256, 0, stream>>>(
        qb, kraw, vb, sq_pos, sk_pos, 0, (float*)d_out, den, nullptr, nullptr);
    k_div<<<dim3(4096), 256, 0, stream>>>(den, (float*)d_out);
  }
}

// Round 12
// 476.357 us; speedup vs baseline: 4.0395x; 1.1366x over previous
//
#include <hip/hip_runtime.h>
#include <math.h>

#define BB 2
#define SS 4096
#define HIDK 512
#define HH 8
#define DD 64
#define NHH 4
#define NCC 256      // chunks per (b,h) = NH*S/CHUNK
#define RANKS 16384  // NH*S

typedef unsigned int u32;
typedef unsigned char u8;
typedef __attribute__((ext_vector_type(8))) short bf16x8;
typedef __attribute__((ext_vector_type(4))) float f32x4;

__device__ __forceinline__ float bflo(u32 u){ return __uint_as_float(u << 16); }
__device__ __forceinline__ float bfhi(u32 u){ return __uint_as_float(u & 0xffff0000u); }

// RN fp32 -> bf16 (top of x)
__device__ __forceinline__ unsigned short brn(float x)
{
  u32 u = __float_as_uint(x);
  u32 r = u + 0x7FFFu + ((u >> 16) & 1u);
  return (unsigned short)(r >> 16);
}

// 2-term bf16 split: x ~= b0 + b1 (residual ~2^-17 |x|).
__device__ __forceinline__ void bsplit2(float x, unsigned short& b0, unsigned short& b1)
{
  b0 = brn(x);
  float x1 = x - __uint_as_float((u32)b0 << 16);
  b1 = brn(x1);
}

// 3-term bf16 split: x ~= b0 + b1 + b2 (Sterbenz-exact residuals).
__device__ __forceinline__ void bsplit3(float x, unsigned short& b0, unsigned short& b1, unsigned short& b2)
{
  b0 = brn(x);
  float x1 = x - __uint_as_float((u32)b0 << 16);
  b1 = brn(x1);
  float x2 = x1 - __uint_as_float((u32)b1 << 16);
  b2 = brn(x2);
}

// ---------------------------------------------------------------------------
// Kernel 0: input dtype detection (bf16 vs fp32 bit patterns in w_qk).
// ---------------------------------------------------------------------------
__global__ __launch_bounds__(256) void k_detect(const u32* __restrict__ w, int* __restrict__ flag)
{
  int i = blockIdx.x * 256 + threadIdx.x;   // grid 512 -> 131072 u32
  float lo = bflo(w[i]);
  bool bad = !(fabsf(lo) <= 1024.0f);       // true also for NaN
  if (__any(bad)) {
    if ((threadIdx.x & 63) == 0) atomicOr(flag, 1);
  }
}

// ---------------------------------------------------------------------------
// Kernel P: prep weights. Transpose W[k][n] -> Wt[n][k], 3-term bf16 split
// for fp32 inputs. wt*: [2][512][512] u16 (plane 0 = wqk, 1 = wv).
// ---------------------------------------------------------------------------
__global__ __launch_bounds__(256) void k_prep(
    const u32* __restrict__ wqk, const u32* __restrict__ wv,
    const int* __restrict__ flag,
    unsigned short* __restrict__ wt0, unsigned short* __restrict__ wt1,
    unsigned short* __restrict__ wt2)
{
  const int which = blockIdx.y;
  const u32* W = which ? wv : wqk;
  const int tk = blockIdx.x >> 4, tn = blockIdx.x & 15;
  const int t = threadIdx.x;
  const int is32 = flag[0];
  __shared__ unsigned short h0s[32][36];
  __shared__ unsigned short h1s[32][36];
  __shared__ unsigned short h2s[32][36];
  if (is32) {
    const float* Wf = (const float*)W;
    #pragma unroll
    for (int it = 0; it < 4; ++it) {
      int idx = t + it * 256;           // 1024 = 32 k x 32 n
      int kk = idx >> 5, nn = idx & 31;
      float x = Wf[(size_t)(tk * 32 + kk) * 512 + tn * 32 + nn];
      bsplit3(x, h0s[kk][nn], h1s[kk][nn], h2s[kk][nn]);
    }
  } else {
    #pragma unroll
    for (int it = 0; it < 2; ++it) {
      int idx = t + it * 256;           // 512 u32 = 32 k x 16 pairs
      int kk = idx >> 4, np = idx & 15;
      u32 uv = W[(size_t)(tk * 32 + kk) * 256 + tn * 16 + np];
      h0s[kk][2 * np]     = (unsigned short)(uv & 0xffffu);
      h0s[kk][2 * np + 1] = (unsigned short)(uv >> 16);
      h1s[kk][2 * np] = 0; h1s[kk][2 * np + 1] = 0;
      h2s[kk][2 * np] = 0; h2s[kk][2 * np + 1] = 0;
    }
  }
  __syncthreads();
  size_t obase = ((size_t)which * 512 + tn * 32) * 512 + tk * 32;
  #pragma unroll
  for (int it = 0; it < 4; ++it) {
    int idx = t + it * 256;
    int nn = idx >> 5, kk = idx & 31;
    wt0[obase + (size_t)nn * 512 + kk] = h0s[kk][nn];
    wt1[obase + (size_t)nn * 512 + kk] = h1s[kk][nn];
    wt2[obase + (size_t)nn * 512 + kk] = h2s[kk][nn];
  }
}

// ---------------------------------------------------------------------------
// Kernel 1a: SCALAR projections for q and k (hash-feeding).
// Accumulation bit-identical to the R0-R2/R7-R11-proven kernel.
// ---------------------------------------------------------------------------
__global__ __launch_bounds__(256) void k_proj_s(
    const u32* __restrict__ dec, const u32* __restrict__ hid,
    const u32* __restrict__ wqk, const u32* __restrict__ wv,
    const int* __restrict__ flag,
    float* __restrict__ qb, float* __restrict__ kraw, float* __restrict__ vb)
{
  const int which = blockIdx.z;
  const u32* A = (which == 0) ? dec : hid;
  const u32* W = (which == 2) ? wv : wqk;
  const int m0 = blockIdx.x * 64;
  const int h  = blockIdx.y;
  const int t  = threadIdx.x;
  const int ty = t >> 4, tx = t & 15;
  const int is32 = flag[0];

  __shared__ __align__(16) float AsT[32][68];  // [kk][row i]; 272B stride
  __shared__ __align__(16) float Wst[32][64];  // [kk][col c]

  float acc[4][4];
  #pragma unroll
  for (int r = 0; r < 4; ++r)
    #pragma unroll
    for (int c = 0; c < 4; ++c) acc[r][c] = 0.0f;

  for (int k0 = 0; k0 < HIDK; k0 += 32) {
    if (is32) {
      const float* Af = (const float*)A;
      const float* Wf = (const float*)W;
      #pragma unroll
      for (int it = 0; it < 8; ++it) {
        int idx = t + it * 256;          // 2048: 64 rows x 32 k
        int i = idx >> 5, kk = idx & 31;
        AsT[kk][i] = Af[(size_t)(m0 + i) * HIDK + k0 + kk];
      }
      #pragma unroll
      for (int it = 0; it < 8; ++it) {
        int idx = t + it * 256;          // 2048: 32 k x 64 cols, c-fast
        int kk = idx >> 6, c = idx & 63;
        Wst[kk][c] = Wf[(size_t)(k0 + kk) * HIDK + h * 64 + c];
      }
    } else {
      #pragma unroll
      for (int it = 0; it < 4; ++it) {
        int idx = t + it * 256;          // 1024: A tile 64 rows x 16 u32
        int i = idx >> 4, kp = idx & 15;
        u32 uv = A[(size_t)(m0 + i) * (HIDK / 2) + (k0 >> 1) + kp];
        AsT[2 * kp][i]     = bflo(uv);
        AsT[2 * kp + 1][i] = bfhi(uv);
      }
      #pragma unroll
      for (int it = 0; it < 4; ++it) {
        int idx = t + it * 256;          // 1024: W tile 32 k x 32 u32, cp-fast
        int kk = idx >> 5, cp = idx & 31;
        u32 uv = W[(size_t)(k0 + kk) * (HIDK / 2) + h * 32 + cp];
        Wst[kk][2 * cp]     = bflo(uv);
        Wst[kk][2 * cp + 1] = bfhi(uv);
      }
    }
    __syncthreads();
    for (int kk = 0; kk < 32; ++kk) {
      float4 a4 = *reinterpret_cast<const float4*>(&AsT[kk][ty * 4]);  // rows ty*4..+3
      float4 w4 = *reinterpret_cast<const float4*>(&Wst[kk][tx * 4]);  // cols tx*4..+3
      acc[0][0] += a4.x * w4.x; acc[0][1] += a4.x * w4.y; acc[0][2] += a4.x * w4.z; acc[0][3] += a4.x * w4.w;
      acc[1][0] += a4.y * w4.x; acc[1][1] += a4.y * w4.y; acc[1][2] += a4.y * w4.z; acc[1][3] += a4.y * w4.w;
      acc[2][0] += a4.z * w4.x; acc[2][1] += a4.z * w4.y; acc[2][2] += a4.z * w4.z; acc[2][3] += a4.z * w4.w;
      acc[3][0] += a4.w * w4.x; acc[3][1] += a4.w * w4.y; acc[3][2] += a4.w * w4.z; acc[3][3] += a4.w * w4.w;
    }
    __syncthreads();
  }

  float* outp = (which == 0) ? qb : ((which == 1) ? kraw : vb);
  #pragma unroll
  for (int r = 0; r < 4; ++r) {
    int m = m0 + ty * 4 + r;
    int b = m >> 12, s = m & 4095;
    float4 o;
    o.x = acc[r][0]; o.y = acc[r][1]; o.z = acc[r][2]; o.w = acc[r][3];
    *reinterpret_cast<float4*>(outp + ((size_t)((b * HH + h) * SS + s)) * DD + tx * 4) = o;
  }
}

// ---------------------------------------------------------------------------
// Kernel 1b: MFMA projection for V ONLY (v = hid @ wv). R7-proven.
// ---------------------------------------------------------------------------
__global__ __launch_bounds__(256) void k_proj_v(
    const u32* __restrict__ hid,
    const unsigned short* __restrict__ wt0, const unsigned short* __restrict__ wt1,
    const unsigned short* __restrict__ wt2,
    const int* __restrict__ flag,
    float* __restrict__ vb)
{
  const int bid = blockIdx.x;              // grid 1024 = 8 x 128
  const int x = bid & 7, l = bid >> 3;     // l in [0,128)
  const int h = l & 7;
  const int m0 = (x * 16 + ((l >> 3) & 15)) * 64;
  const int t = threadIdx.x;
  const int w = t >> 6;
  const int r = t & 15, g = (t & 63) >> 4;
  const int is32 = flag[0];

  const u32* A = hid;
  const size_t wbase = (size_t)1 * 512 * 512 + (size_t)h * 64 * 512;  // wv plane
  const unsigned short* W0 = wt0 + wbase;
  const unsigned short* W1 = wt1 + wbase;
  const unsigned short* W2 = wt2 + wbase;

  __shared__ __align__(16) unsigned short A0[64][40];  // stride 80B
  __shared__ __align__(16) unsigned short A1[64][40];
  __shared__ __align__(16) unsigned short A2[64][40];
  __shared__ __align__(16) unsigned short B0[64][40];
  __shared__ __align__(16) unsigned short B1[64][40];
  __shared__ __align__(16) unsigned short B2[64][40];

  f32x4 acc[4];
  #pragma unroll
  for (int tn = 0; tn < 4; ++tn) { acc[tn][0] = 0.f; acc[tn][1] = 0.f; acc[tn][2] = 0.f; acc[tn][3] = 0.f; }

  for (int k0 = 0; k0 < HIDK; k0 += 32) {
    {
      const int n = t >> 2, kq = t & 3;
      *reinterpret_cast<uint4*>(&B0[n][kq * 8]) =
          *reinterpret_cast<const uint4*>(W0 + (size_t)n * 512 + k0 + kq * 8);
      if (is32) {
        *reinterpret_cast<uint4*>(&B1[n][kq * 8]) =
            *reinterpret_cast<const uint4*>(W1 + (size_t)n * 512 + k0 + kq * 8);
        *reinterpret_cast<uint4*>(&B2[n][kq * 8]) =
            *reinterpret_cast<const uint4*>(W2 + (size_t)n * 512 + k0 + kq * 8);
      }
    }
    if (is32) {
      const float* Af = (const float*)A;
      #pragma unroll
      for (int it = 0; it < 2; ++it) {
        int idx = t + it * 256;
        int m = idx >> 3, kq = idx & 7;
        float4 a4 = *reinterpret_cast<const float4*>(Af + (size_t)(m0 + m) * HIDK + k0 + kq * 4);
        ushort4 p0, p1, p2;
        bsplit3(a4.x, p0.x, p1.x, p2.x);
        bsplit3(a4.y, p0.y, p1.y, p2.y);
        bsplit3(a4.z, p0.z, p1.z, p2.z);
        bsplit3(a4.w, p0.w, p1.w, p2.w);
        *reinterpret_cast<ushort4*>(&A0[m][kq * 4]) = p0;
        *reinterpret_cast<ushort4*>(&A1[m][kq * 4]) = p1;
        *reinterpret_cast<ushort4*>(&A2[m][kq * 4]) = p2;
      }
    } else {
      #pragma unroll
      for (int it = 0; it < 2; ++it) {
        int idx = t + it * 256;
        int m = idx >> 3, kq = idx & 7;
        uint2 uv = *reinterpret_cast<const uint2*>(A + (size_t)(m0 + m) * (HIDK / 2) + (k0 >> 1) + kq * 2);
        *reinterpret_cast<uint2*>(&A0[m][kq * 4]) = uv;
      }
    }
    __syncthreads();

    bf16x8 a0 = *reinterpret_cast<const bf16x8*>(&A0[w * 16 + r][g * 8]);
    if (is32) {
      bf16x8 a1 = *reinterpret_cast<const bf16x8*>(&A1[w * 16 + r][g * 8]);
      bf16x8 a2 = *reinterpret_cast<const bf16x8*>(&A2[w * 16 + r][g * 8]);
      #pragma unroll
      for (int tn = 0; tn < 4; ++tn) {
        bf16x8 b0 = *reinterpret_cast<const bf16x8*>(&B0[tn * 16 + r][g * 8]);
        bf16x8 b1 = *reinterpret_cast<const bf16x8*>(&B1[tn * 16 + r][g * 8]);
        bf16x8 b2 = *reinterpret_cast<const bf16x8*>(&B2[tn * 16 + r][g * 8]);
        acc[tn] = __builtin_amdgcn_mfma_f32_16x16x32_bf16(a0, b0, acc[tn], 0, 0, 0);
        acc[tn] = __builtin_amdgcn_mfma_f32_16x16x32_bf16(a0, b1, acc[tn], 0, 0, 0);
        acc[tn] = __builtin_amdgcn_mfma_f32_16x16x32_bf16(a1, b0, acc[tn], 0, 0, 0);
        acc[tn] = __builtin_amdgcn_mfma_f32_16x16x32_bf16(a0, b2, acc[tn], 0, 0, 0);
        acc[tn] = __builtin_amdgcn_mfma_f32_16x16x32_bf16(a2, b0, acc[tn], 0, 0, 0);
        acc[tn] = __builtin_amdgcn_mfma_f32_16x16x32_bf16(a1, b1, acc[tn], 0, 0, 0);
      }
    } else {
      #pragma unroll
      for (int tn = 0; tn < 4; ++tn) {
        bf16x8 b0 = *reinterpret_cast<const bf16x8*>(&B0[tn * 16 + r][g * 8]);
        acc[tn] = __builtin_amdgcn_mfma_f32_16x16x32_bf16(a0, b0, acc[tn], 0, 0, 0);
      }
    }
    __syncthreads();
  }

  #pragma unroll
  for (int tn = 0; tn < 4; ++tn)
    #pragma unroll
    for (int rg = 0; rg < 4; ++rg) {
      int m = m0 + w * 16 + g * 4 + rg;
      int b = m >> 12, s = m & 4095;
      vb[((size_t)((b * HH + h) * SS + s)) * DD + tn * 16 + r] = acc[tn][rg];
    }
}

// ---------------------------------------------------------------------------
// Kernel 2: LSH hash. rotS [64][64], float4 LDS reads (R8-proven numerics:
// per-output d=0..63 sequential, 16-r blocking). Grid z widened 4->16 so each
// thread owns exactly one row: 2048 blocks = 8 blocks/CU for latency hiding.
// ---------------------------------------------------------------------------
__global__ __launch_bounds__(256) void k_hash(
    const float* __restrict__ qb, const float* __restrict__ kraw,
    const u32* __restrict__ rots, const int* __restrict__ flag,
    u8* __restrict__ bucketOut)
{
  const int bhn = blockIdx.x;       // 0..63 : (b*8+h)*4+n
  const int which = blockIdx.y;     // 0=q 1=k
  const int sslice = blockIdx.z;    // 0..15
  const int t = threadIdx.x;
  const int bh = bhn >> 2;
  const int h  = bh & 7;
  const int n  = bhn & 3;
  const int is32 = flag[0];

  __shared__ __align__(16) float rotS[64][64];   // [d][r], 16 KB
  if (is32) {
    const float* rf = (const float*)rots;
    #pragma unroll
    for (int it = 0; it < 16; ++it) {
      int idx = t + it * 256;       // 4096 floats
      int d = idx >> 6, r = idx & 63;
      rotS[d][r] = rf[((size_t)((h * 64 + d) * 4 + n)) * 64 + r];
    }
  } else {
    #pragma unroll
    for (int it = 0; it < 8; ++it) {
      int idx = t + it * 256;       // 2048 u32 (4096 bf16)
      int d = idx >> 5, rp = idx & 31;
      u32 uv = rots[((size_t)((h * 64 + d) * 4 + n)) * 32 + rp];
      rotS[d][2 * rp]     = bflo(uv);
      rotS[d][2 * rp + 1] = bfhi(uv);
    }
  }
  __syncthreads();

  const float* src = ((which == 0) ? qb : kraw) + (size_t)bh * SS * DD;
  u8* bout = bucketOut + ((size_t)(which * 64 + bhn)) * SS;

  {
    int s = sslice * 256 + t;
    const float* row = src + (size_t)s * DD;
    float vec[64];
    #pragma unroll
    for (int d4 = 0; d4 < 16; ++d4) {
      float4 v4 = *reinterpret_cast<const float4*>(row + d4 * 4);
      vec[d4 * 4 + 0] = v4.x; vec[d4 * 4 + 1] = v4.y;
      vec[d4 * 4 + 2] = v4.z; vec[d4 * 4 + 3] = v4.w;
    }
    float bestP = -1e30f, bestN = -1e30f;
    int idxP = 0, idxN = 0;
    #pragma unroll 1
    for (int r0 = 0; r0 < 64; r0 += 16) {
      float acc[16];
      #pragma unroll
      for (int rr = 0; rr < 16; ++rr) acc[rr] = 0.0f;
      #pragma unroll
      for (int d = 0; d < 64; ++d) {
        float vd = vec[d];
        #pragma unroll
        for (int q4 = 0; q4 < 4; ++q4) {
          float4 rv4 = *reinterpret_cast<const float4*>(&rotS[d][r0 + q4 * 4]);
          acc[q4 * 4 + 0] += vd * rv4.x;
          acc[q4 * 4 + 1] += vd * rv4.y;
          acc[q4 * 4 + 2] += vd * rv4.z;
          acc[q4 * 4 + 3] += vd * rv4.w;
        }
      }
      #pragma unroll
      for (int rr = 0; rr < 16; ++rr) {
        float a = acc[rr];
        int r = r0 + rr;
        if (a > bestP) { bestP = a; idxP = r; }
        if (-a > bestN) { bestN = -a; idxN = r; }
      }
    }
    int bucket = (bestP >= bestN) ? idxP : (64 + idxN);
    bout[s] = (u8)bucket;
  }
}

// ---------------------------------------------------------------------------
// Kernel 3: PARALLEL stable counting sort per (b,h,round,which).
// ---------------------------------------------------------------------------
__global__ __launch_bounds__(256) void k_sort(
    const u8* __restrict__ bucketIn, int* __restrict__ sq_pos,
    int* __restrict__ sk_pos, int* __restrict__ sk_rank)
{
  const int bhn = blockIdx.x, which = blockIdx.y;
  const int t = threadIdx.x;
  const int bh = bhn >> 2, n = bhn & 3;
  const int lane = t & 63, w = t >> 6;

  __shared__ u8 bk[4096];
  __shared__ u8 rk[4096];
  __shared__ int chunkh[64 * 128];   // [chunk][bin], 32 KB
  __shared__ int hist[128];
  __shared__ int scanS[128];

  const u8* bin = bucketIn + ((size_t)(which * 64 + bhn)) * SS;
  #pragma unroll
  for (int it = 0; it < 4; ++it)
    ((u32*)bk)[t + it * 256] = ((const u32*)bin)[t + it * 256];
  #pragma unroll
  for (int it = 0; it < 32; ++it) chunkh[t + it * 256] = 0;
  if (t < 128) hist[t] = 0;
  __syncthreads();

  const unsigned long long below = (lane == 0) ? 0ull : (~0ull >> (64 - lane));
  #pragma unroll 1
  for (int k = 0; k < 16; ++k) {
    const int c = w * 16 + k;
    const int s = c * 64 + lane;
    const int b = bk[s];
    unsigned long long m = ~0ull;
    #pragma unroll
    for (int bit = 0; bit < 7; ++bit) {
      unsigned long long vote = __ballot((b >> bit) & 1);
      m &= ((b >> bit) & 1) ? vote : ~vote;
    }
    const int r = (int)__popcll(m & below);
    rk[s] = (u8)r;
    if (r == 0) {
      const int cnt = (int)__popcll(m);
      chunkh[c * 128 + b] = cnt;
      atomicAdd(&hist[b], cnt);
    }
  }
  __syncthreads();

  if (t < 128) scanS[t] = hist[t];
  __syncthreads();
  for (int off = 1; off < 128; off <<= 1) {
    int add = 0;
    if (t < 128 && t >= off) add = scanS[t - off];
    __syncthreads();
    if (t < 128) scanS[t] += add;
    __syncthreads();
  }
  if (t < 128) {
    int run = scanS[t] - hist[t];    // global bin start
    #pragma unroll 1
    for (int c = 0; c < 64; ++c) {
      int v = chunkh[c * 128 + t];
      chunkh[c * 128 + t] = run;
      run += v;
    }
  }
  __syncthreads();

  int* outp = ((which == 0) ? sq_pos : sk_pos) + (size_t)bh * RANKS + n * SS;
  int* rnkp = sk_rank + (size_t)bh * RANKS + n * SS;
  #pragma unroll 1
  for (int k = 0; k < 16; ++k) {
    const int c = w * 16 + k;
    const int s = c * 64 + lane;
    const int b = bk[s];
    const int pos = chunkh[c * 128 + b] + (int)rk[s];
    outp[pos] = s;
    if (which) rnkp[s] = pos;
  }
}

// ---------------------------------------------------------------------------
// Kernel 4: single attention pass, BOTH matmuls on MFMA (R11-proven).
//   QK: 2-term bf16 split of Q and normalized K, 3 MFMAs.
//   PV: P = exp(dots) 2-term split x V 2-term split, 3 MFMAs; den exact fp32.
// LDS overlay (byte offsets):
//   phase A: Qh@0 Ql@9216 [64][72]u16, Kh@18432 Kl@36864 [128][72]u16 (55.3KB)
//   phase B: Ph@0 Pl@17408 [64][136]u16, Vth@34816 Vtl@52224 [64][136]u16 (69.6KB)
// C/D layouts use the HW-verified col=lane&15, row=(lane>>4)*4+reg mapping.
// ---------------------------------------------------------------------------
__global__ __launch_bounds__(256) void k_attn(
    const float* __restrict__ qb, const float* __restrict__ kraw,
    const float* __restrict__ vb,
    const int* __restrict__ sq_pos, const int* __restrict__ sk_pos,
    const int mode,
    float* __restrict__ outA, float* __restrict__ denA,
    float* __restrict__ numB, float* __restrict__ denB)
{
  const int c = blockIdx.x;
  const int h = blockIdx.y, b = blockIdx.z;
  const int bh = b * HH + h;
  const int t = threadIdx.x;
  const int cprev = (c + NCC - 1) & (NCC - 1);

  __shared__ __align__(16) char smem[69632];
  __shared__ int kposS[128], mposS[128];

  unsigned short* Qh = (unsigned short*)smem;            // [64][72]
  unsigned short* Ql = (unsigned short*)(smem + 9216);   // [64][72]
  unsigned short* Kh = (unsigned short*)(smem + 18432);  // [128][72]
  unsigned short* Kl = (unsigned short*)(smem + 36864);  // [128][72]
  unsigned short* Ph  = (unsigned short*)smem;           // [64][136]
  unsigned short* Pl  = (unsigned short*)(smem + 17408); // [64][136]
  unsigned short* Vth = (unsigned short*)(smem + 34816); // [64][136]
  unsigned short* Vtl = (unsigned short*)(smem + 52224); // [64][136]

  if (t < 128) {
    int slot = (t < 64) ? (cprev * 64 + t) : (c * 64 + (t - 64));
    kposS[t] = sk_pos[(size_t)bh * RANKS + slot];
    mposS[t] = sq_pos[(size_t)bh * RANKS + slot];
  }
  __syncthreads();

  const float* qbase = qb + (size_t)bh * SS * DD;
  const float* kbase = kraw + (size_t)bh * SS * DD;
  const float* vbase = vb + (size_t)bh * SS * DD;

  // stage Q: gather rows, 2-term split
  #pragma unroll
  for (int it = 0; it < 4; ++it) {
    int idx = t + it * 256;
    int i = idx >> 4, d4 = idx & 15;
    float4 q4 = *reinterpret_cast<const float4*>(qbase + (size_t)mposS[64 + i] * DD + d4 * 4);
    ushort4 hh, ll;
    bsplit2(q4.x, hh.x, ll.x); bsplit2(q4.y, hh.y, ll.y);
    bsplit2(q4.z, hh.z, ll.z); bsplit2(q4.w, hh.w, ll.w);
    *reinterpret_cast<ushort4*>(Qh + (size_t)i * 72 + d4 * 4) = hh;
    *reinterpret_cast<ushort4*>(Ql + (size_t)i * 72 + d4 * 4) = ll;
  }
  // stage K: gather rows, normalize (16-lane shuffle row-sumsq), 2-term split
  #pragma unroll
  for (int it = 0; it < 8; ++it) {
    int idx = t + it * 256;
    int j = idx >> 4, d4 = idx & 15;
    float4 k4 = *reinterpret_cast<const float4*>(kbase + (size_t)kposS[j] * DD + d4 * 4);
    float ss = k4.x * k4.x + k4.y * k4.y + k4.z * k4.z + k4.w * k4.w;
    ss += __shfl_xor(ss, 1); ss += __shfl_xor(ss, 2);
    ss += __shfl_xor(ss, 4); ss += __shfl_xor(ss, 8);
    float scj = 0.125f / sqrtf(ss * (1.0f / 64.0f) + 1e-6f);
    k4.x *= scj; k4.y *= scj; k4.z *= scj; k4.w *= scj;
    ushort4 hh, ll;
    bsplit2(k4.x, hh.x, ll.x); bsplit2(k4.y, hh.y, ll.y);
    bsplit2(k4.z, hh.z, ll.z); bsplit2(k4.w, hh.w, ll.w);
    *reinterpret_cast<ushort4*>(Kh + (size_t)j * 72 + d4 * 4) = hh;
    *reinterpret_cast<ushort4*>(Kl + (size_t)j * 72 + d4 * 4) = ll;
  }
  __syncthreads();

  // QK^T via MFMA (R10-proven): dots[w*16+g*4+reg][kt*16+r]
  const int w = t >> 6, r = t & 15, g = (t & 63) >> 4;
  f32x4 dacc[8];
  #pragma unroll
  for (int kt = 0; kt < 8; ++kt) {
    f32x4 a; a[0] = 0.f; a[1] = 0.f; a[2] = 0.f; a[3] = 0.f;
    #pragma unroll
    for (int ks = 0; ks < 2; ++ks) {
      const int qo = (w * 16 + r) * 72 + ks * 32 + g * 8;
      const int ko = (kt * 16 + r) * 72 + ks * 32 + g * 8;
      bf16x8 qh_ = *reinterpret_cast<const bf16x8*>(Qh + qo);
      bf16x8 ql_ = *reinterpret_cast<const bf16x8*>(Ql + qo);
      bf16x8 kh_ = *reinterpret_cast<const bf16x8*>(Kh + ko);
      bf16x8 kl_ = *reinterpret_cast<const bf16x8*>(Kl + ko);
      a = __builtin_amdgcn_mfma_f32_16x16x32_bf16(qh_, kh_, a, 0, 0, 0);
      a = __builtin_amdgcn_mfma_f32_16x16x32_bf16(qh_, kl_, a, 0, 0, 0);
      a = __builtin_amdgcn_mfma_f32_16x16x32_bf16(ql_, kh_, a, 0, 0, 0);
    }
    dacc[kt] = a;
  }
  __syncthreads();  // all frag reads done; phase-B buffers may overwrite

  // issue V gather early (j = idx&127 row, d4 = idx>>7 16B-chunk)
  float4 vld[8];
  #pragma unroll
  for (int it = 0; it < 8; ++it) {
    int idx = t + it * 256;
    int j = idx & 127, d4 = idx >> 7;
    vld[it] = *reinterpret_cast<const float4*>(vbase + (size_t)kposS[j] * DD + d4 * 4);
  }

  // mask + exp + den in registers (rows w*16+g*4+rg, cols kt*16+r)
  int qp0 = mposS[64 + w * 16 + g * 4 + 0];
  int qp1 = mposS[64 + w * 16 + g * 4 + 1];
  int qp2 = mposS[64 + w * 16 + g * 4 + 2];
  int qp3 = mposS[64 + w * 16 + g * 4 + 3];
  float ex[8][4];
  float rs0 = 0.f, rs1 = 0.f, rs2 = 0.f, rs3 = 0.f;
  #pragma unroll
  for (int kt = 0; kt < 8; ++kt) {
    int cp = mposS[kt * 16 + r];
    float d0 = (cp == qp0) ? -100000.0f : dacc[kt][0];
    float d1 = (cp == qp1) ? -100000.0f : dacc[kt][1];
    float d2 = (cp == qp2) ? -100000.0f : dacc[kt][2];
    float d3 = (cp == qp3) ? -100000.0f : dacc[kt][3];
    float e0 = expf(d0), e1 = expf(d1), e2 = expf(d2), e3 = expf(d3);
    ex[kt][0] = e0; ex[kt][1] = e1; ex[kt][2] = e2; ex[kt][3] = e3;
    rs0 += e0; rs1 += e1; rs2 += e2; rs3 += e3;
  }
  #pragma unroll
  for (int st = 1; st <= 8; st <<= 1) {
    rs0 += __shfl_xor(rs0, st); rs1 += __shfl_xor(rs1, st);
    rs2 += __shfl_xor(rs2, st); rs3 += __shfl_xor(rs3, st);
  }
  const int n = c >> 6;
  if (r == 0) {
    #pragma unroll
    for (int rg = 0; rg < 4; ++rg) {
      float rsv = (rg == 0) ? rs0 : (rg == 1) ? rs1 : (rg == 2) ? rs2 : rs3;
      int q = w * 16 + g * 4 + rg;
      if (mode) denB[(size_t)(bh * NHH + n) * SS + (c & 63) * 64 + q] = rsv;
      else      atomicAdd(&denA[(size_t)bh * SS + kposS[64 + q]], rsv);
    }
  }

  // write P planes (2-term split of exp values)
  #pragma unroll
  for (int kt = 0; kt < 8; ++kt)
    #pragma unroll
    for (int rg = 0; rg < 4; ++rg) {
      unsigned short hi, lo;
      bsplit2(ex[kt][rg], hi, lo);
      size_t po = (size_t)(w * 16 + g * 4 + rg) * 136 + kt * 16 + r;
      Ph[po] = hi;
      Pl[po] = lo;
    }
  // write V^T planes (2-term split); per (d,j): 2-way bank access (free)
  #pragma unroll
  for (int it = 0; it < 8; ++it) {
    int idx = t + it * 256;
    int j = idx & 127, d4 = idx >> 7;
    float4 v4 = vld[it];
    unsigned short h0, l0, h1, l1, h2, l2, h3, l3;
    bsplit2(v4.x, h0, l0); bsplit2(v4.y, h1, l1);
    bsplit2(v4.z, h2, l2); bsplit2(v4.w, h3, l3);
    Vth[(size_t)(d4 * 4 + 0) * 136 + j] = h0; Vtl[(size_t)(d4 * 4 + 0) * 136 + j] = l0;
    Vth[(size_t)(d4 * 4 + 1) * 136 + j] = h1; Vtl[(size_t)(d4 * 4 + 1) * 136 + j] = l1;
    Vth[(size_t)(d4 * 4 + 2) * 136 + j] = h2; Vtl[(size_t)(d4 * 4 + 2) * 136 + j] = l2;
    Vth[(size_t)(d4 * 4 + 3) * 136 + j] = h3; Vtl[(size_t)(d4 * 4 + 3) * 136 + j] = l3;
  }
  __syncthreads();

  // PV via MFMA: O[w*16+g*4+reg][tn*16+r] = sum_k P[q][k] V[k][d]
  #pragma unroll
  for (int tn = 0; tn < 4; ++tn) {
    f32x4 a; a[0] = 0.f; a[1] = 0.f; a[2] = 0.f; a[3] = 0.f;
    #pragma unroll
    for (int ks = 0; ks < 4; ++ks) {
      const int po = (w * 16 + r) * 136 + ks * 32 + g * 8;
      const int vo = (tn * 16 + r) * 136 + ks * 32 + g * 8;
      bf16x8 ph_ = *reinterpret_cast<const bf16x8*>(Ph + po);
      bf16x8 pl_ = *reinterpret_cast<const bf16x8*>(Pl + po);
      bf16x8 vh_ = *reinterpret_cast<const bf16x8*>(Vth + vo);
      bf16x8 vl_ = *reinterpret_cast<const bf16x8*>(Vtl + vo);
      a = __builtin_amdgcn_mfma_f32_16x16x32_bf16(ph_, vh_, a, 0, 0, 0);
      a = __builtin_amdgcn_mfma_f32_16x16x32_bf16(ph_, vl_, a, 0, 0, 0);
      a = __builtin_amdgcn_mfma_f32_16x16x32_bf16(pl_, vh_, a, 0, 0, 0);
    }
    // epilogue for this d-tile
    #pragma unroll
    for (int reg = 0; reg < 4; ++reg) {
      int q = w * 16 + g * 4 + reg;
      int d = tn * 16 + r;
      if (mode) {
        numB[((size_t)(bh * NHH + n) * SS + (c & 63) * 64 + q) * DD + d] = a[reg];
      } else {
        atomicAdd(&outA[((size_t)(b * SS + kposS[64 + q])) * (HH * DD) + h * DD + d], a[reg]);
      }
    }
  }
}

// ---------------------------------------------------------------------------
// Kernel 5 (big-ws path): gather-combine.
// ---------------------------------------------------------------------------
__global__ __launch_bounds__(256) void k_combine(
    const float* __restrict__ numB, const float* __restrict__ denB,
    const int* __restrict__ sk_rank, float* __restrict__ outp)
{
  const int bh = blockIdx.y;
  const int s = blockIdx.x * 16 + (threadIdx.x >> 4);
  const int lane = threadIdx.x & 15;
  const int b = bh >> 3, h = bh & 7;
  float4 acc = make_float4(0.f, 0.f, 0.f, 0.f);
  float den = 0.f;
  #pragma unroll
  for (int n = 0; n < NHH; ++n) {
    int r = sk_rank[(size_t)bh * RANKS + n * SS + s];
    size_t rowi = (size_t)(bh * NHH + n) * SS + r;
    float4 v = *reinterpret_cast<const float4*>(numB + rowi * DD + lane * 4);
    acc.x += v.x; acc.y += v.y; acc.z += v.z; acc.w += v.w;
    den += denB[rowi];
  }
  float inv = 1.0f / den;
  acc.x *= inv; acc.y *= inv; acc.z *= inv; acc.w *= inv;
  *reinterpret_cast<float4*>(outp + ((size_t)(b * SS + s)) * (HH * DD) + h * DD + lane * 4) = acc;
}

// ---------------------------------------------------------------------------
// Kernel 5' (fallback path): divide accumulated numerator by denominator.
// ---------------------------------------------------------------------------
__global__ __launch_bounds__(256) void k_div(
    const float* __restrict__ den, float* __restrict__ outp)
{
  int idx = blockIdx.x * 256 + threadIdx.x;  // grid 4096 -> 1,048,576 float4
  int f = idx * 4;
  int col = f & 511;
  int h = col >> 6;
  int srow = f >> 9;                          // b*4096+s
  int b = srow >> 12, s = srow & 4095;
  float inv = 1.0f / den[(size_t)(b * HH + h) * SS + s];
  float4 v = *reinterpret_cast<float4*>(outp + (size_t)f);
  v.x *= inv; v.y *= inv; v.z *= inv; v.w *= inv;
  *reinterpret_cast<float4*>(outp + (size_t)f) = v;
}

// ---------------------------------------------------------------------------
// Kernel Z: zero the fp32 output (fallback path; harness poisons d_out).
// ---------------------------------------------------------------------------
__global__ __launch_bounds__(256) void k_zero_out(float* __restrict__ outp)
{
  int flat = blockIdx.x * 256 + threadIdx.x;  // grid 4096 -> 1,048,576 float4
  float4 z = make_float4(0.f, 0.f, 0.f, 0.f);
  *reinterpret_cast<float4*>(outp + (size_t)flat * 4) = z;
}

// ---------------------------------------------------------------------------
extern "C" void kernel_launch(void* const* d_in, const int* in_sizes, int n_in,
                              void* d_out, int out_size, void* d_ws, size_t ws_size,
                              hipStream_t stream)
{
  (void)in_sizes; (void)n_in; (void)out_size;
  const u32* dec = (const u32*)d_in[0];
  const u32* hid = (const u32*)d_in[1];
  const u32* wqk = (const u32*)d_in[2];
  const u32* wv  = (const u32*)d_in[3];
  const u32* rot = (const u32*)d_in[4];

  const size_t QKV  = (size_t)BB * HH * SS * DD;   // 4,194,304 elems
  const size_t LOGU = (size_t)BB * HH * NHH * SS;  // 262,144

  float* qb      = (float*)d_ws;
  float* kraw    = qb + QKV;
  float* vb      = kraw + QKV;
  float* den     = vb + QKV;                  // LOGU floats
  int*   sq_pos  = (int*)(den + LOGU);
  int*   sk_pos  = sq_pos + LOGU;
  int*   sk_rank = sk_pos + LOGU;
  u8*    buckets = (u8*)(sk_rank + LOGU);
  int*   flag    = (int*)(buckets + (size_t)2 * 64 * SS);
  const size_t numb_off = 55050496;           // align_up(low region, 256)
  float* numb    = (float*)((char*)d_ws + numb_off);
  // wt planes live INSIDE the numb region (numb not yet live during proj):
  unsigned short* wt0 = (unsigned short*)numb;
  unsigned short* wt1 = wt0 + (size_t)2 * 512 * 512;
  unsigned short* wt2 = wt1 + (size_t)2 * 512 * 512;
  const size_t need_big = numb_off + (size_t)NHH * QKV * sizeof(float);  // 122,159,360
  const int big = (ws_size >= need_big) ? 1 : 0;

  hipMemsetAsync(flag, 0, sizeof(int), stream);
  k_detect<<<dim3(512), 256, 0, stream>>>(wqk, flag);
  k_prep<<<dim3(256, 2), 256, 0, stream>>>(wqk, wv, flag, wt0, wt1, wt2);
  // q,k: scalar (hash-feeding, bit-identical accumulation). v: MFMA (R7-proven).
  k_proj_s<<<dim3(128, 8, 2), 256, 0, stream>>>(dec, hid, wqk, wv, flag, qb, kraw, vb);
  k_proj_v<<<dim3(1024), 256, 0, stream>>>(hid, wt0, wt1, wt2, flag, vb);
  k_hash<<<dim3(64, 2, 16), 256, 0, stream>>>(qb, kraw, rot, flag, buckets);
  k_sort<<<dim3(64, 2), 256, 0, stream>>>(buckets, sq_pos, sk_pos, sk_rank);

  if (big) {
    k_attn<<<dim3(NCC, HH, BB), 256, 0, stream>>>(
        qb, kraw, vb, sq_pos, sk_pos, 1, nullptr, nullptr, numb, den);
    k_combine<<<dim3(SS / 16, BB * HH), 256, 0, stream>>>(
        numb, den, sk_rank, (float*)d_out);
  } else {
    hipMemsetAsync(den, 0, (size_t)BB * HH * SS * sizeof(float), stream);
    k_zero_out<<<dim3(4096), 256, 0, stream>>>((float*)d_out);
    k_attn<<<dim3(NCC, HH, BB), 256, 0, stream>>>(
        qb, kraw, vb, sq_pos, sk_pos, 0, (float*)d_out, den, nullptr, nullptr);
    k_div<<<dim3(4096), 256, 0, stream>>>(den, (float*)d_out);
  }
}